// Round 9
// baseline (5127.181 us; speedup 1.0000x reference)
//
#include <hip/hip_runtime.h>
#include <hip/hip_bf16.h>

#define NN 50000
#define NE 800000
#define LDIM 128
#define NSTEPS 10
#define NB (NE / 128)   // 6250 edge-step blocks, node-aligned windows

typedef __hip_bfloat16 bf16;
typedef __bf16 bf8v __attribute__((ext_vector_type(8)));
typedef float f4v __attribute__((ext_vector_type(4)));
typedef unsigned short u16x8 __attribute__((ext_vector_type(8)));

__device__ inline float bflo(unsigned int u) {
    union { unsigned int i; float f; } x; x.i = u << 16; return x.f;
}
__device__ inline float bfhi(unsigned int u) {
    union { unsigned int i; float f; } x; x.i = u & 0xffff0000u; return x.f;
}
__device__ inline unsigned short f2bf(float f) {
    __hip_bfloat16 h = __float2bfloat16(f);
    unsigned short u; __builtin_memcpy(&u, &h, 2); return u;
}

// async global->LDS DMA, 16 B per lane. LDS dest is wave-uniform base + lane*16
// (linear); global src is per-lane. Drained by the vmcnt(0) the compiler emits
// at the next __syncthreads.
__device__ __forceinline__ void gl_lds16(const void* g, void* l) {
    __builtin_amdgcn_global_load_lds(
        (const __attribute__((address_space(1))) unsigned int*)g,
        (__attribute__((address_space(3))) unsigned int*)l, 16, 0, 0);
}

// ---------------- CSR build: histogram, scan, scatter (ushort permuted endpoints) ----------------

__global__ void k_hist(const int* __restrict__ rcv, int* __restrict__ cnt) {
    int i = blockIdx.x * 256 + threadIdx.x;
    if (i < NE) atomicAdd(&cnt[rcv[i]], 1);
}

__global__ __launch_bounds__(1024) void k_scan(
    const int* __restrict__ cnt, int* __restrict__ row_start,
    int* __restrict__ cur, float* __restrict__ degf, int* __restrict__ first_node) {
    __shared__ int part[1024];
    const int t = threadIdx.x;
    const int CH = (NN + 1023) / 1024;  // 49
    int b0 = t * CH, b1 = b0 + CH; if (b1 > NN) b1 = NN; if (b0 > NN) b0 = NN;
    int s = 0;
    for (int i = b0; i < b1; i++) s += cnt[i];
    part[t] = s;
    __syncthreads();
    for (int off = 1; off < 1024; off <<= 1) {
        int v = (t >= off) ? part[t - off] : 0;
        __syncthreads();
        part[t] += v;
        __syncthreads();
    }
    int run = part[t] - s;  // exclusive prefix
    for (int i = b0; i < b1; i++) {
        row_start[i] = run; cur[i] = run; degf[i] = (float)cnt[i];
        // node i's edge-step block = first-edge/128; min node per block
        if (run < NE) atomicMin(&first_node[run >> 7], i);
        run += cnt[i];
    }
    if (t == 1023) { row_start[NN] = part[1023]; first_node[NB] = NN; }
}

__global__ void k_scatter(const int* __restrict__ snd, const int* __restrict__ rcv,
                          int* __restrict__ cur,
                          unsigned short* __restrict__ snd_p, unsigned short* __restrict__ rcv_p) {
    int i = blockIdx.x * 256 + threadIdx.x;
    if (i < NE) {
        int r = rcv[i];
        int p = atomicAdd(&cur[r], 1);
        snd_p[p] = (unsigned short)snd[i];
        rcv_p[p] = (unsigned short)r;
    }
}

__global__ void k_center(const float* __restrict__ pos, float* __restrict__ csum) {
    __shared__ float s[3][256];
    float a = 0.f, b = 0.f, c = 0.f;
    for (int i = blockIdx.x * 256 + threadIdx.x; i < NN; i += gridDim.x * 256) {
        a += pos[3 * i]; b += pos[3 * i + 1]; c += pos[3 * i + 2];
    }
    int t = threadIdx.x;
    s[0][t] = a; s[1][t] = b; s[2][t] = c;
    __syncthreads();
    for (int off = 128; off > 0; off >>= 1) {
        if (t < off) {
            s[0][t] += s[0][t + off];
            s[1][t] += s[1][t + off];
            s[2][t] += s[2][t + off];
        }
        __syncthreads();
    }
    if (t == 0) {
        atomicAdd(&csum[0], s[0][0]);
        atomicAdd(&csum[1], s[1][0]);
        atomicAdd(&csum[2], s[2][0]);
    }
}

// ---------------- weight prep: fp32 -> bf16 B-frag order; lo=1 emits bf16(x - bf16(x)) ----------------

__global__ void k_prep_w(const float* __restrict__ w, unsigned short* __restrict__ wf,
                         int KT, int Ksrc, int lo) {
    int b = blockIdx.x;
    int s = b / (KT * 8), rem = b % (KT * 8);
    int kt = rem / 8, nt = rem % 8;
    int lane = threadIdx.x, col = lane & 15, quad = lane >> 4;
    const float* W = w + (size_t)s * Ksrc * 128;
    u16x8 o;
#pragma unroll
    for (int jj = 0; jj < 8; jj++) {
        int k = kt * 32 + quad * 8 + jj;
        float x = (k < Ksrc) ? W[(size_t)k * 128 + nt * 16 + col] : 0.f;
        unsigned short h = f2bf(x);
        if (lo) h = f2bf(x - bflo(h));
        o[jj] = h;
    }
    *(u16x8*)(wf + (((size_t)b) * 64 + lane) * 8) = o;
}

// ---------------- MFMA node encoder (split-precision): feat(23 pad 32, hi|lo) -> 128 -> 128 ----------------
// Output: node latent as bf16 hi/lo pair (nlh, nll).

__global__ __launch_bounds__(256) void k_node_enc_m(
    const float* __restrict__ pos, const float* __restrict__ vel,
    const int* __restrict__ rid, const float* __restrict__ remb,
    const float* __restrict__ degf, const float* __restrict__ csum,
    const unsigned short* __restrict__ w1h, const unsigned short* __restrict__ w1l,
    const float* __restrict__ b1,
    const unsigned short* __restrict__ w2h, const unsigned short* __restrict__ w2l,
    const float* __restrict__ b2,
    unsigned short* __restrict__ nlh, unsigned short* __restrict__ nll) {
    __shared__ __align__(16) unsigned short feat_s[32 * 72];   // [hi(32)|lo(32)|pad]
    __shared__ __align__(16) unsigned short hid_s[32 * 264];   // [hi(128)|lo(128)|pad]
    const int tid = threadIdx.x, wave = tid >> 6, lane = tid & 63;
    const int col = lane & 15, quad = lane >> 4;
    bf8v W1H[2], W1L[2], W2H[4][2], W2L[4][2];
#pragma unroll
    for (int t = 0; t < 2; t++) {
        W1H[t] = *(const bf8v*)(w1h + ((size_t)(2 * wave + t) * 64 + lane) * 8);
        W1L[t] = *(const bf8v*)(w1l + ((size_t)(2 * wave + t) * 64 + lane) * 8);
    }
#pragma unroll
    for (int kt = 0; kt < 4; kt++)
#pragma unroll
        for (int t = 0; t < 2; t++) {
            W2H[kt][t] = *(const bf8v*)(w2h + ((size_t)(kt * 8 + 2 * wave + t) * 64 + lane) * 8);
            W2L[kt][t] = *(const bf8v*)(w2l + ((size_t)(kt * 8 + 2 * wave + t) * 64 + lane) * 8);
        }
    float bias1[2], bias2[2];
#pragma unroll
    for (int t = 0; t < 2; t++) {
        bias1[t] = b1[(2 * wave + t) * 16 + col];
        bias2[t] = b2[(2 * wave + t) * 16 + col];
    }
    float cx = csum[0] * (1.0f / NN), cy = csum[1] * (1.0f / NN), cz = csum[2] * (1.0f / NN);
    uint4 z = {0u, 0u, 0u, 0u};
    for (int s2 = tid; s2 < 288; s2 += 256) *(uint4*)(feat_s + s2 * 8) = z;  // zero K-pad

    for (int it = 0; it < 4; it++) {
        const int base = blockIdx.x * 128 + it * 32;
        if (base >= NN) break;
        __syncthreads();
        if (tid < 32) {
            int n = base + tid; if (n > NN - 1) n = NN - 1;
            float v[23];
            v[0] = vel[3 * n]; v[1] = vel[3 * n + 1]; v[2] = vel[3 * n + 2];
            v[3] = pos[3 * n] - cx; v[4] = pos[3 * n + 1] - cy; v[5] = pos[3 * n + 2] - cz;
            v[6] = degf[n];
            int rb = rid[n] * 16;
#pragma unroll
            for (int k = 0; k < 16; k++) v[7 + k] = remb[rb + k];
            unsigned short* f = feat_s + tid * 72;
#pragma unroll
            for (int k = 0; k < 23; k++) {
                unsigned short h = f2bf(v[k]);
                f[k] = h; f[32 + k] = f2bf(v[k] - bflo(h));
            }
        }
        __syncthreads();
        f4v acc[2][2];
#pragma unroll
        for (int mt = 0; mt < 2; mt++)
#pragma unroll
            for (int t = 0; t < 2; t++) acc[mt][t] = (f4v){0.f, 0.f, 0.f, 0.f};
        {
            bf8v a0h = *(const bf8v*)(feat_s + col * 72 + quad * 8);
            bf8v a1h = *(const bf8v*)(feat_s + (16 + col) * 72 + quad * 8);
            bf8v a0l = *(const bf8v*)(feat_s + col * 72 + 32 + quad * 8);
            bf8v a1l = *(const bf8v*)(feat_s + (16 + col) * 72 + 32 + quad * 8);
#pragma unroll
            for (int t = 0; t < 2; t++) {
                acc[0][t] = __builtin_amdgcn_mfma_f32_16x16x32_bf16(a0h, W1H[t], acc[0][t], 0, 0, 0);
                acc[1][t] = __builtin_amdgcn_mfma_f32_16x16x32_bf16(a1h, W1H[t], acc[1][t], 0, 0, 0);
                acc[0][t] = __builtin_amdgcn_mfma_f32_16x16x32_bf16(a0l, W1H[t], acc[0][t], 0, 0, 0);
                acc[1][t] = __builtin_amdgcn_mfma_f32_16x16x32_bf16(a1l, W1H[t], acc[1][t], 0, 0, 0);
                acc[0][t] = __builtin_amdgcn_mfma_f32_16x16x32_bf16(a0h, W1L[t], acc[0][t], 0, 0, 0);
                acc[1][t] = __builtin_amdgcn_mfma_f32_16x16x32_bf16(a1h, W1L[t], acc[1][t], 0, 0, 0);
            }
        }
#pragma unroll
        for (int mt = 0; mt < 2; mt++)
#pragma unroll
            for (int t = 0; t < 2; t++) {
                const int nc = (2 * wave + t) * 16 + col;
#pragma unroll
                for (int r = 0; r < 4; r++) {
                    float h = fmaxf(acc[mt][t][r] + bias1[t], 0.f);
                    unsigned short hh = f2bf(h);
                    hid_s[(mt * 16 + quad * 4 + r) * 264 + nc] = hh;
                    hid_s[(mt * 16 + quad * 4 + r) * 264 + 128 + nc] = f2bf(h - bflo(hh));
                }
            }
        __syncthreads();
#pragma unroll
        for (int mt = 0; mt < 2; mt++)
#pragma unroll
            for (int t = 0; t < 2; t++) acc[mt][t] = (f4v){0.f, 0.f, 0.f, 0.f};
#pragma unroll
        for (int kt = 0; kt < 8; kt++) {
            int w = kt & 3;
            bf8v a0 = *(const bf8v*)(hid_s + col * 264 + kt * 32 + quad * 8);
            bf8v a1 = *(const bf8v*)(hid_s + (16 + col) * 264 + kt * 32 + quad * 8);
#pragma unroll
            for (int t = 0; t < 2; t++) {
                acc[0][t] = __builtin_amdgcn_mfma_f32_16x16x32_bf16(a0, W2H[w][t], acc[0][t], 0, 0, 0);
                acc[1][t] = __builtin_amdgcn_mfma_f32_16x16x32_bf16(a1, W2H[w][t], acc[1][t], 0, 0, 0);
            }
        }
#pragma unroll
        for (int kt = 0; kt < 4; kt++) {
            bf8v a0 = *(const bf8v*)(hid_s + col * 264 + kt * 32 + quad * 8);
            bf8v a1 = *(const bf8v*)(hid_s + (16 + col) * 264 + kt * 32 + quad * 8);
#pragma unroll
            for (int t = 0; t < 2; t++) {
                acc[0][t] = __builtin_amdgcn_mfma_f32_16x16x32_bf16(a0, W2L[kt][t], acc[0][t], 0, 0, 0);
                acc[1][t] = __builtin_amdgcn_mfma_f32_16x16x32_bf16(a1, W2L[kt][t], acc[1][t], 0, 0, 0);
            }
        }
        __syncthreads();  // all hid reads done; overwrite with output hi/lo
#pragma unroll
        for (int mt = 0; mt < 2; mt++)
#pragma unroll
            for (int t = 0; t < 2; t++) {
                const int nc = (2 * wave + t) * 16 + col;
#pragma unroll
                for (int r = 0; r < 4; r++) {
                    const int row = mt * 16 + quad * 4 + r;
                    float v = acc[mt][t][r] + bias2[t];
                    unsigned short hh = f2bf(v);
                    hid_s[row * 264 + nc] = hh;
                    hid_s[row * 264 + 128 + nc] = f2bf(v - bflo(hh));
                }
            }
        __syncthreads();
#pragma unroll
        for (int p = 0; p < 2; p++) {
            int s2 = p * 256 + tid, e = s2 >> 4, c16 = s2 & 15;
            if (base + e < NN) {
                *(uint4*)(nlh + (size_t)(base + e) * 128 + c16 * 8) =
                    *(const uint4*)(hid_s + e * 264 + c16 * 8);
                *(uint4*)(nll + (size_t)(base + e) * 128 + c16 * 8) =
                    *(const uint4*)(hid_s + e * 264 + 128 + c16 * 8);
            }
        }
    }
}

// ---------------- MFMA edge encoder (split-precision): feat(9 pad 32, hi|lo) -> 128 -> 128 ----------------

__global__ __launch_bounds__(256) void k_edge_enc_m(
    const float* __restrict__ pos, const float* __restrict__ vel,
    const int* __restrict__ rid,
    const unsigned short* __restrict__ snd, const unsigned short* __restrict__ rcv,
    const unsigned short* __restrict__ w1h, const unsigned short* __restrict__ w1l,
    const float* __restrict__ b1,
    const unsigned short* __restrict__ w2h, const unsigned short* __restrict__ w2l,
    const float* __restrict__ b2,
    unsigned short* __restrict__ el) {
    __shared__ __align__(16) unsigned short feat_s[32 * 72];
    __shared__ __align__(16) unsigned short hid_s[32 * 264];
    const int tid = threadIdx.x, wave = tid >> 6, lane = tid & 63;
    const int col = lane & 15, quad = lane >> 4;
    bf8v W1H[2], W1L[2], W2H[4][2], W2L[4][2];
#pragma unroll
    for (int t = 0; t < 2; t++) {
        W1H[t] = *(const bf8v*)(w1h + ((size_t)(2 * wave + t) * 64 + lane) * 8);
        W1L[t] = *(const bf8v*)(w1l + ((size_t)(2 * wave + t) * 64 + lane) * 8);
    }
#pragma unroll
    for (int kt = 0; kt < 4; kt++)
#pragma unroll
        for (int t = 0; t < 2; t++) {
            W2H[kt][t] = *(const bf8v*)(w2h + ((size_t)(kt * 8 + 2 * wave + t) * 64 + lane) * 8);
            W2L[kt][t] = *(const bf8v*)(w2l + ((size_t)(kt * 8 + 2 * wave + t) * 64 + lane) * 8);
        }
    float bias1[2], bias2[2];
#pragma unroll
    for (int t = 0; t < 2; t++) {
        bias1[t] = b1[(2 * wave + t) * 16 + col];
        bias2[t] = b2[(2 * wave + t) * 16 + col];
    }
    uint4 z = {0u, 0u, 0u, 0u};
    for (int s2 = tid; s2 < 288; s2 += 256) *(uint4*)(feat_s + s2 * 8) = z;

    for (int it = 0; it < 4; it++) {
        const int base = blockIdx.x * 128 + it * 32;
        __syncthreads();
        if (tid < 32) {
            int e = base + tid;
            int s = snd[e], r = rcv[e];
            float v[9];
            v[0] = pos[3 * s] - pos[3 * r]; v[1] = pos[3 * s + 1] - pos[3 * r + 1]; v[2] = pos[3 * s + 2] - pos[3 * r + 2];
            v[3] = vel[3 * s] - vel[3 * r]; v[4] = vel[3 * s + 1] - vel[3 * r + 1]; v[5] = vel[3 * s + 2] - vel[3 * r + 2];
            float sq = v[0] * v[0] + v[1] * v[1] + v[2] * v[2];
            v[6] = sqrtf(sq); v[7] = sq;
            v[8] = (rid[s] == rid[r]) ? 1.f : 0.f;
            unsigned short* f = feat_s + tid * 72;
#pragma unroll
            for (int k = 0; k < 9; k++) {
                unsigned short h = f2bf(v[k]);
                f[k] = h; f[32 + k] = f2bf(v[k] - bflo(h));
            }
        }
        __syncthreads();
        f4v acc[2][2];
#pragma unroll
        for (int mt = 0; mt < 2; mt++)
#pragma unroll
            for (int t = 0; t < 2; t++) acc[mt][t] = (f4v){0.f, 0.f, 0.f, 0.f};
        {
            bf8v a0h = *(const bf8v*)(feat_s + col * 72 + quad * 8);
            bf8v a1h = *(const bf8v*)(feat_s + (16 + col) * 72 + quad * 8);
            bf8v a0l = *(const bf8v*)(feat_s + col * 72 + 32 + quad * 8);
            bf8v a1l = *(const bf8v*)(feat_s + (16 + col) * 72 + 32 + quad * 8);
#pragma unroll
            for (int t = 0; t < 2; t++) {
                acc[0][t] = __builtin_amdgcn_mfma_f32_16x16x32_bf16(a0h, W1H[t], acc[0][t], 0, 0, 0);
                acc[1][t] = __builtin_amdgcn_mfma_f32_16x16x32_bf16(a1h, W1H[t], acc[1][t], 0, 0, 0);
                acc[0][t] = __builtin_amdgcn_mfma_f32_16x16x32_bf16(a0l, W1H[t], acc[0][t], 0, 0, 0);
                acc[1][t] = __builtin_amdgcn_mfma_f32_16x16x32_bf16(a1l, W1H[t], acc[1][t], 0, 0, 0);
                acc[0][t] = __builtin_amdgcn_mfma_f32_16x16x32_bf16(a0h, W1L[t], acc[0][t], 0, 0, 0);
                acc[1][t] = __builtin_amdgcn_mfma_f32_16x16x32_bf16(a1h, W1L[t], acc[1][t], 0, 0, 0);
            }
        }
#pragma unroll
        for (int mt = 0; mt < 2; mt++)
#pragma unroll
            for (int t = 0; t < 2; t++) {
                const int nc = (2 * wave + t) * 16 + col;
#pragma unroll
                for (int r = 0; r < 4; r++) {
                    float h = fmaxf(acc[mt][t][r] + bias1[t], 0.f);
                    unsigned short hh = f2bf(h);
                    hid_s[(mt * 16 + quad * 4 + r) * 264 + nc] = hh;
                    hid_s[(mt * 16 + quad * 4 + r) * 264 + 128 + nc] = f2bf(h - bflo(hh));
                }
            }
        __syncthreads();
#pragma unroll
        for (int mt = 0; mt < 2; mt++)
#pragma unroll
            for (int t = 0; t < 2; t++) acc[mt][t] = (f4v){0.f, 0.f, 0.f, 0.f};
#pragma unroll
        for (int kt = 0; kt < 8; kt++) {
            int w = kt & 3;
            bf8v a0 = *(const bf8v*)(hid_s + col * 264 + kt * 32 + quad * 8);
            bf8v a1 = *(const bf8v*)(hid_s + (16 + col) * 264 + kt * 32 + quad * 8);
#pragma unroll
            for (int t = 0; t < 2; t++) {
                acc[0][t] = __builtin_amdgcn_mfma_f32_16x16x32_bf16(a0, W2H[w][t], acc[0][t], 0, 0, 0);
                acc[1][t] = __builtin_amdgcn_mfma_f32_16x16x32_bf16(a1, W2H[w][t], acc[1][t], 0, 0, 0);
            }
        }
#pragma unroll
        for (int kt = 0; kt < 4; kt++) {
            bf8v a0 = *(const bf8v*)(hid_s + col * 264 + kt * 32 + quad * 8);
            bf8v a1 = *(const bf8v*)(hid_s + (16 + col) * 264 + kt * 32 + quad * 8);
#pragma unroll
            for (int t = 0; t < 2; t++) {
                acc[0][t] = __builtin_amdgcn_mfma_f32_16x16x32_bf16(a0, W2L[kt][t], acc[0][t], 0, 0, 0);
                acc[1][t] = __builtin_amdgcn_mfma_f32_16x16x32_bf16(a1, W2L[kt][t], acc[1][t], 0, 0, 0);
            }
        }
        __syncthreads();
#pragma unroll
        for (int mt = 0; mt < 2; mt++)
#pragma unroll
            for (int t = 0; t < 2; t++) {
                const int nc = (2 * wave + t) * 16 + col;
#pragma unroll
                for (int r = 0; r < 4; r++)
                    hid_s[(mt * 16 + quad * 4 + r) * 264 + nc] = f2bf(acc[mt][t][r] + bias2[t]);
            }
        __syncthreads();
#pragma unroll
        for (int p = 0; p < 2; p++) {
            int s2 = p * 256 + tid, e = s2 >> 4, c16 = s2 & 15;
            *(uint4*)(el + (size_t)(base + e) * 128 + c16 * 8) =
                *(const uint4*)(hid_s + e * 264 + c16 * 8);
        }
    }
}

// ---------------- MFMA edge processor step (node-aligned blocks, fused aggregation) ----------------
// v10 = v9 (node-aligned blocks, fused zero-atomic aggregation) with the walk's
// summation order made BIT-IDENTICAL to the old k_agg: edge j of a node goes to
// partial p[j&3] (named scalars -- rule #20), flush (p0+p1)+(p2+p3). v9's
// sequential sum had ~2x the rounding error of k_agg's 4-way tree and failed
// absmax by 13% after 10 amplifying steps. Branches in the walk are uniform
// across the 128 walker threads (shared rcv_s / same rows), so cheap.

__global__ __launch_bounds__(256) void k_edge_step(
    unsigned short* __restrict__ el, const unsigned short* __restrict__ nlh,
    const unsigned short* __restrict__ snd, const unsigned short* __restrict__ rcv,
    const int* __restrict__ rs, const int* __restrict__ first_node,
    const unsigned short* __restrict__ w1f, const float* __restrict__ b1,
    const unsigned short* __restrict__ w2f, const float* __restrict__ b2,
    unsigned short* __restrict__ agg) {
    __shared__ __align__(1024) unsigned short stage_s[2][3][32][128];  // 48 KB
    __shared__ __align__(16) unsigned short hid_s[32 * 136];           // 8.5 KB
    __shared__ int rcv_s[32];
    const int tid = threadIdx.x;
    const int wave = tid >> 6, lane = tid & 63;
    const int col = lane & 15, quad = lane >> 4;
    const int erow = tid >> 4, c16 = tid & 15;

    const int n0 = first_node[blockIdx.x];
    const int n1 = first_node[blockIdx.x + 1];
    const int st = rs[n0], en = rs[n1];
    const int nt = (en - st + 31) >> 5;

    bf8v W1[12][2], W2[4][2];
#pragma unroll
    for (int kt = 0; kt < 12; kt++)
#pragma unroll
        for (int t = 0; t < 2; t++)
            W1[kt][t] = *(const bf8v*)(w1f + ((size_t)(kt * 8 + 2 * wave + t) * 64 + lane) * 8);
#pragma unroll
    for (int kt = 0; kt < 4; kt++)
#pragma unroll
        for (int t = 0; t < 2; t++)
            W2[kt][t] = *(const bf8v*)(w2f + ((size_t)(kt * 8 + 2 * wave + t) * 64 + lane) * 8);
    float bias1[2], bias2[2];
#pragma unroll
    for (int t = 0; t < 2; t++) {
        bias1[t] = b1[(2 * wave + t) * 16 + col];
        bias2[t] = b2[(2 * wave + t) * 16 + col];
    }

    // staging geometry: wave stages rows [wave*8, wave*8+8) of each stream.
    // lane covers row = wave*8 + i*4 + (lane>>4), 16 B at byte (lane&15)*16.
    // Global source pre-swizzled (byte ^= (row&7)<<4); LDS dest linear.
    const int srow0 = wave * 8 + (lane >> 4);
    const int srow1 = srow0 + 4;
    const int skb = (lane & 15) * 16;
    const int soff0 = skb ^ ((srow0 & 7) << 4);
    const int soff1 = skb ^ ((srow1 & 7) << 4);
    const char* elc = (const char*)el;
    const char* nlc = (const char*)nlh;

    auto clampe = [&](int e) { return e < en ? e : en - 1; };
    auto issue = [&](int t, int b, int si0, int si1, int ri0, int ri1) {
        char* s0 = (char*)&stage_s[b][0][wave * 8][0];
        char* s1 = (char*)&stage_s[b][1][wave * 8][0];
        char* s2 = (char*)&stage_s[b][2][wave * 8][0];
        const int gb = st + t * 32;
        gl_lds16(elc + (size_t)clampe(gb + srow0) * 256 + soff0, s0);
        gl_lds16(elc + (size_t)clampe(gb + srow1) * 256 + soff1, s0 + 1024);
        gl_lds16(nlc + (size_t)si0 * 256 + soff0, s1);
        gl_lds16(nlc + (size_t)si1 * 256 + soff1, s1 + 1024);
        gl_lds16(nlc + (size_t)ri0 * 256 + soff0, s2);
        gl_lds16(nlc + (size_t)ri1 * 256 + soff1, s2 + 1024);
    };

    // prologue: issue tile 0; preload gather indices for tile 1
    {
        int si0 = snd[clampe(st + srow0)], si1 = snd[clampe(st + srow1)];
        int ri0 = rcv[clampe(st + srow0)], ri1 = rcv[clampe(st + srow1)];
        issue(0, 0, si0, si1, ri0, ri1);
    }
    int nsi0 = 0, nsi1 = 0, nri0 = 0, nri1 = 0;
    if (nt > 1) {
        nsi0 = snd[clampe(st + 32 + srow0)]; nsi1 = snd[clampe(st + 32 + srow1)];
        nri0 = rcv[clampe(st + 32 + srow0)]; nri1 = rcv[clampe(st + 32 + srow1)];
    }

    // fused-agg carry state (threads 0-127: channel = tid). k_agg-exact order:
    // edge j of node -> p[j&3]; flush (p0+p1)+(p2+p3).
    int curn = n0, cnt4 = 0;
    float p0 = 0.f, p1 = 0.f, p2 = 0.f, p3 = 0.f;

    for (int it = 0; it < nt; it++) {
        const int cur = it & 1, nxt = cur ^ 1;
        const int base = st + it * 32;
        __syncthreads();  // B0: cur staged+visible; prev tile's hid_s/rcv_s reads done
        if (tid < 32) rcv_s[tid] = rcv[clampe(base + tid)];
        if (it + 1 < nt) {
            issue(it + 1, nxt, nsi0, nsi1, nri0, nri1);  // drains at B1 (under L1)
            if (it + 2 < nt) {
                int gb = st + (it + 2) * 32;
                nsi0 = snd[clampe(gb + srow0)]; nsi1 = snd[clampe(gb + srow1)];
                nri0 = rcv[clampe(gb + srow0)]; nri1 = rcv[clampe(gb + srow1)];
            }
        }

        // ---- layer 1: K=384 over [el|snd|rcv] buffers (swizzled reads) ----
        f4v acc[2][2];
#pragma unroll
        for (int mt = 0; mt < 2; mt++)
#pragma unroll
            for (int t = 0; t < 2; t++) acc[mt][t] = (f4v){0.f, 0.f, 0.f, 0.f};
        const int sw = (col & 7) << 4;
#pragma unroll
        for (int kt = 0; kt < 12; kt++) {
            const char* sb = (const char*)&stage_s[cur][kt >> 2][0][0];
            const int kb = (kt & 3) * 64 + quad * 16;
            bf8v a0 = *(const bf8v*)(sb + col * 256 + (kb ^ sw));
            bf8v a1 = *(const bf8v*)(sb + (16 + col) * 256 + (kb ^ sw));
            acc[0][0] = __builtin_amdgcn_mfma_f32_16x16x32_bf16(a0, W1[kt][0], acc[0][0], 0, 0, 0);
            acc[0][1] = __builtin_amdgcn_mfma_f32_16x16x32_bf16(a0, W1[kt][1], acc[0][1], 0, 0, 0);
            acc[1][0] = __builtin_amdgcn_mfma_f32_16x16x32_bf16(a1, W1[kt][0], acc[1][0], 0, 0, 0);
            acc[1][1] = __builtin_amdgcn_mfma_f32_16x16x32_bf16(a1, W1[kt][1], acc[1][1], 0, 0, 0);
        }
#pragma unroll
        for (int mt = 0; mt < 2; mt++)
#pragma unroll
            for (int t = 0; t < 2; t++) {
                const int nc = (2 * wave + t) * 16 + col;
#pragma unroll
                for (int r = 0; r < 4; r++) {
                    float v = fmaxf(acc[mt][t][r] + bias1[t], 0.f);
                    hid_s[(mt * 16 + quad * 4 + r) * 136 + nc] = f2bf(v);
                }
            }
        __syncthreads();  // B1: hid visible; prefetch vmcnt drained here

        // ---- layer 2 ----
#pragma unroll
        for (int mt = 0; mt < 2; mt++)
#pragma unroll
            for (int t = 0; t < 2; t++) acc[mt][t] = (f4v){0.f, 0.f, 0.f, 0.f};
#pragma unroll
        for (int kt = 0; kt < 4; kt++) {
            bf8v a0 = *(const bf8v*)(hid_s + col * 136 + kt * 32 + quad * 8);
            bf8v a1 = *(const bf8v*)(hid_s + (16 + col) * 136 + kt * 32 + quad * 8);
            acc[0][0] = __builtin_amdgcn_mfma_f32_16x16x32_bf16(a0, W2[kt][0], acc[0][0], 0, 0, 0);
            acc[0][1] = __builtin_amdgcn_mfma_f32_16x16x32_bf16(a0, W2[kt][1], acc[0][1], 0, 0, 0);
            acc[1][0] = __builtin_amdgcn_mfma_f32_16x16x32_bf16(a1, W2[kt][0], acc[1][0], 0, 0, 0);
            acc[1][1] = __builtin_amdgcn_mfma_f32_16x16x32_bf16(a1, W2[kt][1], acc[1][1], 0, 0, 0);
        }
        __syncthreads();  // B2: all hid reads done; reuse hid_s for output

        // ---- epilogue: residual (cur el buffer, swizzled) + bias2 -> hid_s ----
#pragma unroll
        for (int mt = 0; mt < 2; mt++)
#pragma unroll
            for (int t = 0; t < 2; t++) {
                const int nc = (2 * wave + t) * 16 + col;
#pragma unroll
                for (int r = 0; r < 4; r++) {
                    const int row = mt * 16 + quad * 4 + r;
                    float res = bflo((unsigned int)stage_s[cur][0][row][nc ^ ((row & 7) << 3)]);
                    float v = acc[mt][t][r] + bias2[t] + res;
                    hid_s[row * 136 + nc] = f2bf(v);
                }
            }
        __syncthreads();  // B3: out staged

        // global el store (guarded)
#pragma unroll
        for (int p = 0; p < 2; p++) {
            int e = p * 16 + erow;
            if (base + e < en)
                *(uint4*)(el + (size_t)(base + e) * 128 + c16 * 8) =
                    *(const uint4*)(hid_s + e * 136 + c16 * 8);
        }

        // ---- fused aggregation walk: threads 0-127, channel = tid ----
        if (tid < 128) {
            int rows = en - base; if (rows > 32) rows = 32;
            for (int r = 0; r < rows; ++r) {
                int nd = rcv_s[r];
                if (nd != curn) {  // uniform across walker threads
                    agg[(size_t)curn * 128 + tid] = f2bf((p0 + p1) + (p2 + p3));
                    for (int m = curn + 1; m < nd; ++m)
                        agg[(size_t)m * 128 + tid] = 0;  // zero-degree gap
                    curn = nd; p0 = p1 = p2 = p3 = 0.f; cnt4 = 0;
                }
                float v = bflo((unsigned int)hid_s[r * 136 + tid]);
                switch (cnt4 & 3) {  // uniform branch; named scalars stay in VGPRs
                    case 0: p0 += v; break;
                    case 1: p1 += v; break;
                    case 2: p2 += v; break;
                    default: p3 += v; break;
                }
                cnt4++;
            }
        }
    }
    // flush carry + trailing zero-degree nodes
    if (tid < 128) {
        agg[(size_t)curn * 128 + tid] = f2bf((p0 + p1) + (p2 + p3));
        for (int m = curn + 1; m < n1; ++m) agg[(size_t)m * 128 + tid] = 0;
    }
}

// ---------------- node step: [nl_hi|nl_lo|agg_hi] (K=384) -> 128 -> 128, residual, hi/lo out ----------------
// 64 nodes/block (2 tiles of 32), grid 782. agg produced by fused edge-step walk.

__global__ __launch_bounds__(256) void k_node_step_s(
    unsigned short* __restrict__ nlh, unsigned short* __restrict__ nll,
    const unsigned short* __restrict__ agg,
    const unsigned short* __restrict__ w1h, const unsigned short* __restrict__ w1l,
    const float* __restrict__ b1,
    const unsigned short* __restrict__ w2h, const unsigned short* __restrict__ w2l,
    const float* __restrict__ b2) {
    __shared__ __align__(16) unsigned short a_s[32 * 392];
    __shared__ __align__(16) unsigned short hid_s[32 * 264];
    const int tid = threadIdx.x, wave = tid >> 6, lane = tid & 63;
    const int col = lane & 15, quad = lane >> 4;
    bf8v W1H[8][2], W1L[8][2], W2H[4][2], W2L[4][2];
#pragma unroll
    for (int kt = 0; kt < 8; kt++)
#pragma unroll
        for (int t = 0; t < 2; t++) {
            W1H[kt][t] = *(const bf8v*)(w1h + ((size_t)(kt * 8 + 2 * wave + t) * 64 + lane) * 8);
            W1L[kt][t] = *(const bf8v*)(w1l + ((size_t)(kt * 8 + 2 * wave + t) * 64 + lane) * 8);
        }
#pragma unroll
    for (int kt = 0; kt < 4; kt++)
#pragma unroll
        for (int t = 0; t < 2; t++) {
            W2H[kt][t] = *(const bf8v*)(w2h + ((size_t)(kt * 8 + 2 * wave + t) * 64 + lane) * 8);
            W2L[kt][t] = *(const bf8v*)(w2l + ((size_t)(kt * 8 + 2 * wave + t) * 64 + lane) * 8);
        }
    float bias1[2], bias2[2];
#pragma unroll
    for (int t = 0; t < 2; t++) {
        bias1[t] = b1[(2 * wave + t) * 16 + col];
        bias2[t] = b2[(2 * wave + t) * 16 + col];
    }
    for (int it = 0; it < 2; it++) {
        const int base = blockIdx.x * 64 + it * 32;
        if (base >= NN) break;
        __syncthreads();  // prev-iter a_s/hid_s reads done
        // stage: direct uint4 copies (hi | lo | agg)
#pragma unroll
        for (int p = 0; p < 2; p++) {
            int e = p * 16 + (tid >> 4), c16 = tid & 15;
            int n = base + e; if (n > NN - 1) n = NN - 1;
            *(uint4*)(a_s + e * 392 + c16 * 8) =
                *(const uint4*)(nlh + (size_t)n * 128 + c16 * 8);
            *(uint4*)(a_s + e * 392 + 128 + c16 * 8) =
                *(const uint4*)(nll + (size_t)n * 128 + c16 * 8);
            *(uint4*)(a_s + e * 392 + 256 + c16 * 8) =
                *(const uint4*)(agg + (size_t)n * 128 + c16 * 8);
        }
        __syncthreads();

        f4v acc[2][2];
#pragma unroll
        for (int mt = 0; mt < 2; mt++)
#pragma unroll
            for (int t = 0; t < 2; t++) acc[mt][t] = (f4v){0.f, 0.f, 0.f, 0.f};
        // layer1: nl hi+lo vs W1H[0..3], agg vs W1H[4..7], nl hi vs W1L[0..3], agg vs W1L[4..7]
#pragma unroll
        for (int kt = 0; kt < 8; kt++) {
            bf8v a0 = *(const bf8v*)(a_s + col * 392 + kt * 32 + quad * 8);
            bf8v a1 = *(const bf8v*)(a_s + (16 + col) * 392 + kt * 32 + quad * 8);
#pragma unroll
            for (int t = 0; t < 2; t++) {
                acc[0][t] = __builtin_amdgcn_mfma_f32_16x16x32_bf16(a0, W1H[kt & 3][t], acc[0][t], 0, 0, 0);
                acc[1][t] = __builtin_amdgcn_mfma_f32_16x16x32_bf16(a1, W1H[kt & 3][t], acc[1][t], 0, 0, 0);
            }
        }
#pragma unroll
        for (int kt = 0; kt < 4; kt++) {
            bf8v a0 = *(const bf8v*)(a_s + col * 392 + 256 + kt * 32 + quad * 8);
            bf8v a1 = *(const bf8v*)(a_s + (16 + col) * 392 + 256 + kt * 32 + quad * 8);
#pragma unroll
            for (int t = 0; t < 2; t++) {
                acc[0][t] = __builtin_amdgcn_mfma_f32_16x16x32_bf16(a0, W1H[4 + kt][t], acc[0][t], 0, 0, 0);
                acc[1][t] = __builtin_amdgcn_mfma_f32_16x16x32_bf16(a1, W1H[4 + kt][t], acc[1][t], 0, 0, 0);
            }
        }
#pragma unroll
        for (int kt = 0; kt < 4; kt++) {
            bf8v a0 = *(const bf8v*)(a_s + col * 392 + kt * 32 + quad * 8);
            bf8v a1 = *(const bf8v*)(a_s + (16 + col) * 392 + kt * 32 + quad * 8);
#pragma unroll
            for (int t = 0; t < 2; t++) {
                acc[0][t] = __builtin_amdgcn_mfma_f32_16x16x32_bf16(a0, W1L[kt][t], acc[0][t], 0, 0, 0);
                acc[1][t] = __builtin_amdgcn_mfma_f32_16x16x32_bf16(a1, W1L[kt][t], acc[1][t], 0, 0, 0);
            }
        }
#pragma unroll
        for (int kt = 0; kt < 4; kt++) {
            bf8v a0 = *(const bf8v*)(a_s + col * 392 + 256 + kt * 32 + quad * 8);
            bf8v a1 = *(const bf8v*)(a_s + (16 + col) * 392 + 256 + kt * 32 + quad * 8);
#pragma unroll
            for (int t = 0; t < 2; t++) {
                acc[0][t] = __builtin_amdgcn_mfma_f32_16x16x32_bf16(a0, W1L[4 + kt][t], acc[0][t], 0, 0, 0);
                acc[1][t] = __builtin_amdgcn_mfma_f32_16x16x32_bf16(a1, W1L[4 + kt][t], acc[1][t], 0, 0, 0);
            }
        }
#pragma unroll
        for (int mt = 0; mt < 2; mt++)
#pragma unroll
            for (int t = 0; t < 2; t++) {
                const int nc = (2 * wave + t) * 16 + col;
#pragma unroll
                for (int r = 0; r < 4; r++) {
                    float h = fmaxf(acc[mt][t][r] + bias1[t], 0.f);
                    unsigned short hh = f2bf(h);
                    hid_s[(mt * 16 + quad * 4 + r) * 264 + nc] = hh;
                    hid_s[(mt * 16 + quad * 4 + r) * 264 + 128 + nc] = f2bf(h - bflo(hh));
                }
            }
        __syncthreads();
#pragma unroll
        for (int mt = 0; mt < 2; mt++)
#pragma unroll
            for (int t = 0; t < 2; t++) acc[mt][t] = (f4v){0.f, 0.f, 0.f, 0.f};
#pragma unroll
        for (int kt = 0; kt < 8; kt++) {
            int w = kt & 3;
            bf8v a0 = *(const bf8v*)(hid_s + col * 264 + kt * 32 + quad * 8);
            bf8v a1 = *(const bf8v*)(hid_s + (16 + col) * 264 + kt * 32 + quad * 8);
#pragma unroll
            for (int t = 0; t < 2; t++) {
                acc[0][t] = __builtin_amdgcn_mfma_f32_16x16x32_bf16(a0, W2H[w][t], acc[0][t], 0, 0, 0);
                acc[1][t] = __builtin_amdgcn_mfma_f32_16x16x32_bf16(a1, W2H[w][t], acc[1][t], 0, 0, 0);
            }
        }
#pragma unroll
        for (int kt = 0; kt < 4; kt++) {
            bf8v a0 = *(const bf8v*)(hid_s + col * 264 + kt * 32 + quad * 8);
            bf8v a1 = *(const bf8v*)(hid_s + (16 + col) * 264 + kt * 32 + quad * 8);
#pragma unroll
            for (int t = 0; t < 2; t++) {
                acc[0][t] = __builtin_amdgcn_mfma_f32_16x16x32_bf16(a0, W2L[kt][t], acc[0][t], 0, 0, 0);
                acc[1][t] = __builtin_amdgcn_mfma_f32_16x16x32_bf16(a1, W2L[kt][t], acc[1][t], 0, 0, 0);
            }
        }
        __syncthreads();  // all L2 reads of hid done; reuse hid_s for output staging
#pragma unroll
        for (int mt = 0; mt < 2; mt++)
#pragma unroll
            for (int t = 0; t < 2; t++) {
                const int nc = (2 * wave + t) * 16 + col;
#pragma unroll
                for (int r = 0; r < 4; r++) {
                    const int row = mt * 16 + quad * 4 + r;
                    // residual from a_s hi+lo (still intact)
                    float res = bflo((unsigned int)a_s[row * 392 + nc]) +
                                bflo((unsigned int)a_s[row * 392 + 128 + nc]);
                    float v = acc[mt][t][r] + bias2[t] + res;
                    unsigned short hh = f2bf(v);
                    hid_s[row * 264 + nc] = hh;
                    hid_s[row * 264 + 128 + nc] = f2bf(v - bflo(hh));
                }
            }
        __syncthreads();  // out staged
#pragma unroll
        for (int p = 0; p < 2; p++) {
            int e = p * 16 + (tid >> 4), c16 = tid & 15;
            if (base + e < NN) {
                *(uint4*)(nlh + (size_t)(base + e) * 128 + c16 * 8) =
                    *(const uint4*)(hid_s + e * 264 + c16 * 8);
                *(uint4*)(nll + (size_t)(base + e) * 128 + c16 * 8) =
                    *(const uint4*)(hid_s + e * 264 + 128 + c16 * 8);
            }
        }
    }
}

// ---------------- decoder: 128 -> 128 -> 3 (fp32 VALU, reads hi+lo) ----------------

__global__ __launch_bounds__(128) void k_decode(
    const unsigned short* __restrict__ nlh, const unsigned short* __restrict__ nll,
    const float* __restrict__ w1, const float* __restrict__ b1,
    const float* __restrict__ w2, const float* __restrict__ b2,
    float* __restrict__ out) {
    __shared__ float inl[16][128];
    __shared__ float hid[16][128];
    int j = threadIdx.x;
    int base = blockIdx.x * 16;
    for (int e = 0; e < 16; e++)
        inl[e][j] = bflo((unsigned int)nlh[(size_t)(base + e) * 128 + j]) +
                    bflo((unsigned int)nll[(size_t)(base + e) * 128 + j]);
    __syncthreads();
    float acc[16];
#pragma unroll
    for (int e = 0; e < 16; e++) acc[e] = b1[j];
    for (int kc = 0; kc < 16; kc++) {
        float w[8];
#pragma unroll
        for (int t = 0; t < 8; t++) w[t] = w1[(kc * 8 + t) * 128 + j];
#pragma unroll
        for (int e = 0; e < 16; e++) {
            float4 h0 = *(const float4*)&inl[e][kc * 8];
            float4 h1 = *(const float4*)&inl[e][kc * 8 + 4];
            acc[e] = fmaf(h0.x, w[0], acc[e]); acc[e] = fmaf(h0.y, w[1], acc[e]);
            acc[e] = fmaf(h0.z, w[2], acc[e]); acc[e] = fmaf(h0.w, w[3], acc[e]);
            acc[e] = fmaf(h1.x, w[4], acc[e]); acc[e] = fmaf(h1.y, w[5], acc[e]);
            acc[e] = fmaf(h1.z, w[6], acc[e]); acc[e] = fmaf(h1.w, w[7], acc[e]);
        }
    }
#pragma unroll
    for (int e = 0; e < 16; e++) hid[e][j] = fmaxf(acc[e], 0.f);
    __syncthreads();
    if (j < 48) {
        int e = j / 3, ch = j - 3 * (j / 3);
        float s = b2[ch];
        for (int k = 0; k < 128; k++) s = fmaf(hid[e][k], w2[k * 3 + ch], s);
        out[(size_t)(base + e) * 3 + ch] = s;
    }
}

// ---------------- launch ----------------

extern "C" void kernel_launch(void* const* d_in, const int* in_sizes, int n_in,
                              void* d_out, int out_size, void* d_ws, size_t ws_size,
                              hipStream_t stream) {
    (void)in_sizes; (void)n_in; (void)out_size; (void)ws_size;
    const float* pos   = (const float*)d_in[0];
    const float* vel   = (const float*)d_in[1];
    const int*   rid   = (const int*)d_in[2];
    const int*   snd   = (const int*)d_in[3];
    const int*   rcv   = (const int*)d_in[4];
    const float* remb  = (const float*)d_in[5];
    const float* ne_w1 = (const float*)d_in[6];
    const float* ne_b1 = (const float*)d_in[7];
    const float* ne_w2 = (const float*)d_in[8];
    const float* ne_b2 = (const float*)d_in[9];
    const float* ee_w1 = (const float*)d_in[10];
    const float* ee_b1 = (const float*)d_in[11];
    const float* ee_w2 = (const float*)d_in[12];
    const float* ee_b2 = (const float*)d_in[13];
    const float* pe_w1 = (const float*)d_in[14];
    const float* pe_b1 = (const float*)d_in[15];
    const float* pe_w2 = (const float*)d_in[16];
    const float* pe_b2 = (const float*)d_in[17];
    const float* pn_w1 = (const float*)d_in[18];
    const float* pn_b1 = (const float*)d_in[19];
    const float* pn_w2 = (const float*)d_in[20];
    const float* pn_b2 = (const float*)d_in[21];
    const float* de_w1 = (const float*)d_in[22];
    const float* de_b1 = (const float*)d_in[23];
    const float* de_w2 = (const float*)d_in[24];
    const float* de_b2 = (const float*)d_in[25];
    float* out = (float*)d_out;

    // workspace carve (~250.7e6 B — under the 256.2e6 proven available)
    char* p = (char*)d_ws;
    auto carve = [&](size_t bytes) { void* q = (void*)p; p += (bytes + 15) & ~(size_t)15; return q; };
    unsigned short* el    = (unsigned short*)carve((size_t)NE * LDIM * 2);   // 204.8e6, CSR order
    unsigned short* nlh   = (unsigned short*)carve((size_t)NN * LDIM * 2);   // 12.8e6
    unsigned short* nll   = (unsigned short*)carve((size_t)NN * LDIM * 2);   // 12.8e6
    unsigned short* agg   = (unsigned short*)carve((size_t)NN * LDIM * 2);   // 12.8e6 (bf16)
    unsigned short* w1f_e = (unsigned short*)carve((size_t)NSTEPS * 12 * 8 * 512 * 2);
    unsigned short* w2f_e = (unsigned short*)carve((size_t)NSTEPS * 4 * 8 * 512 * 2);
    unsigned short* w1h_n = (unsigned short*)carve((size_t)NSTEPS * 8 * 8 * 512 * 2);
    unsigned short* w1l_n = (unsigned short*)carve((size_t)NSTEPS * 8 * 8 * 512 * 2);
    unsigned short* w2h_n = (unsigned short*)carve((size_t)NSTEPS * 4 * 8 * 512 * 2);
    unsigned short* w2l_n = (unsigned short*)carve((size_t)NSTEPS * 4 * 8 * 512 * 2);
    unsigned short* eew1h = (unsigned short*)carve((size_t)1 * 8 * 512 * 2);
    unsigned short* eew1l = (unsigned short*)carve((size_t)1 * 8 * 512 * 2);
    unsigned short* eew2h = (unsigned short*)carve((size_t)4 * 8 * 512 * 2);
    unsigned short* eew2l = (unsigned short*)carve((size_t)4 * 8 * 512 * 2);
    unsigned short* new1h = (unsigned short*)carve((size_t)1 * 8 * 512 * 2);
    unsigned short* new1l = (unsigned short*)carve((size_t)1 * 8 * 512 * 2);
    unsigned short* new2h = (unsigned short*)carve((size_t)4 * 8 * 512 * 2);
    unsigned short* new2l = (unsigned short*)carve((size_t)4 * 8 * 512 * 2);
    unsigned short* snd_p = (unsigned short*)carve((size_t)NE * 2);          // 1.6e6
    unsigned short* rcv_p = (unsigned short*)carve((size_t)NE * 2);          // 1.6e6
    int*            rs    = (int*)carve((size_t)(NN + 1) * 4);
    int*            cnt   = (int*)carve((size_t)NN * 4);
    int*            cur   = (int*)carve((size_t)NN * 4);
    float*          degf  = (float*)carve((size_t)NN * 4);
    int*            fn    = (int*)carve((size_t)(NB + 1) * 4);               // first node per edge block
    float*          csum  = (float*)carve(16);

    hipMemsetAsync(cnt, 0, (size_t)NN * 4, stream);
    hipMemsetAsync(csum, 0, 16, stream);
    hipMemsetAsync(fn, 0x7f, (size_t)(NB + 1) * 4, stream);
    k_hist<<<NE / 256, 256, 0, stream>>>(rcv, cnt);
    k_scan<<<1, 1024, 0, stream>>>(cnt, rs, cur, degf, fn);
    k_center<<<64, 256, 0, stream>>>(pos, csum);
    k_scatter<<<NE / 256, 256, 0, stream>>>(snd, rcv, cur, snd_p, rcv_p);
    k_prep_w<<<NSTEPS * 12 * 8, 64, 0, stream>>>(pe_w1, w1f_e, 12, 384, 0);
    k_prep_w<<<NSTEPS * 4 * 8, 64, 0, stream>>>(pe_w2, w2f_e, 4, 128, 0);
    k_prep_w<<<NSTEPS * 8 * 8, 64, 0, stream>>>(pn_w1, w1h_n, 8, 256, 0);
    k_prep_w<<<NSTEPS * 8 * 8, 64, 0, stream>>>(pn_w1, w1l_n, 8, 256, 1);
    k_prep_w<<<NSTEPS * 4 * 8, 64, 0, stream>>>(pn_w2, w2h_n, 4, 128, 0);
    k_prep_w<<<NSTEPS * 4 * 8, 64, 0, stream>>>(pn_w2, w2l_n, 4, 128, 1);
    k_prep_w<<<8, 64, 0, stream>>>(ee_w1, eew1h, 1, 9, 0);
    k_prep_w<<<8, 64, 0, stream>>>(ee_w1, eew1l, 1, 9, 1);
    k_prep_w<<<4 * 8, 64, 0, stream>>>(ee_w2, eew2h, 4, 128, 0);
    k_prep_w<<<4 * 8, 64, 0, stream>>>(ee_w2, eew2l, 4, 128, 1);
    k_prep_w<<<8, 64, 0, stream>>>(ne_w1, new1h, 1, 23, 0);
    k_prep_w<<<8, 64, 0, stream>>>(ne_w1, new1l, 1, 23, 1);
    k_prep_w<<<4 * 8, 64, 0, stream>>>(ne_w2, new2h, 4, 128, 0);
    k_prep_w<<<4 * 8, 64, 0, stream>>>(ne_w2, new2l, 4, 128, 1);

    k_node_enc_m<<<(NN + 127) / 128, 256, 0, stream>>>(pos, vel, rid, remb, degf, csum,
                                                       new1h, new1l, ne_b1, new2h, new2l, ne_b2, nlh, nll);
    k_edge_enc_m<<<NE / 128, 256, 0, stream>>>(pos, vel, rid, snd_p, rcv_p,
                                               eew1h, eew1l, ee_b1, eew2h, eew2l, ee_b2, el);
    for (int i = 0; i < NSTEPS; i++) {
        k_edge_step<<<NB, 256, 0, stream>>>(el, nlh, snd_p, rcv_p, rs, fn,
            w1f_e + (size_t)i * 12 * 8 * 512, pe_b1 + i * 128,
            w2f_e + (size_t)i * 4 * 8 * 512, pe_b2 + i * 128, agg);
        k_node_step_s<<<(NN + 63) / 64, 256, 0, stream>>>(nlh, nll, agg,
            w1h_n + (size_t)i * 8 * 8 * 512, w1l_n + (size_t)i * 8 * 8 * 512, pn_b1 + i * 128,
            w2h_n + (size_t)i * 4 * 8 * 512, w2l_n + (size_t)i * 4 * 8 * 512, pn_b2 + i * 128);
    }
    k_decode<<<NN / 16, 128, 0, stream>>>(nlh, nll, de_w1, de_b1, de_w2, de_b2, out);
}

// Round 10
// 3394.433 us; speedup vs baseline: 1.5105x; 1.5105x over previous
//
#include <hip/hip_runtime.h>
#include <hip/hip_bf16.h>

#define NN 50000
#define NE 800000
#define LDIM 128
#define NSTEPS 10
#define NB (NE / 128)   // 6250 edge-step blocks, node-aligned windows

typedef __hip_bfloat16 bf16;
typedef __bf16 bf8v __attribute__((ext_vector_type(8)));
typedef float f4v __attribute__((ext_vector_type(4)));
typedef unsigned short u16x8 __attribute__((ext_vector_type(8)));

__device__ inline float bflo(unsigned int u) {
    union { unsigned int i; float f; } x; x.i = u << 16; return x.f;
}
__device__ inline float bfhi(unsigned int u) {
    union { unsigned int i; float f; } x; x.i = u & 0xffff0000u; return x.f;
}
__device__ inline unsigned short f2bf(float f) {
    __hip_bfloat16 h = __float2bfloat16(f);
    unsigned short u; __builtin_memcpy(&u, &h, 2); return u;
}

// async global->LDS DMA, 16 B per lane. LDS dest is wave-uniform base + lane*16
// (linear); global src is per-lane. Drained by the vmcnt(0) the compiler emits
// at the next __syncthreads.
__device__ __forceinline__ void gl_lds16(const void* g, void* l) {
    __builtin_amdgcn_global_load_lds(
        (const __attribute__((address_space(1))) unsigned int*)g,
        (__attribute__((address_space(3))) unsigned int*)l, 16, 0, 0);
}

// ---------------- CSR build: histogram, scan, scatter (ushort permuted endpoints) ----------------

__global__ void k_hist(const int* __restrict__ rcv, int* __restrict__ cnt) {
    int i = blockIdx.x * 256 + threadIdx.x;
    if (i < NE) atomicAdd(&cnt[rcv[i]], 1);
}

__global__ __launch_bounds__(1024) void k_scan(
    const int* __restrict__ cnt, int* __restrict__ row_start,
    int* __restrict__ cur, float* __restrict__ degf, int* __restrict__ first_node) {
    __shared__ int part[1024];
    const int t = threadIdx.x;
    const int CH = (NN + 1023) / 1024;  // 49
    int b0 = t * CH, b1 = b0 + CH; if (b1 > NN) b1 = NN; if (b0 > NN) b0 = NN;
    int s = 0;
    for (int i = b0; i < b1; i++) s += cnt[i];
    part[t] = s;
    __syncthreads();
    for (int off = 1; off < 1024; off <<= 1) {
        int v = (t >= off) ? part[t - off] : 0;
        __syncthreads();
        part[t] += v;
        __syncthreads();
    }
    int run = part[t] - s;  // exclusive prefix
    for (int i = b0; i < b1; i++) {
        row_start[i] = run; cur[i] = run; degf[i] = (float)cnt[i];
        // node i's edge-step block = first-edge/128; min node per block
        if (run < NE) atomicMin(&first_node[run >> 7], i);
        run += cnt[i];
    }
    if (t == 1023) { row_start[NN] = part[1023]; first_node[NB] = NN; }
}

__global__ void k_scatter(const int* __restrict__ snd, const int* __restrict__ rcv,
                          int* __restrict__ cur,
                          unsigned short* __restrict__ snd_p, unsigned short* __restrict__ rcv_p) {
    int i = blockIdx.x * 256 + threadIdx.x;
    if (i < NE) {
        int r = rcv[i];
        int p = atomicAdd(&cur[r], 1);
        snd_p[p] = (unsigned short)snd[i];
        rcv_p[p] = (unsigned short)r;
    }
}

__global__ void k_center(const float* __restrict__ pos, float* __restrict__ csum) {
    __shared__ float s[3][256];
    float a = 0.f, b = 0.f, c = 0.f;
    for (int i = blockIdx.x * 256 + threadIdx.x; i < NN; i += gridDim.x * 256) {
        a += pos[3 * i]; b += pos[3 * i + 1]; c += pos[3 * i + 2];
    }
    int t = threadIdx.x;
    s[0][t] = a; s[1][t] = b; s[2][t] = c;
    __syncthreads();
    for (int off = 128; off > 0; off >>= 1) {
        if (t < off) {
            s[0][t] += s[0][t + off];
            s[1][t] += s[1][t + off];
            s[2][t] += s[2][t + off];
        }
        __syncthreads();
    }
    if (t == 0) {
        atomicAdd(&csum[0], s[0][0]);
        atomicAdd(&csum[1], s[1][0]);
        atomicAdd(&csum[2], s[2][0]);
    }
}

// ---------------- weight prep: fp32 -> bf16 B-frag order; lo=1 emits bf16(x - bf16(x)) ----------------

__global__ void k_prep_w(const float* __restrict__ w, unsigned short* __restrict__ wf,
                         int KT, int Ksrc, int lo) {
    int b = blockIdx.x;
    int s = b / (KT * 8), rem = b % (KT * 8);
    int kt = rem / 8, nt = rem % 8;
    int lane = threadIdx.x, col = lane & 15, quad = lane >> 4;
    const float* W = w + (size_t)s * Ksrc * 128;
    u16x8 o;
#pragma unroll
    for (int jj = 0; jj < 8; jj++) {
        int k = kt * 32 + quad * 8 + jj;
        float x = (k < Ksrc) ? W[(size_t)k * 128 + nt * 16 + col] : 0.f;
        unsigned short h = f2bf(x);
        if (lo) h = f2bf(x - bflo(h));
        o[jj] = h;
    }
    *(u16x8*)(wf + (((size_t)b) * 64 + lane) * 8) = o;
}

// ---------------- MFMA node encoder (split-precision): feat(23 pad 32, hi|lo) -> 128 -> 128 ----------------
// Output: node latent as bf16 hi/lo pair (nlh, nll).

__global__ __launch_bounds__(256) void k_node_enc_m(
    const float* __restrict__ pos, const float* __restrict__ vel,
    const int* __restrict__ rid, const float* __restrict__ remb,
    const float* __restrict__ degf, const float* __restrict__ csum,
    const unsigned short* __restrict__ w1h, const unsigned short* __restrict__ w1l,
    const float* __restrict__ b1,
    const unsigned short* __restrict__ w2h, const unsigned short* __restrict__ w2l,
    const float* __restrict__ b2,
    unsigned short* __restrict__ nlh, unsigned short* __restrict__ nll) {
    __shared__ __align__(16) unsigned short feat_s[32 * 72];   // [hi(32)|lo(32)|pad]
    __shared__ __align__(16) unsigned short hid_s[32 * 264];   // [hi(128)|lo(128)|pad]
    const int tid = threadIdx.x, wave = tid >> 6, lane = tid & 63;
    const int col = lane & 15, quad = lane >> 4;
    bf8v W1H[2], W1L[2], W2H[4][2], W2L[4][2];
#pragma unroll
    for (int t = 0; t < 2; t++) {
        W1H[t] = *(const bf8v*)(w1h + ((size_t)(2 * wave + t) * 64 + lane) * 8);
        W1L[t] = *(const bf8v*)(w1l + ((size_t)(2 * wave + t) * 64 + lane) * 8);
    }
#pragma unroll
    for (int kt = 0; kt < 4; kt++)
#pragma unroll
        for (int t = 0; t < 2; t++) {
            W2H[kt][t] = *(const bf8v*)(w2h + ((size_t)(kt * 8 + 2 * wave + t) * 64 + lane) * 8);
            W2L[kt][t] = *(const bf8v*)(w2l + ((size_t)(kt * 8 + 2 * wave + t) * 64 + lane) * 8);
        }
    float bias1[2], bias2[2];
#pragma unroll
    for (int t = 0; t < 2; t++) {
        bias1[t] = b1[(2 * wave + t) * 16 + col];
        bias2[t] = b2[(2 * wave + t) * 16 + col];
    }
    float cx = csum[0] * (1.0f / NN), cy = csum[1] * (1.0f / NN), cz = csum[2] * (1.0f / NN);
    uint4 z = {0u, 0u, 0u, 0u};
    for (int s2 = tid; s2 < 288; s2 += 256) *(uint4*)(feat_s + s2 * 8) = z;  // zero K-pad

    for (int it = 0; it < 4; it++) {
        const int base = blockIdx.x * 128 + it * 32;
        if (base >= NN) break;
        __syncthreads();
        if (tid < 32) {
            int n = base + tid; if (n > NN - 1) n = NN - 1;
            float v[23];
            v[0] = vel[3 * n]; v[1] = vel[3 * n + 1]; v[2] = vel[3 * n + 2];
            v[3] = pos[3 * n] - cx; v[4] = pos[3 * n + 1] - cy; v[5] = pos[3 * n + 2] - cz;
            v[6] = degf[n];
            int rb = rid[n] * 16;
#pragma unroll
            for (int k = 0; k < 16; k++) v[7 + k] = remb[rb + k];
            unsigned short* f = feat_s + tid * 72;
#pragma unroll
            for (int k = 0; k < 23; k++) {
                unsigned short h = f2bf(v[k]);
                f[k] = h; f[32 + k] = f2bf(v[k] - bflo(h));
            }
        }
        __syncthreads();
        f4v acc[2][2];
#pragma unroll
        for (int mt = 0; mt < 2; mt++)
#pragma unroll
            for (int t = 0; t < 2; t++) acc[mt][t] = (f4v){0.f, 0.f, 0.f, 0.f};
        {
            bf8v a0h = *(const bf8v*)(feat_s + col * 72 + quad * 8);
            bf8v a1h = *(const bf8v*)(feat_s + (16 + col) * 72 + quad * 8);
            bf8v a0l = *(const bf8v*)(feat_s + col * 72 + 32 + quad * 8);
            bf8v a1l = *(const bf8v*)(feat_s + (16 + col) * 72 + 32 + quad * 8);
#pragma unroll
            for (int t = 0; t < 2; t++) {
                acc[0][t] = __builtin_amdgcn_mfma_f32_16x16x32_bf16(a0h, W1H[t], acc[0][t], 0, 0, 0);
                acc[1][t] = __builtin_amdgcn_mfma_f32_16x16x32_bf16(a1h, W1H[t], acc[1][t], 0, 0, 0);
                acc[0][t] = __builtin_amdgcn_mfma_f32_16x16x32_bf16(a0l, W1H[t], acc[0][t], 0, 0, 0);
                acc[1][t] = __builtin_amdgcn_mfma_f32_16x16x32_bf16(a1l, W1H[t], acc[1][t], 0, 0, 0);
                acc[0][t] = __builtin_amdgcn_mfma_f32_16x16x32_bf16(a0h, W1L[t], acc[0][t], 0, 0, 0);
                acc[1][t] = __builtin_amdgcn_mfma_f32_16x16x32_bf16(a1h, W1L[t], acc[1][t], 0, 0, 0);
            }
        }
#pragma unroll
        for (int mt = 0; mt < 2; mt++)
#pragma unroll
            for (int t = 0; t < 2; t++) {
                const int nc = (2 * wave + t) * 16 + col;
#pragma unroll
                for (int r = 0; r < 4; r++) {
                    float h = fmaxf(acc[mt][t][r] + bias1[t], 0.f);
                    unsigned short hh = f2bf(h);
                    hid_s[(mt * 16 + quad * 4 + r) * 264 + nc] = hh;
                    hid_s[(mt * 16 + quad * 4 + r) * 264 + 128 + nc] = f2bf(h - bflo(hh));
                }
            }
        __syncthreads();
#pragma unroll
        for (int mt = 0; mt < 2; mt++)
#pragma unroll
            for (int t = 0; t < 2; t++) acc[mt][t] = (f4v){0.f, 0.f, 0.f, 0.f};
#pragma unroll
        for (int kt = 0; kt < 8; kt++) {
            int w = kt & 3;
            bf8v a0 = *(const bf8v*)(hid_s + col * 264 + kt * 32 + quad * 8);
            bf8v a1 = *(const bf8v*)(hid_s + (16 + col) * 264 + kt * 32 + quad * 8);
#pragma unroll
            for (int t = 0; t < 2; t++) {
                acc[0][t] = __builtin_amdgcn_mfma_f32_16x16x32_bf16(a0, W2H[w][t], acc[0][t], 0, 0, 0);
                acc[1][t] = __builtin_amdgcn_mfma_f32_16x16x32_bf16(a1, W2H[w][t], acc[1][t], 0, 0, 0);
            }
        }
#pragma unroll
        for (int kt = 0; kt < 4; kt++) {
            bf8v a0 = *(const bf8v*)(hid_s + col * 264 + kt * 32 + quad * 8);
            bf8v a1 = *(const bf8v*)(hid_s + (16 + col) * 264 + kt * 32 + quad * 8);
#pragma unroll
            for (int t = 0; t < 2; t++) {
                acc[0][t] = __builtin_amdgcn_mfma_f32_16x16x32_bf16(a0, W2L[kt][t], acc[0][t], 0, 0, 0);
                acc[1][t] = __builtin_amdgcn_mfma_f32_16x16x32_bf16(a1, W2L[kt][t], acc[1][t], 0, 0, 0);
            }
        }
        __syncthreads();  // all hid reads done; overwrite with output hi/lo
#pragma unroll
        for (int mt = 0; mt < 2; mt++)
#pragma unroll
            for (int t = 0; t < 2; t++) {
                const int nc = (2 * wave + t) * 16 + col;
#pragma unroll
                for (int r = 0; r < 4; r++) {
                    const int row = mt * 16 + quad * 4 + r;
                    float v = acc[mt][t][r] + bias2[t];
                    unsigned short hh = f2bf(v);
                    hid_s[row * 264 + nc] = hh;
                    hid_s[row * 264 + 128 + nc] = f2bf(v - bflo(hh));
                }
            }
        __syncthreads();
#pragma unroll
        for (int p = 0; p < 2; p++) {
            int s2 = p * 256 + tid, e = s2 >> 4, c16 = s2 & 15;
            if (base + e < NN) {
                *(uint4*)(nlh + (size_t)(base + e) * 128 + c16 * 8) =
                    *(const uint4*)(hid_s + e * 264 + c16 * 8);
                *(uint4*)(nll + (size_t)(base + e) * 128 + c16 * 8) =
                    *(const uint4*)(hid_s + e * 264 + 128 + c16 * 8);
            }
        }
    }
}

// ---------------- MFMA edge encoder (split-precision): feat(9 pad 32, hi|lo) -> 128 -> 128 ----------------

__global__ __launch_bounds__(256) void k_edge_enc_m(
    const float* __restrict__ pos, const float* __restrict__ vel,
    const int* __restrict__ rid,
    const unsigned short* __restrict__ snd, const unsigned short* __restrict__ rcv,
    const unsigned short* __restrict__ w1h, const unsigned short* __restrict__ w1l,
    const float* __restrict__ b1,
    const unsigned short* __restrict__ w2h, const unsigned short* __restrict__ w2l,
    const float* __restrict__ b2,
    unsigned short* __restrict__ el) {
    __shared__ __align__(16) unsigned short feat_s[32 * 72];
    __shared__ __align__(16) unsigned short hid_s[32 * 264];
    const int tid = threadIdx.x, wave = tid >> 6, lane = tid & 63;
    const int col = lane & 15, quad = lane >> 4;
    bf8v W1H[2], W1L[2], W2H[4][2], W2L[4][2];
#pragma unroll
    for (int t = 0; t < 2; t++) {
        W1H[t] = *(const bf8v*)(w1h + ((size_t)(2 * wave + t) * 64 + lane) * 8);
        W1L[t] = *(const bf8v*)(w1l + ((size_t)(2 * wave + t) * 64 + lane) * 8);
    }
#pragma unroll
    for (int kt = 0; kt < 4; kt++)
#pragma unroll
        for (int t = 0; t < 2; t++) {
            W2H[kt][t] = *(const bf8v*)(w2h + ((size_t)(kt * 8 + 2 * wave + t) * 64 + lane) * 8);
            W2L[kt][t] = *(const bf8v*)(w2l + ((size_t)(kt * 8 + 2 * wave + t) * 64 + lane) * 8);
        }
    float bias1[2], bias2[2];
#pragma unroll
    for (int t = 0; t < 2; t++) {
        bias1[t] = b1[(2 * wave + t) * 16 + col];
        bias2[t] = b2[(2 * wave + t) * 16 + col];
    }
    uint4 z = {0u, 0u, 0u, 0u};
    for (int s2 = tid; s2 < 288; s2 += 256) *(uint4*)(feat_s + s2 * 8) = z;

    for (int it = 0; it < 4; it++) {
        const int base = blockIdx.x * 128 + it * 32;
        __syncthreads();
        if (tid < 32) {
            int e = base + tid;
            int s = snd[e], r = rcv[e];
            float v[9];
            v[0] = pos[3 * s] - pos[3 * r]; v[1] = pos[3 * s + 1] - pos[3 * r + 1]; v[2] = pos[3 * s + 2] - pos[3 * r + 2];
            v[3] = vel[3 * s] - vel[3 * r]; v[4] = vel[3 * s + 1] - vel[3 * r + 1]; v[5] = vel[3 * s + 2] - vel[3 * r + 2];
            float sq = v[0] * v[0] + v[1] * v[1] + v[2] * v[2];
            v[6] = sqrtf(sq); v[7] = sq;
            v[8] = (rid[s] == rid[r]) ? 1.f : 0.f;
            unsigned short* f = feat_s + tid * 72;
#pragma unroll
            for (int k = 0; k < 9; k++) {
                unsigned short h = f2bf(v[k]);
                f[k] = h; f[32 + k] = f2bf(v[k] - bflo(h));
            }
        }
        __syncthreads();
        f4v acc[2][2];
#pragma unroll
        for (int mt = 0; mt < 2; mt++)
#pragma unroll
            for (int t = 0; t < 2; t++) acc[mt][t] = (f4v){0.f, 0.f, 0.f, 0.f};
        {
            bf8v a0h = *(const bf8v*)(feat_s + col * 72 + quad * 8);
            bf8v a1h = *(const bf8v*)(feat_s + (16 + col) * 72 + quad * 8);
            bf8v a0l = *(const bf8v*)(feat_s + col * 72 + 32 + quad * 8);
            bf8v a1l = *(const bf8v*)(feat_s + (16 + col) * 72 + 32 + quad * 8);
#pragma unroll
            for (int t = 0; t < 2; t++) {
                acc[0][t] = __builtin_amdgcn_mfma_f32_16x16x32_bf16(a0h, W1H[t], acc[0][t], 0, 0, 0);
                acc[1][t] = __builtin_amdgcn_mfma_f32_16x16x32_bf16(a1h, W1H[t], acc[1][t], 0, 0, 0);
                acc[0][t] = __builtin_amdgcn_mfma_f32_16x16x32_bf16(a0l, W1H[t], acc[0][t], 0, 0, 0);
                acc[1][t] = __builtin_amdgcn_mfma_f32_16x16x32_bf16(a1l, W1H[t], acc[1][t], 0, 0, 0);
                acc[0][t] = __builtin_amdgcn_mfma_f32_16x16x32_bf16(a0h, W1L[t], acc[0][t], 0, 0, 0);
                acc[1][t] = __builtin_amdgcn_mfma_f32_16x16x32_bf16(a1h, W1L[t], acc[1][t], 0, 0, 0);
            }
        }
#pragma unroll
        for (int mt = 0; mt < 2; mt++)
#pragma unroll
            for (int t = 0; t < 2; t++) {
                const int nc = (2 * wave + t) * 16 + col;
#pragma unroll
                for (int r = 0; r < 4; r++) {
                    float h = fmaxf(acc[mt][t][r] + bias1[t], 0.f);
                    unsigned short hh = f2bf(h);
                    hid_s[(mt * 16 + quad * 4 + r) * 264 + nc] = hh;
                    hid_s[(mt * 16 + quad * 4 + r) * 264 + 128 + nc] = f2bf(h - bflo(hh));
                }
            }
        __syncthreads();
#pragma unroll
        for (int mt = 0; mt < 2; mt++)
#pragma unroll
            for (int t = 0; t < 2; t++) acc[mt][t] = (f4v){0.f, 0.f, 0.f, 0.f};
#pragma unroll
        for (int kt = 0; kt < 8; kt++) {
            int w = kt & 3;
            bf8v a0 = *(const bf8v*)(hid_s + col * 264 + kt * 32 + quad * 8);
            bf8v a1 = *(const bf8v*)(hid_s + (16 + col) * 264 + kt * 32 + quad * 8);
#pragma unroll
            for (int t = 0; t < 2; t++) {
                acc[0][t] = __builtin_amdgcn_mfma_f32_16x16x32_bf16(a0, W2H[w][t], acc[0][t], 0, 0, 0);
                acc[1][t] = __builtin_amdgcn_mfma_f32_16x16x32_bf16(a1, W2H[w][t], acc[1][t], 0, 0, 0);
            }
        }
#pragma unroll
        for (int kt = 0; kt < 4; kt++) {
            bf8v a0 = *(const bf8v*)(hid_s + col * 264 + kt * 32 + quad * 8);
            bf8v a1 = *(const bf8v*)(hid_s + (16 + col) * 264 + kt * 32 + quad * 8);
#pragma unroll
            for (int t = 0; t < 2; t++) {
                acc[0][t] = __builtin_amdgcn_mfma_f32_16x16x32_bf16(a0, W2L[kt][t], acc[0][t], 0, 0, 0);
                acc[1][t] = __builtin_amdgcn_mfma_f32_16x16x32_bf16(a1, W2L[kt][t], acc[1][t], 0, 0, 0);
            }
        }
        __syncthreads();
#pragma unroll
        for (int mt = 0; mt < 2; mt++)
#pragma unroll
            for (int t = 0; t < 2; t++) {
                const int nc = (2 * wave + t) * 16 + col;
#pragma unroll
                for (int r = 0; r < 4; r++)
                    hid_s[(mt * 16 + quad * 4 + r) * 264 + nc] = f2bf(acc[mt][t][r] + bias2[t]);
            }
        __syncthreads();
#pragma unroll
        for (int p = 0; p < 2; p++) {
            int s2 = p * 256 + tid, e = s2 >> 4, c16 = s2 & 15;
            *(uint4*)(el + (size_t)(base + e) * 128 + c16 * 8) =
                *(const uint4*)(hid_s + e * 264 + c16 * 8);
        }
    }
}

// ---------------- MFMA edge processor step (node-aligned blocks, fused aggregation) ----------------
// v11 = v10's mapping (node-aligned blocks, zero-atomic fused agg, k_agg-exact
// summation order) with the WALK reimplemented in k_agg's parallel form on
// wave 0: ballot-based segment boundaries (uniform bit-scan), then per segment
// each lane (sub=lane>>4, c16=lane&15) reads rows of matching edge-phase
// (j === sub mod 4, phase-aligned across tiles via cntn) as independent
// pipelined uint4 LDS reads into sg[8]; flush = shfl_xor(16)+shfl_xor(32)
// tree, sub==0 lanes write u16x8. v10's 128-thread serial scalar walk was
// ~3800 dependent-latency cycles/tile (438 us); this is ~300.

__global__ __launch_bounds__(256) void k_edge_step(
    unsigned short* __restrict__ el, const unsigned short* __restrict__ nlh,
    const unsigned short* __restrict__ snd, const unsigned short* __restrict__ rcv,
    const int* __restrict__ rs, const int* __restrict__ first_node,
    const unsigned short* __restrict__ w1f, const float* __restrict__ b1,
    const unsigned short* __restrict__ w2f, const float* __restrict__ b2,
    unsigned short* __restrict__ agg) {
    __shared__ __align__(1024) unsigned short stage_s[2][3][32][128];  // 48 KB
    __shared__ __align__(16) unsigned short hid_s[32 * 136];           // 8.5 KB
    __shared__ int rcv_s[32];
    const int tid = threadIdx.x;
    const int wave = tid >> 6, lane = tid & 63;
    const int col = lane & 15, quad = lane >> 4;
    const int erow = tid >> 4, c16 = tid & 15;

    const int n0 = first_node[blockIdx.x];
    const int n1 = first_node[blockIdx.x + 1];
    const int st = rs[n0], en = rs[n1];
    const int nt = (en - st + 31) >> 5;

    bf8v W1[12][2], W2[4][2];
#pragma unroll
    for (int kt = 0; kt < 12; kt++)
#pragma unroll
        for (int t = 0; t < 2; t++)
            W1[kt][t] = *(const bf8v*)(w1f + ((size_t)(kt * 8 + 2 * wave + t) * 64 + lane) * 8);
#pragma unroll
    for (int kt = 0; kt < 4; kt++)
#pragma unroll
        for (int t = 0; t < 2; t++)
            W2[kt][t] = *(const bf8v*)(w2f + ((size_t)(kt * 8 + 2 * wave + t) * 64 + lane) * 8);
    float bias1[2], bias2[2];
#pragma unroll
    for (int t = 0; t < 2; t++) {
        bias1[t] = b1[(2 * wave + t) * 16 + col];
        bias2[t] = b2[(2 * wave + t) * 16 + col];
    }

    // staging geometry: wave stages rows [wave*8, wave*8+8) of each stream.
    // lane covers row = wave*8 + i*4 + (lane>>4), 16 B at byte (lane&15)*16.
    // Global source pre-swizzled (byte ^= (row&7)<<4); LDS dest linear.
    const int srow0 = wave * 8 + (lane >> 4);
    const int srow1 = srow0 + 4;
    const int skb = (lane & 15) * 16;
    const int soff0 = skb ^ ((srow0 & 7) << 4);
    const int soff1 = skb ^ ((srow1 & 7) << 4);
    const char* elc = (const char*)el;
    const char* nlc = (const char*)nlh;

    auto clampe = [&](int e) { return e < en ? e : en - 1; };
    auto issue = [&](int t, int b, int si0, int si1, int ri0, int ri1) {
        char* s0 = (char*)&stage_s[b][0][wave * 8][0];
        char* s1 = (char*)&stage_s[b][1][wave * 8][0];
        char* s2 = (char*)&stage_s[b][2][wave * 8][0];
        const int gb = st + t * 32;
        gl_lds16(elc + (size_t)clampe(gb + srow0) * 256 + soff0, s0);
        gl_lds16(elc + (size_t)clampe(gb + srow1) * 256 + soff1, s0 + 1024);
        gl_lds16(nlc + (size_t)si0 * 256 + soff0, s1);
        gl_lds16(nlc + (size_t)si1 * 256 + soff1, s1 + 1024);
        gl_lds16(nlc + (size_t)ri0 * 256 + soff0, s2);
        gl_lds16(nlc + (size_t)ri1 * 256 + soff1, s2 + 1024);
    };

    // prologue: issue tile 0; preload gather indices for tile 1
    {
        int si0 = snd[clampe(st + srow0)], si1 = snd[clampe(st + srow1)];
        int ri0 = rcv[clampe(st + srow0)], ri1 = rcv[clampe(st + srow1)];
        issue(0, 0, si0, si1, ri0, ri1);
    }
    int nsi0 = 0, nsi1 = 0, nri0 = 0, nri1 = 0;
    if (nt > 1) {
        nsi0 = snd[clampe(st + 32 + srow0)]; nsi1 = snd[clampe(st + 32 + srow1)];
        nri0 = rcv[clampe(st + 32 + srow0)]; nri1 = rcv[clampe(st + 32 + srow1)];
    }

    // fused-agg carry state (wave 0 only; sub = quad, chan group = col).
    // sg[k]: partial for edge-phase `quad`, channels col*8+k (k_agg layout).
    float sg[8];
#pragma unroll
    for (int k = 0; k < 8; k++) sg[k] = 0.f;
    int curn = n0, cntn = 0;

    auto flushseg = [&](int nd) {
#pragma unroll
        for (int k = 0; k < 8; k++) {
            sg[k] += __shfl_xor(sg[k], 16);
            sg[k] += __shfl_xor(sg[k], 32);
        }
        if (quad == 0) {
            u16x8 o;
#pragma unroll
            for (int k = 0; k < 8; k++) o[k] = f2bf(sg[k]);
            *(u16x8*)(agg + (size_t)nd * 128 + col * 8) = o;
        }
    };

    for (int it = 0; it < nt; it++) {
        const int cur = it & 1, nxt = cur ^ 1;
        const int base = st + it * 32;
        __syncthreads();  // B0: cur staged+visible; prev tile's hid_s/rcv_s reads done
        if (tid < 32) rcv_s[tid] = rcv[clampe(base + tid)];
        if (it + 1 < nt) {
            issue(it + 1, nxt, nsi0, nsi1, nri0, nri1);  // drains at B1 (under L1)
            if (it + 2 < nt) {
                int gb = st + (it + 2) * 32;
                nsi0 = snd[clampe(gb + srow0)]; nsi1 = snd[clampe(gb + srow1)];
                nri0 = rcv[clampe(gb + srow0)]; nri1 = rcv[clampe(gb + srow1)];
            }
        }

        // ---- layer 1: K=384 over [el|snd|rcv] buffers (swizzled reads) ----
        f4v acc[2][2];
#pragma unroll
        for (int mt = 0; mt < 2; mt++)
#pragma unroll
            for (int t = 0; t < 2; t++) acc[mt][t] = (f4v){0.f, 0.f, 0.f, 0.f};
        const int sw = (col & 7) << 4;
#pragma unroll
        for (int kt = 0; kt < 12; kt++) {
            const char* sb = (const char*)&stage_s[cur][kt >> 2][0][0];
            const int kb = (kt & 3) * 64 + quad * 16;
            bf8v a0 = *(const bf8v*)(sb + col * 256 + (kb ^ sw));
            bf8v a1 = *(const bf8v*)(sb + (16 + col) * 256 + (kb ^ sw));
            acc[0][0] = __builtin_amdgcn_mfma_f32_16x16x32_bf16(a0, W1[kt][0], acc[0][0], 0, 0, 0);
            acc[0][1] = __builtin_amdgcn_mfma_f32_16x16x32_bf16(a0, W1[kt][1], acc[0][1], 0, 0, 0);
            acc[1][0] = __builtin_amdgcn_mfma_f32_16x16x32_bf16(a1, W1[kt][0], acc[1][0], 0, 0, 0);
            acc[1][1] = __builtin_amdgcn_mfma_f32_16x16x32_bf16(a1, W1[kt][1], acc[1][1], 0, 0, 0);
        }
#pragma unroll
        for (int mt = 0; mt < 2; mt++)
#pragma unroll
            for (int t = 0; t < 2; t++) {
                const int nc = (2 * wave + t) * 16 + col;
#pragma unroll
                for (int r = 0; r < 4; r++) {
                    float v = fmaxf(acc[mt][t][r] + bias1[t], 0.f);
                    hid_s[(mt * 16 + quad * 4 + r) * 136 + nc] = f2bf(v);
                }
            }
        __syncthreads();  // B1: hid visible; prefetch vmcnt drained here

        // ---- layer 2 ----
#pragma unroll
        for (int mt = 0; mt < 2; mt++)
#pragma unroll
            for (int t = 0; t < 2; t++) acc[mt][t] = (f4v){0.f, 0.f, 0.f, 0.f};
#pragma unroll
        for (int kt = 0; kt < 4; kt++) {
            bf8v a0 = *(const bf8v*)(hid_s + col * 136 + kt * 32 + quad * 8);
            bf8v a1 = *(const bf8v*)(hid_s + (16 + col) * 136 + kt * 32 + quad * 8);
            acc[0][0] = __builtin_amdgcn_mfma_f32_16x16x32_bf16(a0, W2[kt][0], acc[0][0], 0, 0, 0);
            acc[0][1] = __builtin_amdgcn_mfma_f32_16x16x32_bf16(a0, W2[kt][1], acc[0][1], 0, 0, 0);
            acc[1][0] = __builtin_amdgcn_mfma_f32_16x16x32_bf16(a1, W2[kt][0], acc[1][0], 0, 0, 0);
            acc[1][1] = __builtin_amdgcn_mfma_f32_16x16x32_bf16(a1, W2[kt][1], acc[1][1], 0, 0, 0);
        }
        __syncthreads();  // B2: all hid reads done; reuse hid_s for output

        // ---- epilogue: residual (cur el buffer, swizzled) + bias2 -> hid_s ----
#pragma unroll
        for (int mt = 0; mt < 2; mt++)
#pragma unroll
            for (int t = 0; t < 2; t++) {
                const int nc = (2 * wave + t) * 16 + col;
#pragma unroll
                for (int r = 0; r < 4; r++) {
                    const int row = mt * 16 + quad * 4 + r;
                    float res = bflo((unsigned int)stage_s[cur][0][row][nc ^ ((row & 7) << 3)]);
                    float v = acc[mt][t][r] + bias2[t] + res;
                    hid_s[row * 136 + nc] = f2bf(v);
                }
            }
        __syncthreads();  // B3: out staged

        // global el store (guarded)
#pragma unroll
        for (int p = 0; p < 2; p++) {
            int e = p * 16 + erow;
            if (base + e < en)
                *(uint4*)(el + (size_t)(base + e) * 128 + c16 * 8) =
                    *(const uint4*)(hid_s + e * 136 + c16 * 8);
        }

        // ---- fused aggregation: wave 0, ballot-segmented k_agg-parallel ----
        if (wave == 0) {
            int rows = en - base; if (rows > 32) rows = 32;
            const int rl = lane & 31;
            int nd_rl = rcv_s[rl];
            int prev_rl = (rl == 0) ? curn : rcv_s[rl - 1];
            unsigned long long bm =
                __ballot(rl < rows && nd_rl != prev_rl) & 0xffffffffull;
            int segstart = 0;
            while (segstart < rows) {
                if (bm & (1ull << segstart)) {  // node boundary: flush carry
                    flushseg(curn);
                    int nd = rcv_s[segstart];
                    if (quad == 0) {
                        u16x8 zz = (u16x8)(unsigned short)0;
                        for (int m = curn + 1; m < nd; m++)
                            *(u16x8*)(agg + (size_t)m * 128 + col * 8) = zz;
                    }
                    curn = nd; cntn = 0;
#pragma unroll
                    for (int k = 0; k < 8; k++) sg[k] = 0.f;
                }
                unsigned long long hi = bm & (~0ull << (segstart + 1));
                int segend = hi ? (int)(__ffsll((unsigned long long)hi) - 1) : rows;
                if (segend > rows) segend = rows;
                // phase-aligned rows: edge j = cntn + (rr - segstart); pick j === quad (mod 4)
                for (int rr = segstart + ((quad - cntn) & 3); rr < segend; rr += 4) {
                    uint4 v = *(const uint4*)(hid_s + rr * 136 + col * 8);
                    sg[0] += bflo(v.x); sg[1] += bfhi(v.x);
                    sg[2] += bflo(v.y); sg[3] += bfhi(v.y);
                    sg[4] += bflo(v.z); sg[5] += bfhi(v.z);
                    sg[6] += bflo(v.w); sg[7] += bfhi(v.w);
                }
                cntn += segend - segstart;
                segstart = segend;
            }
        }
    }
    // flush final carry + trailing zero-degree nodes
    if (wave == 0) {
        flushseg(curn);
        if (quad == 0) {
            u16x8 zz = (u16x8)(unsigned short)0;
            for (int m = curn + 1; m < n1; m++)
                *(u16x8*)(agg + (size_t)m * 128 + col * 8) = zz;
        }
    }
}

// ---------------- node step: [nl_hi|nl_lo|agg_hi] (K=384) -> 128 -> 128, residual, hi/lo out ----------------
// 64 nodes/block (2 tiles of 32), grid 782. agg produced by fused edge-step walk.

__global__ __launch_bounds__(256) void k_node_step_s(
    unsigned short* __restrict__ nlh, unsigned short* __restrict__ nll,
    const unsigned short* __restrict__ agg,
    const unsigned short* __restrict__ w1h, const unsigned short* __restrict__ w1l,
    const float* __restrict__ b1,
    const unsigned short* __restrict__ w2h, const unsigned short* __restrict__ w2l,
    const float* __restrict__ b2) {
    __shared__ __align__(16) unsigned short a_s[32 * 392];
    __shared__ __align__(16) unsigned short hid_s[32 * 264];
    const int tid = threadIdx.x, wave = tid >> 6, lane = tid & 63;
    const int col = lane & 15, quad = lane >> 4;
    bf8v W1H[8][2], W1L[8][2], W2H[4][2], W2L[4][2];
#pragma unroll
    for (int kt = 0; kt < 8; kt++)
#pragma unroll
        for (int t = 0; t < 2; t++) {
            W1H[kt][t] = *(const bf8v*)(w1h + ((size_t)(kt * 8 + 2 * wave + t) * 64 + lane) * 8);
            W1L[kt][t] = *(const bf8v*)(w1l + ((size_t)(kt * 8 + 2 * wave + t) * 64 + lane) * 8);
        }
#pragma unroll
    for (int kt = 0; kt < 4; kt++)
#pragma unroll
        for (int t = 0; t < 2; t++) {
            W2H[kt][t] = *(const bf8v*)(w2h + ((size_t)(kt * 8 + 2 * wave + t) * 64 + lane) * 8);
            W2L[kt][t] = *(const bf8v*)(w2l + ((size_t)(kt * 8 + 2 * wave + t) * 64 + lane) * 8);
        }
    float bias1[2], bias2[2];
#pragma unroll
    for (int t = 0; t < 2; t++) {
        bias1[t] = b1[(2 * wave + t) * 16 + col];
        bias2[t] = b2[(2 * wave + t) * 16 + col];
    }
    for (int it = 0; it < 2; it++) {
        const int base = blockIdx.x * 64 + it * 32;
        if (base >= NN) break;
        __syncthreads();  // prev-iter a_s/hid_s reads done
        // stage: direct uint4 copies (hi | lo | agg)
#pragma unroll
        for (int p = 0; p < 2; p++) {
            int e = p * 16 + (tid >> 4), c16 = tid & 15;
            int n = base + e; if (n > NN - 1) n = NN - 1;
            *(uint4*)(a_s + e * 392 + c16 * 8) =
                *(const uint4*)(nlh + (size_t)n * 128 + c16 * 8);
            *(uint4*)(a_s + e * 392 + 128 + c16 * 8) =
                *(const uint4*)(nll + (size_t)n * 128 + c16 * 8);
            *(uint4*)(a_s + e * 392 + 256 + c16 * 8) =
                *(const uint4*)(agg + (size_t)n * 128 + c16 * 8);
        }
        __syncthreads();

        f4v acc[2][2];
#pragma unroll
        for (int mt = 0; mt < 2; mt++)
#pragma unroll
            for (int t = 0; t < 2; t++) acc[mt][t] = (f4v){0.f, 0.f, 0.f, 0.f};
        // layer1: nl hi+lo vs W1H[0..3], agg vs W1H[4..7], nl hi vs W1L[0..3], agg vs W1L[4..7]
#pragma unroll
        for (int kt = 0; kt < 8; kt++) {
            bf8v a0 = *(const bf8v*)(a_s + col * 392 + kt * 32 + quad * 8);
            bf8v a1 = *(const bf8v*)(a_s + (16 + col) * 392 + kt * 32 + quad * 8);
#pragma unroll
            for (int t = 0; t < 2; t++) {
                acc[0][t] = __builtin_amdgcn_mfma_f32_16x16x32_bf16(a0, W1H[kt & 3][t], acc[0][t], 0, 0, 0);
                acc[1][t] = __builtin_amdgcn_mfma_f32_16x16x32_bf16(a1, W1H[kt & 3][t], acc[1][t], 0, 0, 0);
            }
        }
#pragma unroll
        for (int kt = 0; kt < 4; kt++) {
            bf8v a0 = *(const bf8v*)(a_s + col * 392 + 256 + kt * 32 + quad * 8);
            bf8v a1 = *(const bf8v*)(a_s + (16 + col) * 392 + 256 + kt * 32 + quad * 8);
#pragma unroll
            for (int t = 0; t < 2; t++) {
                acc[0][t] = __builtin_amdgcn_mfma_f32_16x16x32_bf16(a0, W1H[4 + kt][t], acc[0][t], 0, 0, 0);
                acc[1][t] = __builtin_amdgcn_mfma_f32_16x16x32_bf16(a1, W1H[4 + kt][t], acc[1][t], 0, 0, 0);
            }
        }
#pragma unroll
        for (int kt = 0; kt < 4; kt++) {
            bf8v a0 = *(const bf8v*)(a_s + col * 392 + kt * 32 + quad * 8);
            bf8v a1 = *(const bf8v*)(a_s + (16 + col) * 392 + kt * 32 + quad * 8);
#pragma unroll
            for (int t = 0; t < 2; t++) {
                acc[0][t] = __builtin_amdgcn_mfma_f32_16x16x32_bf16(a0, W1L[kt][t], acc[0][t], 0, 0, 0);
                acc[1][t] = __builtin_amdgcn_mfma_f32_16x16x32_bf16(a1, W1L[kt][t], acc[1][t], 0, 0, 0);
            }
        }
#pragma unroll
        for (int kt = 0; kt < 4; kt++) {
            bf8v a0 = *(const bf8v*)(a_s + col * 392 + 256 + kt * 32 + quad * 8);
            bf8v a1 = *(const bf8v*)(a_s + (16 + col) * 392 + 256 + kt * 32 + quad * 8);
#pragma unroll
            for (int t = 0; t < 2; t++) {
                acc[0][t] = __builtin_amdgcn_mfma_f32_16x16x32_bf16(a0, W1L[4 + kt][t], acc[0][t], 0, 0, 0);
                acc[1][t] = __builtin_amdgcn_mfma_f32_16x16x32_bf16(a1, W1L[4 + kt][t], acc[1][t], 0, 0, 0);
            }
        }
#pragma unroll
        for (int mt = 0; mt < 2; mt++)
#pragma unroll
            for (int t = 0; t < 2; t++) {
                const int nc = (2 * wave + t) * 16 + col;
#pragma unroll
                for (int r = 0; r < 4; r++) {
                    float h = fmaxf(acc[mt][t][r] + bias1[t], 0.f);
                    unsigned short hh = f2bf(h);
                    hid_s[(mt * 16 + quad * 4 + r) * 264 + nc] = hh;
                    hid_s[(mt * 16 + quad * 4 + r) * 264 + 128 + nc] = f2bf(h - bflo(hh));
                }
            }
        __syncthreads();
#pragma unroll
        for (int mt = 0; mt < 2; mt++)
#pragma unroll
            for (int t = 0; t < 2; t++) acc[mt][t] = (f4v){0.f, 0.f, 0.f, 0.f};
#pragma unroll
        for (int kt = 0; kt < 8; kt++) {
            int w = kt & 3;
            bf8v a0 = *(const bf8v*)(hid_s + col * 264 + kt * 32 + quad * 8);
            bf8v a1 = *(const bf8v*)(hid_s + (16 + col) * 264 + kt * 32 + quad * 8);
#pragma unroll
            for (int t = 0; t < 2; t++) {
                acc[0][t] = __builtin_amdgcn_mfma_f32_16x16x32_bf16(a0, W2H[w][t], acc[0][t], 0, 0, 0);
                acc[1][t] = __builtin_amdgcn_mfma_f32_16x16x32_bf16(a1, W2H[w][t], acc[1][t], 0, 0, 0);
            }
        }
#pragma unroll
        for (int kt = 0; kt < 4; kt++) {
            bf8v a0 = *(const bf8v*)(hid_s + col * 264 + kt * 32 + quad * 8);
            bf8v a1 = *(const bf8v*)(hid_s + (16 + col) * 264 + kt * 32 + quad * 8);
#pragma unroll
            for (int t = 0; t < 2; t++) {
                acc[0][t] = __builtin_amdgcn_mfma_f32_16x16x32_bf16(a0, W2L[kt][t], acc[0][t], 0, 0, 0);
                acc[1][t] = __builtin_amdgcn_mfma_f32_16x16x32_bf16(a1, W2L[kt][t], acc[1][t], 0, 0, 0);
            }
        }
        __syncthreads();  // all L2 reads of hid done; reuse hid_s for output staging
#pragma unroll
        for (int mt = 0; mt < 2; mt++)
#pragma unroll
            for (int t = 0; t < 2; t++) {
                const int nc = (2 * wave + t) * 16 + col;
#pragma unroll
                for (int r = 0; r < 4; r++) {
                    const int row = mt * 16 + quad * 4 + r;
                    // residual from a_s hi+lo (still intact)
                    float res = bflo((unsigned int)a_s[row * 392 + nc]) +
                                bflo((unsigned int)a_s[row * 392 + 128 + nc]);
                    float v = acc[mt][t][r] + bias2[t] + res;
                    unsigned short hh = f2bf(v);
                    hid_s[row * 264 + nc] = hh;
                    hid_s[row * 264 + 128 + nc] = f2bf(v - bflo(hh));
                }
            }
        __syncthreads();  // out staged
#pragma unroll
        for (int p = 0; p < 2; p++) {
            int e = p * 16 + (tid >> 4), c16 = tid & 15;
            if (base + e < NN) {
                *(uint4*)(nlh + (size_t)(base + e) * 128 + c16 * 8) =
                    *(const uint4*)(hid_s + e * 264 + c16 * 8);
                *(uint4*)(nll + (size_t)(base + e) * 128 + c16 * 8) =
                    *(const uint4*)(hid_s + e * 264 + 128 + c16 * 8);
            }
        }
    }
}

// ---------------- decoder: 128 -> 128 -> 3 (fp32 VALU, reads hi+lo) ----------------

__global__ __launch_bounds__(128) void k_decode(
    const unsigned short* __restrict__ nlh, const unsigned short* __restrict__ nll,
    const float* __restrict__ w1, const float* __restrict__ b1,
    const float* __restrict__ w2, const float* __restrict__ b2,
    float* __restrict__ out) {
    __shared__ float inl[16][128];
    __shared__ float hid[16][128];
    int j = threadIdx.x;
    int base = blockIdx.x * 16;
    for (int e = 0; e < 16; e++)
        inl[e][j] = bflo((unsigned int)nlh[(size_t)(base + e) * 128 + j]) +
                    bflo((unsigned int)nll[(size_t)(base + e) * 128 + j]);
    __syncthreads();
    float acc[16];
#pragma unroll
    for (int e = 0; e < 16; e++) acc[e] = b1[j];
    for (int kc = 0; kc < 16; kc++) {
        float w[8];
#pragma unroll
        for (int t = 0; t < 8; t++) w[t] = w1[(kc * 8 + t) * 128 + j];
#pragma unroll
        for (int e = 0; e < 16; e++) {
            float4 h0 = *(const float4*)&inl[e][kc * 8];
            float4 h1 = *(const float4*)&inl[e][kc * 8 + 4];
            acc[e] = fmaf(h0.x, w[0], acc[e]); acc[e] = fmaf(h0.y, w[1], acc[e]);
            acc[e] = fmaf(h0.z, w[2], acc[e]); acc[e] = fmaf(h0.w, w[3], acc[e]);
            acc[e] = fmaf(h1.x, w[4], acc[e]); acc[e] = fmaf(h1.y, w[5], acc[e]);
            acc[e] = fmaf(h1.z, w[6], acc[e]); acc[e] = fmaf(h1.w, w[7], acc[e]);
        }
    }
#pragma unroll
    for (int e = 0; e < 16; e++) hid[e][j] = fmaxf(acc[e], 0.f);
    __syncthreads();
    if (j < 48) {
        int e = j / 3, ch = j - 3 * (j / 3);
        float s = b2[ch];
        for (int k = 0; k < 128; k++) s = fmaf(hid[e][k], w2[k * 3 + ch], s);
        out[(size_t)(base + e) * 3 + ch] = s;
    }
}

// ---------------- launch ----------------

extern "C" void kernel_launch(void* const* d_in, const int* in_sizes, int n_in,
                              void* d_out, int out_size, void* d_ws, size_t ws_size,
                              hipStream_t stream) {
    (void)in_sizes; (void)n_in; (void)out_size; (void)ws_size;
    const float* pos   = (const float*)d_in[0];
    const float* vel   = (const float*)d_in[1];
    const int*   rid   = (const int*)d_in[2];
    const int*   snd   = (const int*)d_in[3];
    const int*   rcv   = (const int*)d_in[4];
    const float* remb  = (const float*)d_in[5];
    const float* ne_w1 = (const float*)d_in[6];
    const float* ne_b1 = (const float*)d_in[7];
    const float* ne_w2 = (const float*)d_in[8];
    const float* ne_b2 = (const float*)d_in[9];
    const float* ee_w1 = (const float*)d_in[10];
    const float* ee_b1 = (const float*)d_in[11];
    const float* ee_w2 = (const float*)d_in[12];
    const float* ee_b2 = (const float*)d_in[13];
    const float* pe_w1 = (const float*)d_in[14];
    const float* pe_b1 = (const float*)d_in[15];
    const float* pe_w2 = (const float*)d_in[16];
    const float* pe_b2 = (const float*)d_in[17];
    const float* pn_w1 = (const float*)d_in[18];
    const float* pn_b1 = (const float*)d_in[19];
    const float* pn_w2 = (const float*)d_in[20];
    const float* pn_b2 = (const float*)d_in[21];
    const float* de_w1 = (const float*)d_in[22];
    const float* de_b1 = (const float*)d_in[23];
    const float* de_w2 = (const float*)d_in[24];
    const float* de_b2 = (const float*)d_in[25];
    float* out = (float*)d_out;

    // workspace carve (~250.7e6 B — under the 256.2e6 proven available)
    char* p = (char*)d_ws;
    auto carve = [&](size_t bytes) { void* q = (void*)p; p += (bytes + 15) & ~(size_t)15; return q; };
    unsigned short* el    = (unsigned short*)carve((size_t)NE * LDIM * 2);   // 204.8e6, CSR order
    unsigned short* nlh   = (unsigned short*)carve((size_t)NN * LDIM * 2);   // 12.8e6
    unsigned short* nll   = (unsigned short*)carve((size_t)NN * LDIM * 2);   // 12.8e6
    unsigned short* agg   = (unsigned short*)carve((size_t)NN * LDIM * 2);   // 12.8e6 (bf16)
    unsigned short* w1f_e = (unsigned short*)carve((size_t)NSTEPS * 12 * 8 * 512 * 2);
    unsigned short* w2f_e = (unsigned short*)carve((size_t)NSTEPS * 4 * 8 * 512 * 2);
    unsigned short* w1h_n = (unsigned short*)carve((size_t)NSTEPS * 8 * 8 * 512 * 2);
    unsigned short* w1l_n = (unsigned short*)carve((size_t)NSTEPS * 8 * 8 * 512 * 2);
    unsigned short* w2h_n = (unsigned short*)carve((size_t)NSTEPS * 4 * 8 * 512 * 2);
    unsigned short* w2l_n = (unsigned short*)carve((size_t)NSTEPS * 4 * 8 * 512 * 2);
    unsigned short* eew1h = (unsigned short*)carve((size_t)1 * 8 * 512 * 2);
    unsigned short* eew1l = (unsigned short*)carve((size_t)1 * 8 * 512 * 2);
    unsigned short* eew2h = (unsigned short*)carve((size_t)4 * 8 * 512 * 2);
    unsigned short* eew2l = (unsigned short*)carve((size_t)4 * 8 * 512 * 2);
    unsigned short* new1h = (unsigned short*)carve((size_t)1 * 8 * 512 * 2);
    unsigned short* new1l = (unsigned short*)carve((size_t)1 * 8 * 512 * 2);
    unsigned short* new2h = (unsigned short*)carve((size_t)4 * 8 * 512 * 2);
    unsigned short* new2l = (unsigned short*)carve((size_t)4 * 8 * 512 * 2);
    unsigned short* snd_p = (unsigned short*)carve((size_t)NE * 2);          // 1.6e6
    unsigned short* rcv_p = (unsigned short*)carve((size_t)NE * 2);          // 1.6e6
    int*            rs    = (int*)carve((size_t)(NN + 1) * 4);
    int*            cnt   = (int*)carve((size_t)NN * 4);
    int*            cur   = (int*)carve((size_t)NN * 4);
    float*          degf  = (float*)carve((size_t)NN * 4);
    int*            fn    = (int*)carve((size_t)(NB + 1) * 4);               // first node per edge block
    float*          csum  = (float*)carve(16);

    hipMemsetAsync(cnt, 0, (size_t)NN * 4, stream);
    hipMemsetAsync(csum, 0, 16, stream);
    hipMemsetAsync(fn, 0x7f, (size_t)(NB + 1) * 4, stream);
    k_hist<<<NE / 256, 256, 0, stream>>>(rcv, cnt);
    k_scan<<<1, 1024, 0, stream>>>(cnt, rs, cur, degf, fn);
    k_center<<<64, 256, 0, stream>>>(pos, csum);
    k_scatter<<<NE / 256, 256, 0, stream>>>(snd, rcv, cur, snd_p, rcv_p);
    k_prep_w<<<NSTEPS * 12 * 8, 64, 0, stream>>>(pe_w1, w1f_e, 12, 384, 0);
    k_prep_w<<<NSTEPS * 4 * 8, 64, 0, stream>>>(pe_w2, w2f_e, 4, 128, 0);
    k_prep_w<<<NSTEPS * 8 * 8, 64, 0, stream>>>(pn_w1, w1h_n, 8, 256, 0);
    k_prep_w<<<NSTEPS * 8 * 8, 64, 0, stream>>>(pn_w1, w1l_n, 8, 256, 1);
    k_prep_w<<<NSTEPS * 4 * 8, 64, 0, stream>>>(pn_w2, w2h_n, 4, 128, 0);
    k_prep_w<<<NSTEPS * 4 * 8, 64, 0, stream>>>(pn_w2, w2l_n, 4, 128, 1);
    k_prep_w<<<8, 64, 0, stream>>>(ee_w1, eew1h, 1, 9, 0);
    k_prep_w<<<8, 64, 0, stream>>>(ee_w1, eew1l, 1, 9, 1);
    k_prep_w<<<4 * 8, 64, 0, stream>>>(ee_w2, eew2h, 4, 128, 0);
    k_prep_w<<<4 * 8, 64, 0, stream>>>(ee_w2, eew2l, 4, 128, 1);
    k_prep_w<<<8, 64, 0, stream>>>(ne_w1, new1h, 1, 23, 0);
    k_prep_w<<<8, 64, 0, stream>>>(ne_w1, new1l, 1, 23, 1);
    k_prep_w<<<4 * 8, 64, 0, stream>>>(ne_w2, new2h, 4, 128, 0);
    k_prep_w<<<4 * 8, 64, 0, stream>>>(ne_w2, new2l, 4, 128, 1);

    k_node_enc_m<<<(NN + 127) / 128, 256, 0, stream>>>(pos, vel, rid, remb, degf, csum,
                                                       new1h, new1l, ne_b1, new2h, new2l, ne_b2, nlh, nll);
    k_edge_enc_m<<<NE / 128, 256, 0, stream>>>(pos, vel, rid, snd_p, rcv_p,
                                               eew1h, eew1l, ee_b1, eew2h, eew2l, ee_b2, el);
    for (int i = 0; i < NSTEPS; i++) {
        k_edge_step<<<NB, 256, 0, stream>>>(el, nlh, snd_p, rcv_p, rs, fn,
            w1f_e + (size_t)i * 12 * 8 * 512, pe_b1 + i * 128,
            w2f_e + (size_t)i * 4 * 8 * 512, pe_b2 + i * 128, agg);
        k_node_step_s<<<(NN + 63) / 64, 256, 0, stream>>>(nlh, nll, agg,
            w1h_n + (size_t)i * 8 * 8 * 512, w1l_n + (size_t)i * 8 * 8 * 512, pn_b1 + i * 128,
            w2h_n + (size_t)i * 4 * 8 * 512, w2l_n + (size_t)i * 4 * 8 * 512, pn_b2 + i * 128);
    }
    k_decode<<<NN / 16, 128, 0, stream>>>(nlh, nll, de_w1, de_b1, de_w2, de_b2, out);
}

// Round 11
// 2890.619 us; speedup vs baseline: 1.7737x; 1.1743x over previous
//
#include <hip/hip_runtime.h>
#include <hip/hip_bf16.h>

#define NN 50000
#define NE 800000
#define LDIM 128
#define NSTEPS 10

typedef __hip_bfloat16 bf16;
typedef __bf16 bf8v __attribute__((ext_vector_type(8)));
typedef float f4v __attribute__((ext_vector_type(4)));
typedef unsigned short u16x8 __attribute__((ext_vector_type(8)));

__device__ inline float bflo(unsigned int u) {
    union { unsigned int i; float f; } x; x.i = u << 16; return x.f;
}
__device__ inline float bfhi(unsigned int u) {
    union { unsigned int i; float f; } x; x.i = u & 0xffff0000u; return x.f;
}
__device__ inline unsigned short f2bf(float f) {
    __hip_bfloat16 h = __float2bfloat16(f);
    unsigned short u; __builtin_memcpy(&u, &h, 2); return u;
}

// async global->LDS DMA, 16 B per lane. LDS dest is wave-uniform base + lane*16
// (linear); global src is per-lane. Drained by the vmcnt(0) the compiler emits
// at the next __syncthreads.
__device__ __forceinline__ void gl_lds16(const void* g, void* l) {
    __builtin_amdgcn_global_load_lds(
        (const __attribute__((address_space(1))) unsigned int*)g,
        (__attribute__((address_space(3))) unsigned int*)l, 16, 0, 0);
}

// ---------------- CSR build: histogram, scan, scatter (ushort permuted endpoints) ----------------

__global__ void k_hist(const int* __restrict__ rcv, int* __restrict__ cnt) {
    int i = blockIdx.x * 256 + threadIdx.x;
    if (i < NE) atomicAdd(&cnt[rcv[i]], 1);
}

__global__ __launch_bounds__(1024) void k_scan(
    const int* __restrict__ cnt, int* __restrict__ row_start,
    int* __restrict__ cur, float* __restrict__ degf) {
    __shared__ int part[1024];
    const int t = threadIdx.x;
    const int CH = (NN + 1023) / 1024;  // 49
    int b0 = t * CH, b1 = b0 + CH; if (b1 > NN) b1 = NN; if (b0 > NN) b0 = NN;
    int s = 0;
    for (int i = b0; i < b1; i++) s += cnt[i];
    part[t] = s;
    __syncthreads();
    for (int off = 1; off < 1024; off <<= 1) {
        int v = (t >= off) ? part[t - off] : 0;
        __syncthreads();
        part[t] += v;
        __syncthreads();
    }
    int run = part[t] - s;  // exclusive prefix
    for (int i = b0; i < b1; i++) {
        row_start[i] = run; cur[i] = run; degf[i] = (float)cnt[i];
        run += cnt[i];
    }
    if (t == 1023) row_start[NN] = part[1023];
}

__global__ void k_scatter(const int* __restrict__ snd, const int* __restrict__ rcv,
                          int* __restrict__ cur,
                          unsigned short* __restrict__ snd_p, unsigned short* __restrict__ rcv_p) {
    int i = blockIdx.x * 256 + threadIdx.x;
    if (i < NE) {
        int r = rcv[i];
        int p = atomicAdd(&cur[r], 1);
        snd_p[p] = (unsigned short)snd[i];
        rcv_p[p] = (unsigned short)r;
    }
}

__global__ void k_center(const float* __restrict__ pos, float* __restrict__ csum) {
    __shared__ float s[3][256];
    float a = 0.f, b = 0.f, c = 0.f;
    for (int i = blockIdx.x * 256 + threadIdx.x; i < NN; i += gridDim.x * 256) {
        a += pos[3 * i]; b += pos[3 * i + 1]; c += pos[3 * i + 2];
    }
    int t = threadIdx.x;
    s[0][t] = a; s[1][t] = b; s[2][t] = c;
    __syncthreads();
    for (int off = 128; off > 0; off >>= 1) {
        if (t < off) {
            s[0][t] += s[0][t + off];
            s[1][t] += s[1][t + off];
            s[2][t] += s[2][t + off];
        }
        __syncthreads();
    }
    if (t == 0) {
        atomicAdd(&csum[0], s[0][0]);
        atomicAdd(&csum[1], s[1][0]);
        atomicAdd(&csum[2], s[2][0]);
    }
}

// ---------------- weight prep: fp32 -> bf16 B-frag order; lo=1 emits bf16(x - bf16(x)) ----------------

__global__ void k_prep_w(const float* __restrict__ w, unsigned short* __restrict__ wf,
                         int KT, int Ksrc, int lo) {
    int b = blockIdx.x;
    int s = b / (KT * 8), rem = b % (KT * 8);
    int kt = rem / 8, nt = rem % 8;
    int lane = threadIdx.x, col = lane & 15, quad = lane >> 4;
    const float* W = w + (size_t)s * Ksrc * 128;
    u16x8 o;
#pragma unroll
    for (int jj = 0; jj < 8; jj++) {
        int k = kt * 32 + quad * 8 + jj;
        float x = (k < Ksrc) ? W[(size_t)k * 128 + nt * 16 + col] : 0.f;
        unsigned short h = f2bf(x);
        if (lo) h = f2bf(x - bflo(h));
        o[jj] = h;
    }
    *(u16x8*)(wf + (((size_t)b) * 64 + lane) * 8) = o;
}

// ---------------- CSR aggregation: streaming reduction el (CSR order) -> bf16 agg ----------------

__global__ __launch_bounds__(256) void k_agg(
    const unsigned short* __restrict__ el, const int* __restrict__ row_start,
    unsigned short* __restrict__ agg) {
    const int wave = threadIdx.x >> 6, lane = threadIdx.x & 63;
    const int n = blockIdx.x * 4 + wave;
    if (n >= NN) return;
    const int sub = lane >> 4, c16 = lane & 15;
    const int st = row_start[n], en = row_start[n + 1];
    float s[8];
#pragma unroll
    for (int k = 0; k < 8; k++) s[k] = 0.f;
    for (int q = st + sub; q < en; q += 4) {
        uint4 v = *(const uint4*)(el + (size_t)q * 128 + c16 * 8);
        s[0] += bflo(v.x); s[1] += bfhi(v.x);
        s[2] += bflo(v.y); s[3] += bfhi(v.y);
        s[4] += bflo(v.z); s[5] += bfhi(v.z);
        s[6] += bflo(v.w); s[7] += bfhi(v.w);
    }
#pragma unroll
    for (int k = 0; k < 8; k++) {
        s[k] += __shfl_xor(s[k], 16);
        s[k] += __shfl_xor(s[k], 32);
    }
    if (sub == 0) {
        u16x8 o;
#pragma unroll
        for (int k = 0; k < 8; k++) o[k] = f2bf(s[k]);
        *(u16x8*)(agg + (size_t)n * 128 + c16 * 8) = o;
    }
}

// ---------------- MFMA node encoder (split-precision): feat(23 pad 32, hi|lo) -> 128 -> 128 ----------------
// Output: node latent as bf16 hi/lo pair (nlh, nll).

__global__ __launch_bounds__(256) void k_node_enc_m(
    const float* __restrict__ pos, const float* __restrict__ vel,
    const int* __restrict__ rid, const float* __restrict__ remb,
    const float* __restrict__ degf, const float* __restrict__ csum,
    const unsigned short* __restrict__ w1h, const unsigned short* __restrict__ w1l,
    const float* __restrict__ b1,
    const unsigned short* __restrict__ w2h, const unsigned short* __restrict__ w2l,
    const float* __restrict__ b2,
    unsigned short* __restrict__ nlh, unsigned short* __restrict__ nll) {
    __shared__ __align__(16) unsigned short feat_s[32 * 72];   // [hi(32)|lo(32)|pad]
    __shared__ __align__(16) unsigned short hid_s[32 * 264];   // [hi(128)|lo(128)|pad]
    const int tid = threadIdx.x, wave = tid >> 6, lane = tid & 63;
    const int col = lane & 15, quad = lane >> 4;
    bf8v W1H[2], W1L[2], W2H[4][2], W2L[4][2];
#pragma unroll
    for (int t = 0; t < 2; t++) {
        W1H[t] = *(const bf8v*)(w1h + ((size_t)(2 * wave + t) * 64 + lane) * 8);
        W1L[t] = *(const bf8v*)(w1l + ((size_t)(2 * wave + t) * 64 + lane) * 8);
    }
#pragma unroll
    for (int kt = 0; kt < 4; kt++)
#pragma unroll
        for (int t = 0; t < 2; t++) {
            W2H[kt][t] = *(const bf8v*)(w2h + ((size_t)(kt * 8 + 2 * wave + t) * 64 + lane) * 8);
            W2L[kt][t] = *(const bf8v*)(w2l + ((size_t)(kt * 8 + 2 * wave + t) * 64 + lane) * 8);
        }
    float bias1[2], bias2[2];
#pragma unroll
    for (int t = 0; t < 2; t++) {
        bias1[t] = b1[(2 * wave + t) * 16 + col];
        bias2[t] = b2[(2 * wave + t) * 16 + col];
    }
    float cx = csum[0] * (1.0f / NN), cy = csum[1] * (1.0f / NN), cz = csum[2] * (1.0f / NN);
    uint4 z = {0u, 0u, 0u, 0u};
    for (int s2 = tid; s2 < 288; s2 += 256) *(uint4*)(feat_s + s2 * 8) = z;  // zero K-pad

    for (int it = 0; it < 4; it++) {
        const int base = blockIdx.x * 128 + it * 32;
        if (base >= NN) break;
        __syncthreads();
        if (tid < 32) {
            int n = base + tid; if (n > NN - 1) n = NN - 1;
            float v[23];
            v[0] = vel[3 * n]; v[1] = vel[3 * n + 1]; v[2] = vel[3 * n + 2];
            v[3] = pos[3 * n] - cx; v[4] = pos[3 * n + 1] - cy; v[5] = pos[3 * n + 2] - cz;
            v[6] = degf[n];
            int rb = rid[n] * 16;
#pragma unroll
            for (int k = 0; k < 16; k++) v[7 + k] = remb[rb + k];
            unsigned short* f = feat_s + tid * 72;
#pragma unroll
            for (int k = 0; k < 23; k++) {
                unsigned short h = f2bf(v[k]);
                f[k] = h; f[32 + k] = f2bf(v[k] - bflo(h));
            }
        }
        __syncthreads();
        f4v acc[2][2];
#pragma unroll
        for (int mt = 0; mt < 2; mt++)
#pragma unroll
            for (int t = 0; t < 2; t++) acc[mt][t] = (f4v){0.f, 0.f, 0.f, 0.f};
        {
            bf8v a0h = *(const bf8v*)(feat_s + col * 72 + quad * 8);
            bf8v a1h = *(const bf8v*)(feat_s + (16 + col) * 72 + quad * 8);
            bf8v a0l = *(const bf8v*)(feat_s + col * 72 + 32 + quad * 8);
            bf8v a1l = *(const bf8v*)(feat_s + (16 + col) * 72 + 32 + quad * 8);
#pragma unroll
            for (int t = 0; t < 2; t++) {
                acc[0][t] = __builtin_amdgcn_mfma_f32_16x16x32_bf16(a0h, W1H[t], acc[0][t], 0, 0, 0);
                acc[1][t] = __builtin_amdgcn_mfma_f32_16x16x32_bf16(a1h, W1H[t], acc[1][t], 0, 0, 0);
                acc[0][t] = __builtin_amdgcn_mfma_f32_16x16x32_bf16(a0l, W1H[t], acc[0][t], 0, 0, 0);
                acc[1][t] = __builtin_amdgcn_mfma_f32_16x16x32_bf16(a1l, W1H[t], acc[1][t], 0, 0, 0);
                acc[0][t] = __builtin_amdgcn_mfma_f32_16x16x32_bf16(a0h, W1L[t], acc[0][t], 0, 0, 0);
                acc[1][t] = __builtin_amdgcn_mfma_f32_16x16x32_bf16(a1h, W1L[t], acc[1][t], 0, 0, 0);
            }
        }
#pragma unroll
        for (int mt = 0; mt < 2; mt++)
#pragma unroll
            for (int t = 0; t < 2; t++) {
                const int nc = (2 * wave + t) * 16 + col;
#pragma unroll
                for (int r = 0; r < 4; r++) {
                    float h = fmaxf(acc[mt][t][r] + bias1[t], 0.f);
                    unsigned short hh = f2bf(h);
                    hid_s[(mt * 16 + quad * 4 + r) * 264 + nc] = hh;
                    hid_s[(mt * 16 + quad * 4 + r) * 264 + 128 + nc] = f2bf(h - bflo(hh));
                }
            }
        __syncthreads();
#pragma unroll
        for (int mt = 0; mt < 2; mt++)
#pragma unroll
            for (int t = 0; t < 2; t++) acc[mt][t] = (f4v){0.f, 0.f, 0.f, 0.f};
#pragma unroll
        for (int kt = 0; kt < 8; kt++) {
            int w = kt & 3;
            bf8v a0 = *(const bf8v*)(hid_s + col * 264 + kt * 32 + quad * 8);
            bf8v a1 = *(const bf8v*)(hid_s + (16 + col) * 264 + kt * 32 + quad * 8);
#pragma unroll
            for (int t = 0; t < 2; t++) {
                acc[0][t] = __builtin_amdgcn_mfma_f32_16x16x32_bf16(a0, W2H[w][t], acc[0][t], 0, 0, 0);
                acc[1][t] = __builtin_amdgcn_mfma_f32_16x16x32_bf16(a1, W2H[w][t], acc[1][t], 0, 0, 0);
            }
        }
#pragma unroll
        for (int kt = 0; kt < 4; kt++) {
            bf8v a0 = *(const bf8v*)(hid_s + col * 264 + kt * 32 + quad * 8);
            bf8v a1 = *(const bf8v*)(hid_s + (16 + col) * 264 + kt * 32 + quad * 8);
#pragma unroll
            for (int t = 0; t < 2; t++) {
                acc[0][t] = __builtin_amdgcn_mfma_f32_16x16x32_bf16(a0, W2L[kt][t], acc[0][t], 0, 0, 0);
                acc[1][t] = __builtin_amdgcn_mfma_f32_16x16x32_bf16(a1, W2L[kt][t], acc[1][t], 0, 0, 0);
            }
        }
        __syncthreads();  // all hid reads done; overwrite with output hi/lo
#pragma unroll
        for (int mt = 0; mt < 2; mt++)
#pragma unroll
            for (int t = 0; t < 2; t++) {
                const int nc = (2 * wave + t) * 16 + col;
#pragma unroll
                for (int r = 0; r < 4; r++) {
                    const int row = mt * 16 + quad * 4 + r;
                    float v = acc[mt][t][r] + bias2[t];
                    unsigned short hh = f2bf(v);
                    hid_s[row * 264 + nc] = hh;
                    hid_s[row * 264 + 128 + nc] = f2bf(v - bflo(hh));
                }
            }
        __syncthreads();
#pragma unroll
        for (int p = 0; p < 2; p++) {
            int s2 = p * 256 + tid, e = s2 >> 4, c16 = s2 & 15;
            if (base + e < NN) {
                *(uint4*)(nlh + (size_t)(base + e) * 128 + c16 * 8) =
                    *(const uint4*)(hid_s + e * 264 + c16 * 8);
                *(uint4*)(nll + (size_t)(base + e) * 128 + c16 * 8) =
                    *(const uint4*)(hid_s + e * 264 + 128 + c16 * 8);
            }
        }
    }
}

// ---------------- MFMA edge encoder (split-precision): feat(9 pad 32, hi|lo) -> 128 -> 128 ----------------

__global__ __launch_bounds__(256) void k_edge_enc_m(
    const float* __restrict__ pos, const float* __restrict__ vel,
    const int* __restrict__ rid,
    const unsigned short* __restrict__ snd, const unsigned short* __restrict__ rcv,
    const unsigned short* __restrict__ w1h, const unsigned short* __restrict__ w1l,
    const float* __restrict__ b1,
    const unsigned short* __restrict__ w2h, const unsigned short* __restrict__ w2l,
    const float* __restrict__ b2,
    unsigned short* __restrict__ el) {
    __shared__ __align__(16) unsigned short feat_s[32 * 72];
    __shared__ __align__(16) unsigned short hid_s[32 * 264];
    const int tid = threadIdx.x, wave = tid >> 6, lane = tid & 63;
    const int col = lane & 15, quad = lane >> 4;
    bf8v W1H[2], W1L[2], W2H[4][2], W2L[4][2];
#pragma unroll
    for (int t = 0; t < 2; t++) {
        W1H[t] = *(const bf8v*)(w1h + ((size_t)(2 * wave + t) * 64 + lane) * 8);
        W1L[t] = *(const bf8v*)(w1l + ((size_t)(2 * wave + t) * 64 + lane) * 8);
    }
#pragma unroll
    for (int kt = 0; kt < 4; kt++)
#pragma unroll
        for (int t = 0; t < 2; t++) {
            W2H[kt][t] = *(const bf8v*)(w2h + ((size_t)(kt * 8 + 2 * wave + t) * 64 + lane) * 8);
            W2L[kt][t] = *(const bf8v*)(w2l + ((size_t)(kt * 8 + 2 * wave + t) * 64 + lane) * 8);
        }
    float bias1[2], bias2[2];
#pragma unroll
    for (int t = 0; t < 2; t++) {
        bias1[t] = b1[(2 * wave + t) * 16 + col];
        bias2[t] = b2[(2 * wave + t) * 16 + col];
    }
    uint4 z = {0u, 0u, 0u, 0u};
    for (int s2 = tid; s2 < 288; s2 += 256) *(uint4*)(feat_s + s2 * 8) = z;

    for (int it = 0; it < 4; it++) {
        const int base = blockIdx.x * 128 + it * 32;
        __syncthreads();
        if (tid < 32) {
            int e = base + tid;
            int s = snd[e], r = rcv[e];
            float v[9];
            v[0] = pos[3 * s] - pos[3 * r]; v[1] = pos[3 * s + 1] - pos[3 * r + 1]; v[2] = pos[3 * s + 2] - pos[3 * r + 2];
            v[3] = vel[3 * s] - vel[3 * r]; v[4] = vel[3 * s + 1] - vel[3 * r + 1]; v[5] = vel[3 * s + 2] - vel[3 * r + 2];
            float sq = v[0] * v[0] + v[1] * v[1] + v[2] * v[2];
            v[6] = sqrtf(sq); v[7] = sq;
            v[8] = (rid[s] == rid[r]) ? 1.f : 0.f;
            unsigned short* f = feat_s + tid * 72;
#pragma unroll
            for (int k = 0; k < 9; k++) {
                unsigned short h = f2bf(v[k]);
                f[k] = h; f[32 + k] = f2bf(v[k] - bflo(h));
            }
        }
        __syncthreads();
        f4v acc[2][2];
#pragma unroll
        for (int mt = 0; mt < 2; mt++)
#pragma unroll
            for (int t = 0; t < 2; t++) acc[mt][t] = (f4v){0.f, 0.f, 0.f, 0.f};
        {
            bf8v a0h = *(const bf8v*)(feat_s + col * 72 + quad * 8);
            bf8v a1h = *(const bf8v*)(feat_s + (16 + col) * 72 + quad * 8);
            bf8v a0l = *(const bf8v*)(feat_s + col * 72 + 32 + quad * 8);
            bf8v a1l = *(const bf8v*)(feat_s + (16 + col) * 72 + 32 + quad * 8);
#pragma unroll
            for (int t = 0; t < 2; t++) {
                acc[0][t] = __builtin_amdgcn_mfma_f32_16x16x32_bf16(a0h, W1H[t], acc[0][t], 0, 0, 0);
                acc[1][t] = __builtin_amdgcn_mfma_f32_16x16x32_bf16(a1h, W1H[t], acc[1][t], 0, 0, 0);
                acc[0][t] = __builtin_amdgcn_mfma_f32_16x16x32_bf16(a0l, W1H[t], acc[0][t], 0, 0, 0);
                acc[1][t] = __builtin_amdgcn_mfma_f32_16x16x32_bf16(a1l, W1H[t], acc[1][t], 0, 0, 0);
                acc[0][t] = __builtin_amdgcn_mfma_f32_16x16x32_bf16(a0h, W1L[t], acc[0][t], 0, 0, 0);
                acc[1][t] = __builtin_amdgcn_mfma_f32_16x16x32_bf16(a1h, W1L[t], acc[1][t], 0, 0, 0);
            }
        }
#pragma unroll
        for (int mt = 0; mt < 2; mt++)
#pragma unroll
            for (int t = 0; t < 2; t++) {
                const int nc = (2 * wave + t) * 16 + col;
#pragma unroll
                for (int r = 0; r < 4; r++) {
                    float h = fmaxf(acc[mt][t][r] + bias1[t], 0.f);
                    unsigned short hh = f2bf(h);
                    hid_s[(mt * 16 + quad * 4 + r) * 264 + nc] = hh;
                    hid_s[(mt * 16 + quad * 4 + r) * 264 + 128 + nc] = f2bf(h - bflo(hh));
                }
            }
        __syncthreads();
#pragma unroll
        for (int mt = 0; mt < 2; mt++)
#pragma unroll
            for (int t = 0; t < 2; t++) acc[mt][t] = (f4v){0.f, 0.f, 0.f, 0.f};
#pragma unroll
        for (int kt = 0; kt < 8; kt++) {
            int w = kt & 3;
            bf8v a0 = *(const bf8v*)(hid_s + col * 264 + kt * 32 + quad * 8);
            bf8v a1 = *(const bf8v*)(hid_s + (16 + col) * 264 + kt * 32 + quad * 8);
#pragma unroll
            for (int t = 0; t < 2; t++) {
                acc[0][t] = __builtin_amdgcn_mfma_f32_16x16x32_bf16(a0, W2H[w][t], acc[0][t], 0, 0, 0);
                acc[1][t] = __builtin_amdgcn_mfma_f32_16x16x32_bf16(a1, W2H[w][t], acc[1][t], 0, 0, 0);
            }
        }
#pragma unroll
        for (int kt = 0; kt < 4; kt++) {
            bf8v a0 = *(const bf8v*)(hid_s + col * 264 + kt * 32 + quad * 8);
            bf8v a1 = *(const bf8v*)(hid_s + (16 + col) * 264 + kt * 32 + quad * 8);
#pragma unroll
            for (int t = 0; t < 2; t++) {
                acc[0][t] = __builtin_amdgcn_mfma_f32_16x16x32_bf16(a0, W2L[kt][t], acc[0][t], 0, 0, 0);
                acc[1][t] = __builtin_amdgcn_mfma_f32_16x16x32_bf16(a1, W2L[kt][t], acc[1][t], 0, 0, 0);
            }
        }
        __syncthreads();
#pragma unroll
        for (int mt = 0; mt < 2; mt++)
#pragma unroll
            for (int t = 0; t < 2; t++) {
                const int nc = (2 * wave + t) * 16 + col;
#pragma unroll
                for (int r = 0; r < 4; r++)
                    hid_s[(mt * 16 + quad * 4 + r) * 264 + nc] = f2bf(acc[mt][t][r] + bias2[t]);
            }
        __syncthreads();
#pragma unroll
        for (int p = 0; p < 2; p++) {
            int s2 = p * 256 + tid, e = s2 >> 4, c16 = s2 & 15;
            *(uint4*)(el + (size_t)(base + e) * 128 + c16 * 8) =
                *(const uint4*)(hid_s + e * 264 + c16 * 8);
        }
    }
}

// ---------------- MFMA edge processor step (CSR order) ----------------
// v6 (best verified, 2887 us): double-buffered global_load_lds staging.
// Register prefetch across barriers spills to scratch regardless of
// launch_bounds (v3/v4/v5: WRITE +120..300 MB); global_load_lds has zero
// register footprint. Issue tile t+1 right after the top barrier; compiler's
// vmcnt(0) at the post-L1 barrier drains it -> HBM latency hides under
// ~24 ds_read + 48 MFMA. Counted-vmcnt raw barriers (v7), 4-blocks/CU
// re-tile (v8), and fused aggregation (v9-v11) all measured worse.
// LDS: stage[buf][3][32][128], XOR-swizzle byte^=(row&7)<<4 (rule #21:
// linear LDS dest + inverse-swizzled per-lane GLOBAL source + swizzled read).

__global__ __launch_bounds__(256) void k_edge_step(
    unsigned short* __restrict__ el, const unsigned short* __restrict__ nlh,
    const unsigned short* __restrict__ snd, const unsigned short* __restrict__ rcv,
    const unsigned short* __restrict__ w1f, const float* __restrict__ b1,
    const unsigned short* __restrict__ w2f, const float* __restrict__ b2) {
    __shared__ __align__(1024) unsigned short stage_s[2][3][32][128];  // 48 KB
    __shared__ __align__(16) unsigned short hid_s[32 * 136];           // 8.5 KB
    const int tid = threadIdx.x;
    const int wave = tid >> 6, lane = tid & 63;
    const int col = lane & 15, quad = lane >> 4;
    const int erow = tid >> 4, c16 = tid & 15;

    bf8v W1[12][2], W2[4][2];
#pragma unroll
    for (int kt = 0; kt < 12; kt++)
#pragma unroll
        for (int t = 0; t < 2; t++)
            W1[kt][t] = *(const bf8v*)(w1f + ((size_t)(kt * 8 + 2 * wave + t) * 64 + lane) * 8);
#pragma unroll
    for (int kt = 0; kt < 4; kt++)
#pragma unroll
        for (int t = 0; t < 2; t++)
            W2[kt][t] = *(const bf8v*)(w2f + ((size_t)(kt * 8 + 2 * wave + t) * 64 + lane) * 8);
    float bias1[2], bias2[2];
#pragma unroll
    for (int t = 0; t < 2; t++) {
        bias1[t] = b1[(2 * wave + t) * 16 + col];
        bias2[t] = b2[(2 * wave + t) * 16 + col];
    }

    // staging geometry: wave stages rows [wave*8, wave*8+8) of each stream,
    // 2 instructions x 1024 B. lane covers row = wave*8 + i*4 + (lane>>4),
    // 16 B at byte (lane&15)*16 within the row. Global source pre-swizzled.
    const int srow0 = wave * 8 + (lane >> 4);
    const int srow1 = srow0 + 4;
    const int skb = (lane & 15) * 16;
    const int soff0 = skb ^ ((srow0 & 7) << 4);
    const int soff1 = skb ^ ((srow1 & 7) << 4);
    const int gb0 = blockIdx.x * 128;
    const char* elc = (const char*)el;
    const char* nlc = (const char*)nlh;

    auto issue = [&](int t, int b, int si0, int si1, int ri0, int ri1) {
        char* s0 = (char*)&stage_s[b][0][wave * 8][0];
        char* s1 = (char*)&stage_s[b][1][wave * 8][0];
        char* s2 = (char*)&stage_s[b][2][wave * 8][0];
        const size_t gb = (size_t)(gb0 + t * 32);
        gl_lds16(elc + (gb + srow0) * 256 + soff0, s0);
        gl_lds16(elc + (gb + srow1) * 256 + soff1, s0 + 1024);
        gl_lds16(nlc + (size_t)si0 * 256 + soff0, s1);
        gl_lds16(nlc + (size_t)si1 * 256 + soff1, s1 + 1024);
        gl_lds16(nlc + (size_t)ri0 * 256 + soff0, s2);
        gl_lds16(nlc + (size_t)ri1 * 256 + soff1, s2 + 1024);
    };

    // prologue: issue tile 0; preload gather indices for tile 1
    {
        int si0 = snd[gb0 + srow0], si1 = snd[gb0 + srow1];
        int ri0 = rcv[gb0 + srow0], ri1 = rcv[gb0 + srow1];
        issue(0, 0, si0, si1, ri0, ri1);
    }
    int nsi0 = snd[gb0 + 32 + srow0], nsi1 = snd[gb0 + 32 + srow1];
    int nri0 = rcv[gb0 + 32 + srow0], nri1 = rcv[gb0 + 32 + srow1];

    for (int it = 0; it < 4; it++) {
        const int cur = it & 1, nxt = cur ^ 1;
        const int base = gb0 + it * 32;
        __syncthreads();  // B0: cur staged+visible; prev stores' hid_s reads done
        if (it < 3) {
            issue(it + 1, nxt, nsi0, nsi1, nri0, nri1);  // drains at B1 (under L1)
            if (it < 2) {
                int gb = gb0 + (it + 2) * 32;
                nsi0 = snd[gb + srow0]; nsi1 = snd[gb + srow1];
                nri0 = rcv[gb + srow0]; nri1 = rcv[gb + srow1];
            }
        }

        // ---- layer 1: K=384 over [el|snd|rcv] buffers (swizzled reads) ----
        f4v acc[2][2];
#pragma unroll
        for (int mt = 0; mt < 2; mt++)
#pragma unroll
            for (int t = 0; t < 2; t++) acc[mt][t] = (f4v){0.f, 0.f, 0.f, 0.f};
        const int sw = (col & 7) << 4;
#pragma unroll
        for (int kt = 0; kt < 12; kt++) {
            const char* sb = (const char*)&stage_s[cur][kt >> 2][0][0];
            const int kb = (kt & 3) * 64 + quad * 16;
            bf8v a0 = *(const bf8v*)(sb + col * 256 + (kb ^ sw));
            bf8v a1 = *(const bf8v*)(sb + (16 + col) * 256 + (kb ^ sw));
            acc[0][0] = __builtin_amdgcn_mfma_f32_16x16x32_bf16(a0, W1[kt][0], acc[0][0], 0, 0, 0);
            acc[0][1] = __builtin_amdgcn_mfma_f32_16x16x32_bf16(a0, W1[kt][1], acc[0][1], 0, 0, 0);
            acc[1][0] = __builtin_amdgcn_mfma_f32_16x16x32_bf16(a1, W1[kt][0], acc[1][0], 0, 0, 0);
            acc[1][1] = __builtin_amdgcn_mfma_f32_16x16x32_bf16(a1, W1[kt][1], acc[1][1], 0, 0, 0);
        }
#pragma unroll
        for (int mt = 0; mt < 2; mt++)
#pragma unroll
            for (int t = 0; t < 2; t++) {
                const int nc = (2 * wave + t) * 16 + col;
#pragma unroll
                for (int r = 0; r < 4; r++) {
                    float v = fmaxf(acc[mt][t][r] + bias1[t], 0.f);
                    hid_s[(mt * 16 + quad * 4 + r) * 136 + nc] = f2bf(v);
                }
            }
        __syncthreads();  // B1: hid visible; prefetch vmcnt drained here

        // ---- layer 2 ----
#pragma unroll
        for (int mt = 0; mt < 2; mt++)
#pragma unroll
            for (int t = 0; t < 2; t++) acc[mt][t] = (f4v){0.f, 0.f, 0.f, 0.f};
#pragma unroll
        for (int kt = 0; kt < 4; kt++) {
            bf8v a0 = *(const bf8v*)(hid_s + col * 136 + kt * 32 + quad * 8);
            bf8v a1 = *(const bf8v*)(hid_s + (16 + col) * 136 + kt * 32 + quad * 8);
            acc[0][0] = __builtin_amdgcn_mfma_f32_16x16x32_bf16(a0, W2[kt][0], acc[0][0], 0, 0, 0);
            acc[0][1] = __builtin_amdgcn_mfma_f32_16x16x32_bf16(a0, W2[kt][1], acc[0][1], 0, 0, 0);
            acc[1][0] = __builtin_amdgcn_mfma_f32_16x16x32_bf16(a1, W2[kt][0], acc[1][0], 0, 0, 0);
            acc[1][1] = __builtin_amdgcn_mfma_f32_16x16x32_bf16(a1, W2[kt][1], acc[1][1], 0, 0, 0);
        }
        __syncthreads();  // B2: all hid reads done

        // ---- epilogue: residual (from cur el buffer, swizzled) + bias2 -> hid_s ----
#pragma unroll
        for (int mt = 0; mt < 2; mt++)
#pragma unroll
            for (int t = 0; t < 2; t++) {
                const int nc = (2 * wave + t) * 16 + col;
#pragma unroll
                for (int r = 0; r < 4; r++) {
                    const int row = mt * 16 + quad * 4 + r;
                    float res = bflo((unsigned int)stage_s[cur][0][row][nc ^ ((row & 7) << 3)]);
                    float v = acc[mt][t][r] + bias2[t] + res;
                    hid_s[row * 136 + nc] = f2bf(v);
                }
            }
        __syncthreads();  // B3: out staged; cur fully consumed
#pragma unroll
        for (int p = 0; p < 2; p++) {
            int e = p * 16 + erow;
            *(uint4*)(el + (size_t)(base + e) * 128 + c16 * 8) =
                *(const uint4*)(hid_s + e * 136 + c16 * 8);
        }
    }
}

// ---------------- node step: [nl_hi|nl_lo|agg_hi] (K=384) -> 128 -> 128, residual, hi/lo out ----------------
// 64 nodes/block (2 tiles of 32), grid 782. agg precomputed bf16 by k_agg.

__global__ __launch_bounds__(256) void k_node_step_s(
    unsigned short* __restrict__ nlh, unsigned short* __restrict__ nll,
    const unsigned short* __restrict__ agg,
    const unsigned short* __restrict__ w1h, const unsigned short* __restrict__ w1l,
    const float* __restrict__ b1,
    const unsigned short* __restrict__ w2h, const unsigned short* __restrict__ w2l,
    const float* __restrict__ b2) {
    __shared__ __align__(16) unsigned short a_s[32 * 392];
    __shared__ __align__(16) unsigned short hid_s[32 * 264];
    const int tid = threadIdx.x, wave = tid >> 6, lane = tid & 63;
    const int col = lane & 15, quad = lane >> 4;
    bf8v W1H[8][2], W1L[8][2], W2H[4][2], W2L[4][2];
#pragma unroll
    for (int kt = 0; kt < 8; kt++)
#pragma unroll
        for (int t = 0; t < 2; t++) {
            W1H[kt][t] = *(const bf8v*)(w1h + ((size_t)(kt * 8 + 2 * wave + t) * 64 + lane) * 8);
            W1L[kt][t] = *(const bf8v*)(w1l + ((size_t)(kt * 8 + 2 * wave + t) * 64 + lane) * 8);
        }
#pragma unroll
    for (int kt = 0; kt < 4; kt++)
#pragma unroll
        for (int t = 0; t < 2; t++) {
            W2H[kt][t] = *(const bf8v*)(w2h + ((size_t)(kt * 8 + 2 * wave + t) * 64 + lane) * 8);
            W2L[kt][t] = *(const bf8v*)(w2l + ((size_t)(kt * 8 + 2 * wave + t) * 64 + lane) * 8);
        }
    float bias1[2], bias2[2];
#pragma unroll
    for (int t = 0; t < 2; t++) {
        bias1[t] = b1[(2 * wave + t) * 16 + col];
        bias2[t] = b2[(2 * wave + t) * 16 + col];
    }
    for (int it = 0; it < 2; it++) {
        const int base = blockIdx.x * 64 + it * 32;
        if (base >= NN) break;
        __syncthreads();  // prev-iter a_s/hid_s reads done
        // stage: direct uint4 copies (hi | lo | agg)
#pragma unroll
        for (int p = 0; p < 2; p++) {
            int e = p * 16 + (tid >> 4), c16 = tid & 15;
            int n = base + e; if (n > NN - 1) n = NN - 1;
            *(uint4*)(a_s + e * 392 + c16 * 8) =
                *(const uint4*)(nlh + (size_t)n * 128 + c16 * 8);
            *(uint4*)(a_s + e * 392 + 128 + c16 * 8) =
                *(const uint4*)(nll + (size_t)n * 128 + c16 * 8);
            *(uint4*)(a_s + e * 392 + 256 + c16 * 8) =
                *(const uint4*)(agg + (size_t)n * 128 + c16 * 8);
        }
        __syncthreads();

        f4v acc[2][2];
#pragma unroll
        for (int mt = 0; mt < 2; mt++)
#pragma unroll
            for (int t = 0; t < 2; t++) acc[mt][t] = (f4v){0.f, 0.f, 0.f, 0.f};
        // layer1: nl hi+lo vs W1H[0..3], agg vs W1H[4..7], nl hi vs W1L[0..3], agg vs W1L[4..7]
#pragma unroll
        for (int kt = 0; kt < 8; kt++) {
            bf8v a0 = *(const bf8v*)(a_s + col * 392 + kt * 32 + quad * 8);
            bf8v a1 = *(const bf8v*)(a_s + (16 + col) * 392 + kt * 32 + quad * 8);
#pragma unroll
            for (int t = 0; t < 2; t++) {
                acc[0][t] = __builtin_amdgcn_mfma_f32_16x16x32_bf16(a0, W1H[kt & 3][t], acc[0][t], 0, 0, 0);
                acc[1][t] = __builtin_amdgcn_mfma_f32_16x16x32_bf16(a1, W1H[kt & 3][t], acc[1][t], 0, 0, 0);
            }
        }
#pragma unroll
        for (int kt = 0; kt < 4; kt++) {
            bf8v a0 = *(const bf8v*)(a_s + col * 392 + 256 + kt * 32 + quad * 8);
            bf8v a1 = *(const bf8v*)(a_s + (16 + col) * 392 + 256 + kt * 32 + quad * 8);
#pragma unroll
            for (int t = 0; t < 2; t++) {
                acc[0][t] = __builtin_amdgcn_mfma_f32_16x16x32_bf16(a0, W1H[4 + kt][t], acc[0][t], 0, 0, 0);
                acc[1][t] = __builtin_amdgcn_mfma_f32_16x16x32_bf16(a1, W1H[4 + kt][t], acc[1][t], 0, 0, 0);
            }
        }
#pragma unroll
        for (int kt = 0; kt < 4; kt++) {
            bf8v a0 = *(const bf8v*)(a_s + col * 392 + kt * 32 + quad * 8);
            bf8v a1 = *(const bf8v*)(a_s + (16 + col) * 392 + kt * 32 + quad * 8);
#pragma unroll
            for (int t = 0; t < 2; t++) {
                acc[0][t] = __builtin_amdgcn_mfma_f32_16x16x32_bf16(a0, W1L[kt][t], acc[0][t], 0, 0, 0);
                acc[1][t] = __builtin_amdgcn_mfma_f32_16x16x32_bf16(a1, W1L[kt][t], acc[1][t], 0, 0, 0);
            }
        }
#pragma unroll
        for (int kt = 0; kt < 4; kt++) {
            bf8v a0 = *(const bf8v*)(a_s + col * 392 + 256 + kt * 32 + quad * 8);
            bf8v a1 = *(const bf8v*)(a_s + (16 + col) * 392 + 256 + kt * 32 + quad * 8);
#pragma unroll
            for (int t = 0; t < 2; t++) {
                acc[0][t] = __builtin_amdgcn_mfma_f32_16x16x32_bf16(a0, W1L[4 + kt][t], acc[0][t], 0, 0, 0);
                acc[1][t] = __builtin_amdgcn_mfma_f32_16x16x32_bf16(a1, W1L[4 + kt][t], acc[1][t], 0, 0, 0);
            }
        }
#pragma unroll
        for (int mt = 0; mt < 2; mt++)
#pragma unroll
            for (int t = 0; t < 2; t++) {
                const int nc = (2 * wave + t) * 16 + col;
#pragma unroll
                for (int r = 0; r < 4; r++) {
                    float h = fmaxf(acc[mt][t][r] + bias1[t], 0.f);
                    unsigned short hh = f2bf(h);
                    hid_s[(mt * 16 + quad * 4 + r) * 264 + nc] = hh;
                    hid_s[(mt * 16 + quad * 4 + r) * 264 + 128 + nc] = f2bf(h - bflo(hh));
                }
            }
        __syncthreads();
#pragma unroll
        for (int mt = 0; mt < 2; mt++)
#pragma unroll
            for (int t = 0; t < 2; t++) acc[mt][t] = (f4v){0.f, 0.f, 0.f, 0.f};
#pragma unroll
        for (int kt = 0; kt < 8; kt++) {
            int w = kt & 3;
            bf8v a0 = *(const bf8v*)(hid_s + col * 264 + kt * 32 + quad * 8);
            bf8v a1 = *(const bf8v*)(hid_s + (16 + col) * 264 + kt * 32 + quad * 8);
#pragma unroll
            for (int t = 0; t < 2; t++) {
                acc[0][t] = __builtin_amdgcn_mfma_f32_16x16x32_bf16(a0, W2H[w][t], acc[0][t], 0, 0, 0);
                acc[1][t] = __builtin_amdgcn_mfma_f32_16x16x32_bf16(a1, W2H[w][t], acc[1][t], 0, 0, 0);
            }
        }
#pragma unroll
        for (int kt = 0; kt < 4; kt++) {
            bf8v a0 = *(const bf8v*)(hid_s + col * 264 + kt * 32 + quad * 8);
            bf8v a1 = *(const bf8v*)(hid_s + (16 + col) * 264 + kt * 32 + quad * 8);
#pragma unroll
            for (int t = 0; t < 2; t++) {
                acc[0][t] = __builtin_amdgcn_mfma_f32_16x16x32_bf16(a0, W2L[kt][t], acc[0][t], 0, 0, 0);
                acc[1][t] = __builtin_amdgcn_mfma_f32_16x16x32_bf16(a1, W2L[kt][t], acc[1][t], 0, 0, 0);
            }
        }
        __syncthreads();  // all L2 reads of hid done; reuse hid_s for output staging
#pragma unroll
        for (int mt = 0; mt < 2; mt++)
#pragma unroll
            for (int t = 0; t < 2; t++) {
                const int nc = (2 * wave + t) * 16 + col;
#pragma unroll
                for (int r = 0; r < 4; r++) {
                    const int row = mt * 16 + quad * 4 + r;
                    // residual from a_s hi+lo (still intact)
                    float res = bflo((unsigned int)a_s[row * 392 + nc]) +
                                bflo((unsigned int)a_s[row * 392 + 128 + nc]);
                    float v = acc[mt][t][r] + bias2[t] + res;
                    unsigned short hh = f2bf(v);
                    hid_s[row * 264 + nc] = hh;
                    hid_s[row * 264 + 128 + nc] = f2bf(v - bflo(hh));
                }
            }
        __syncthreads();  // out staged
#pragma unroll
        for (int p = 0; p < 2; p++) {
            int e = p * 16 + (tid >> 4), c16 = tid & 15;
            if (base + e < NN) {
                *(uint4*)(nlh + (size_t)(base + e) * 128 + c16 * 8) =
                    *(const uint4*)(hid_s + e * 264 + c16 * 8);
                *(uint4*)(nll + (size_t)(base + e) * 128 + c16 * 8) =
                    *(const uint4*)(hid_s + e * 264 + 128 + c16 * 8);
            }
        }
    }
}

// ---------------- decoder: 128 -> 128 -> 3 (fp32 VALU, reads hi+lo) ----------------

__global__ __launch_bounds__(128) void k_decode(
    const unsigned short* __restrict__ nlh, const unsigned short* __restrict__ nll,
    const float* __restrict__ w1, const float* __restrict__ b1,
    const float* __restrict__ w2, const float* __restrict__ b2,
    float* __restrict__ out) {
    __shared__ float inl[16][128];
    __shared__ float hid[16][128];
    int j = threadIdx.x;
    int base = blockIdx.x * 16;
    for (int e = 0; e < 16; e++)
        inl[e][j] = bflo((unsigned int)nlh[(size_t)(base + e) * 128 + j]) +
                    bflo((unsigned int)nll[(size_t)(base + e) * 128 + j]);
    __syncthreads();
    float acc[16];
#pragma unroll
    for (int e = 0; e < 16; e++) acc[e] = b1[j];
    for (int kc = 0; kc < 16; kc++) {
        float w[8];
#pragma unroll
        for (int t = 0; t < 8; t++) w[t] = w1[(kc * 8 + t) * 128 + j];
#pragma unroll
        for (int e = 0; e < 16; e++) {
            float4 h0 = *(const float4*)&inl[e][kc * 8];
            float4 h1 = *(const float4*)&inl[e][kc * 8 + 4];
            acc[e] = fmaf(h0.x, w[0], acc[e]); acc[e] = fmaf(h0.y, w[1], acc[e]);
            acc[e] = fmaf(h0.z, w[2], acc[e]); acc[e] = fmaf(h0.w, w[3], acc[e]);
            acc[e] = fmaf(h1.x, w[4], acc[e]); acc[e] = fmaf(h1.y, w[5], acc[e]);
            acc[e] = fmaf(h1.z, w[6], acc[e]); acc[e] = fmaf(h1.w, w[7], acc[e]);
        }
    }
#pragma unroll
    for (int e = 0; e < 16; e++) hid[e][j] = fmaxf(acc[e], 0.f);
    __syncthreads();
    if (j < 48) {
        int e = j / 3, ch = j - 3 * (j / 3);
        float s = b2[ch];
        for (int k = 0; k < 128; k++) s = fmaf(hid[e][k], w2[k * 3 + ch], s);
        out[(size_t)(base + e) * 3 + ch] = s;
    }
}

// ---------------- launch ----------------

extern "C" void kernel_launch(void* const* d_in, const int* in_sizes, int n_in,
                              void* d_out, int out_size, void* d_ws, size_t ws_size,
                              hipStream_t stream) {
    (void)in_sizes; (void)n_in; (void)out_size; (void)ws_size;
    const float* pos   = (const float*)d_in[0];
    const float* vel   = (const float*)d_in[1];
    const int*   rid   = (const int*)d_in[2];
    const int*   snd   = (const int*)d_in[3];
    const int*   rcv   = (const int*)d_in[4];
    const float* remb  = (const float*)d_in[5];
    const float* ne_w1 = (const float*)d_in[6];
    const float* ne_b1 = (const float*)d_in[7];
    const float* ne_w2 = (const float*)d_in[8];
    const float* ne_b2 = (const float*)d_in[9];
    const float* ee_w1 = (const float*)d_in[10];
    const float* ee_b1 = (const float*)d_in[11];
    const float* ee_w2 = (const float*)d_in[12];
    const float* ee_b2 = (const float*)d_in[13];
    const float* pe_w1 = (const float*)d_in[14];
    const float* pe_b1 = (const float*)d_in[15];
    const float* pe_w2 = (const float*)d_in[16];
    const float* pe_b2 = (const float*)d_in[17];
    const float* pn_w1 = (const float*)d_in[18];
    const float* pn_b1 = (const float*)d_in[19];
    const float* pn_w2 = (const float*)d_in[20];
    const float* pn_b2 = (const float*)d_in[21];
    const float* de_w1 = (const float*)d_in[22];
    const float* de_b1 = (const float*)d_in[23];
    const float* de_w2 = (const float*)d_in[24];
    const float* de_b2 = (const float*)d_in[25];
    float* out = (float*)d_out;

    // workspace carve (~250.6e6 B — under the 256.2e6 proven available)
    char* p = (char*)d_ws;
    auto carve = [&](size_t bytes) { void* q = (void*)p; p += (bytes + 15) & ~(size_t)15; return q; };
    unsigned short* el    = (unsigned short*)carve((size_t)NE * LDIM * 2);   // 204.8e6, CSR order
    unsigned short* nlh   = (unsigned short*)carve((size_t)NN * LDIM * 2);   // 12.8e6
    unsigned short* nll   = (unsigned short*)carve((size_t)NN * LDIM * 2);   // 12.8e6
    unsigned short* agg   = (unsigned short*)carve((size_t)NN * LDIM * 2);   // 12.8e6 (bf16)
    unsigned short* w1f_e = (unsigned short*)carve((size_t)NSTEPS * 12 * 8 * 512 * 2);
    unsigned short* w2f_e = (unsigned short*)carve((size_t)NSTEPS * 4 * 8 * 512 * 2);
    unsigned short* w1h_n = (unsigned short*)carve((size_t)NSTEPS * 8 * 8 * 512 * 2);
    unsigned short* w1l_n = (unsigned short*)carve((size_t)NSTEPS * 8 * 8 * 512 * 2);
    unsigned short* w2h_n = (unsigned short*)carve((size_t)NSTEPS * 4 * 8 * 512 * 2);
    unsigned short* w2l_n = (unsigned short*)carve((size_t)NSTEPS * 4 * 8 * 512 * 2);
    unsigned short* eew1h = (unsigned short*)carve((size_t)1 * 8 * 512 * 2);
    unsigned short* eew1l = (unsigned short*)carve((size_t)1 * 8 * 512 * 2);
    unsigned short* eew2h = (unsigned short*)carve((size_t)4 * 8 * 512 * 2);
    unsigned short* eew2l = (unsigned short*)carve((size_t)4 * 8 * 512 * 2);
    unsigned short* new1h = (unsigned short*)carve((size_t)1 * 8 * 512 * 2);
    unsigned short* new1l = (unsigned short*)carve((size_t)1 * 8 * 512 * 2);
    unsigned short* new2h = (unsigned short*)carve((size_t)4 * 8 * 512 * 2);
    unsigned short* new2l = (unsigned short*)carve((size_t)4 * 8 * 512 * 2);
    unsigned short* snd_p = (unsigned short*)carve((size_t)NE * 2);          // 1.6e6
    unsigned short* rcv_p = (unsigned short*)carve((size_t)NE * 2);          // 1.6e6
    int*            rs    = (int*)carve((size_t)(NN + 1) * 4);
    int*            cnt   = (int*)carve((size_t)NN * 4);
    int*            cur   = (int*)carve((size_t)NN * 4);
    float*          degf  = (float*)carve((size_t)NN * 4);
    float*          csum  = (float*)carve(16);

    hipMemsetAsync(cnt, 0, (size_t)NN * 4, stream);
    hipMemsetAsync(csum, 0, 16, stream);
    k_hist<<<NE / 256, 256, 0, stream>>>(rcv, cnt);
    k_scan<<<1, 1024, 0, stream>>>(cnt, rs, cur, degf);
    k_center<<<64, 256, 0, stream>>>(pos, csum);
    k_scatter<<<NE / 256, 256, 0, stream>>>(snd, rcv, cur, snd_p, rcv_p);
    k_prep_w<<<NSTEPS * 12 * 8, 64, 0, stream>>>(pe_w1, w1f_e, 12, 384, 0);
    k_prep_w<<<NSTEPS * 4 * 8, 64, 0, stream>>>(pe_w2, w2f_e, 4, 128, 0);
    k_prep_w<<<NSTEPS * 8 * 8, 64, 0, stream>>>(pn_w1, w1h_n, 8, 256, 0);
    k_prep_w<<<NSTEPS * 8 * 8, 64, 0, stream>>>(pn_w1, w1l_n, 8, 256, 1);
    k_prep_w<<<NSTEPS * 4 * 8, 64, 0, stream>>>(pn_w2, w2h_n, 4, 128, 0);
    k_prep_w<<<NSTEPS * 4 * 8, 64, 0, stream>>>(pn_w2, w2l_n, 4, 128, 1);
    k_prep_w<<<8, 64, 0, stream>>>(ee_w1, eew1h, 1, 9, 0);
    k_prep_w<<<8, 64, 0, stream>>>(ee_w1, eew1l, 1, 9, 1);
    k_prep_w<<<4 * 8, 64, 0, stream>>>(ee_w2, eew2h, 4, 128, 0);
    k_prep_w<<<4 * 8, 64, 0, stream>>>(ee_w2, eew2l, 4, 128, 1);
    k_prep_w<<<8, 64, 0, stream>>>(ne_w1, new1h, 1, 23, 0);
    k_prep_w<<<8, 64, 0, stream>>>(ne_w1, new1l, 1, 23, 1);
    k_prep_w<<<4 * 8, 64, 0, stream>>>(ne_w2, new2h, 4, 128, 0);
    k_prep_w<<<4 * 8, 64, 0, stream>>>(ne_w2, new2l, 4, 128, 1);

    k_node_enc_m<<<(NN + 127) / 128, 256, 0, stream>>>(pos, vel, rid, remb, degf, csum,
                                                       new1h, new1l, ne_b1, new2h, new2l, ne_b2, nlh, nll);
    k_edge_enc_m<<<NE / 128, 256, 0, stream>>>(pos, vel, rid, snd_p, rcv_p,
                                               eew1h, eew1l, ee_b1, eew2h, eew2l, ee_b2, el);
    for (int i = 0; i < NSTEPS; i++) {
        k_edge_step<<<NE / 128, 256, 0, stream>>>(el, nlh, snd_p, rcv_p,
            w1f_e + (size_t)i * 12 * 8 * 512, pe_b1 + i * 128,
            w2f_e + (size_t)i * 4 * 8 * 512, pe_b2 + i * 128);
        k_agg<<<(NN + 3) / 4, 256, 0, stream>>>(el, rs, agg);
        k_node_step_s<<<(NN + 63) / 64, 256, 0, stream>>>(nlh, nll, agg,
            w1h_n + (size_t)i * 8 * 8 * 512, w1l_n + (size_t)i * 8 * 8 * 512, pn_b1 + i * 128,
            w2h_n + (size_t)i * 4 * 8 * 512, w2l_n + (size_t)i * 4 * 8 * 512, pn_b2 + i * 128);
    }
    k_decode<<<NN / 16, 128, 0, stream>>>(nlh, nll, de_w1, de_b1, de_w2, de_b2, out);
}

// Round 12
// 2862.554 us; speedup vs baseline: 1.7911x; 1.0098x over previous
//
#include <hip/hip_runtime.h>
#include <hip/hip_bf16.h>

#define NN 50000
#define NE 800000
#define LDIM 128
#define NSTEPS 10

typedef __hip_bfloat16 bf16;
typedef __bf16 bf8v __attribute__((ext_vector_type(8)));
typedef float f4v __attribute__((ext_vector_type(4)));
typedef unsigned short u16x8 __attribute__((ext_vector_type(8)));

__device__ inline float bflo(unsigned int u) {
    union { unsigned int i; float f; } x; x.i = u << 16; return x.f;
}
__device__ inline float bfhi(unsigned int u) {
    union { unsigned int i; float f; } x; x.i = u & 0xffff0000u; return x.f;
}
__device__ inline unsigned short f2bf(float f) {
    __hip_bfloat16 h = __float2bfloat16(f);
    unsigned short u; __builtin_memcpy(&u, &h, 2); return u;
}

// async global->LDS DMA, 16 B per lane. LDS dest is wave-uniform base + lane*16
// (linear); global src is per-lane. Drained by the vmcnt(0) the compiler emits
// at the next __syncthreads.
__device__ __forceinline__ void gl_lds16(const void* g, void* l) {
    __builtin_amdgcn_global_load_lds(
        (const __attribute__((address_space(1))) unsigned int*)g,
        (__attribute__((address_space(3))) unsigned int*)l, 16, 0, 0);
}

// ---------------- CSR build: histogram, scan, scatter (ushort permuted endpoints) ----------------

__global__ void k_hist(const int* __restrict__ rcv, int* __restrict__ cnt) {
    int i = blockIdx.x * 256 + threadIdx.x;
    if (i < NE) atomicAdd(&cnt[rcv[i]], 1);
}

__global__ __launch_bounds__(1024) void k_scan(
    const int* __restrict__ cnt, int* __restrict__ row_start,
    int* __restrict__ cur, float* __restrict__ degf) {
    __shared__ int part[1024];
    const int t = threadIdx.x;
    const int CH = (NN + 1023) / 1024;  // 49
    int b0 = t * CH, b1 = b0 + CH; if (b1 > NN) b1 = NN; if (b0 > NN) b0 = NN;
    int s = 0;
    for (int i = b0; i < b1; i++) s += cnt[i];
    part[t] = s;
    __syncthreads();
    for (int off = 1; off < 1024; off <<= 1) {
        int v = (t >= off) ? part[t - off] : 0;
        __syncthreads();
        part[t] += v;
        __syncthreads();
    }
    int run = part[t] - s;  // exclusive prefix
    for (int i = b0; i < b1; i++) {
        row_start[i] = run; cur[i] = run; degf[i] = (float)cnt[i];
        run += cnt[i];
    }
    if (t == 1023) row_start[NN] = part[1023];
}

__global__ void k_scatter(const int* __restrict__ snd, const int* __restrict__ rcv,
                          int* __restrict__ cur,
                          unsigned short* __restrict__ snd_p, unsigned short* __restrict__ rcv_p) {
    int i = blockIdx.x * 256 + threadIdx.x;
    if (i < NE) {
        int r = rcv[i];
        int p = atomicAdd(&cur[r], 1);
        snd_p[p] = (unsigned short)snd[i];
        rcv_p[p] = (unsigned short)r;
    }
}

__global__ void k_center(const float* __restrict__ pos, float* __restrict__ csum) {
    __shared__ float s[3][256];
    float a = 0.f, b = 0.f, c = 0.f;
    for (int i = blockIdx.x * 256 + threadIdx.x; i < NN; i += gridDim.x * 256) {
        a += pos[3 * i]; b += pos[3 * i + 1]; c += pos[3 * i + 2];
    }
    int t = threadIdx.x;
    s[0][t] = a; s[1][t] = b; s[2][t] = c;
    __syncthreads();
    for (int off = 128; off > 0; off >>= 1) {
        if (t < off) {
            s[0][t] += s[0][t + off];
            s[1][t] += s[1][t + off];
            s[2][t] += s[2][t + off];
        }
        __syncthreads();
    }
    if (t == 0) {
        atomicAdd(&csum[0], s[0][0]);
        atomicAdd(&csum[1], s[1][0]);
        atomicAdd(&csum[2], s[2][0]);
    }
}

// ---------------- weight prep: fp32 -> bf16 B-frag order; lo=1 emits bf16(x - bf16(x)) ----------------

__global__ void k_prep_w(const float* __restrict__ w, unsigned short* __restrict__ wf,
                         int KT, int Ksrc, int lo) {
    int b = blockIdx.x;
    int s = b / (KT * 8), rem = b % (KT * 8);
    int kt = rem / 8, nt = rem % 8;
    int lane = threadIdx.x, col = lane & 15, quad = lane >> 4;
    const float* W = w + (size_t)s * Ksrc * 128;
    u16x8 o;
#pragma unroll
    for (int jj = 0; jj < 8; jj++) {
        int k = kt * 32 + quad * 8 + jj;
        float x = (k < Ksrc) ? W[(size_t)k * 128 + nt * 16 + col] : 0.f;
        unsigned short h = f2bf(x);
        if (lo) h = f2bf(x - bflo(h));
        o[jj] = h;
    }
    *(u16x8*)(wf + (((size_t)b) * 64 + lane) * 8) = o;
}

// ---------------- CSR aggregation: streaming reduction el (CSR order) -> bf16 agg ----------------

__global__ __launch_bounds__(256) void k_agg(
    const unsigned short* __restrict__ el, const int* __restrict__ row_start,
    unsigned short* __restrict__ agg) {
    const int wave = threadIdx.x >> 6, lane = threadIdx.x & 63;
    const int n = blockIdx.x * 4 + wave;
    if (n >= NN) return;
    const int sub = lane >> 4, c16 = lane & 15;
    const int st = row_start[n], en = row_start[n + 1];
    float s[8];
#pragma unroll
    for (int k = 0; k < 8; k++) s[k] = 0.f;
    for (int q = st + sub; q < en; q += 4) {
        uint4 v = *(const uint4*)(el + (size_t)q * 128 + c16 * 8);
        s[0] += bflo(v.x); s[1] += bfhi(v.x);
        s[2] += bflo(v.y); s[3] += bfhi(v.y);
        s[4] += bflo(v.z); s[5] += bfhi(v.z);
        s[6] += bflo(v.w); s[7] += bfhi(v.w);
    }
#pragma unroll
    for (int k = 0; k < 8; k++) {
        s[k] += __shfl_xor(s[k], 16);
        s[k] += __shfl_xor(s[k], 32);
    }
    if (sub == 0) {
        u16x8 o;
#pragma unroll
        for (int k = 0; k < 8; k++) o[k] = f2bf(s[k]);
        *(u16x8*)(agg + (size_t)n * 128 + c16 * 8) = o;
    }
}

// ---------------- MFMA node encoder (split-precision): feat(23 pad 32, hi|lo) -> 128 -> 128 ----------------
// Output: node latent as bf16 hi/lo pair (nlh, nll).

__global__ __launch_bounds__(256) void k_node_enc_m(
    const float* __restrict__ pos, const float* __restrict__ vel,
    const int* __restrict__ rid, const float* __restrict__ remb,
    const float* __restrict__ degf, const float* __restrict__ csum,
    const unsigned short* __restrict__ w1h, const unsigned short* __restrict__ w1l,
    const float* __restrict__ b1,
    const unsigned short* __restrict__ w2h, const unsigned short* __restrict__ w2l,
    const float* __restrict__ b2,
    unsigned short* __restrict__ nlh, unsigned short* __restrict__ nll) {
    __shared__ __align__(16) unsigned short feat_s[32 * 72];   // [hi(32)|lo(32)|pad]
    __shared__ __align__(16) unsigned short hid_s[32 * 264];   // [hi(128)|lo(128)|pad]
    const int tid = threadIdx.x, wave = tid >> 6, lane = tid & 63;
    const int col = lane & 15, quad = lane >> 4;
    bf8v W1H[2], W1L[2], W2H[4][2], W2L[4][2];
#pragma unroll
    for (int t = 0; t < 2; t++) {
        W1H[t] = *(const bf8v*)(w1h + ((size_t)(2 * wave + t) * 64 + lane) * 8);
        W1L[t] = *(const bf8v*)(w1l + ((size_t)(2 * wave + t) * 64 + lane) * 8);
    }
#pragma unroll
    for (int kt = 0; kt < 4; kt++)
#pragma unroll
        for (int t = 0; t < 2; t++) {
            W2H[kt][t] = *(const bf8v*)(w2h + ((size_t)(kt * 8 + 2 * wave + t) * 64 + lane) * 8);
            W2L[kt][t] = *(const bf8v*)(w2l + ((size_t)(kt * 8 + 2 * wave + t) * 64 + lane) * 8);
        }
    float bias1[2], bias2[2];
#pragma unroll
    for (int t = 0; t < 2; t++) {
        bias1[t] = b1[(2 * wave + t) * 16 + col];
        bias2[t] = b2[(2 * wave + t) * 16 + col];
    }
    float cx = csum[0] * (1.0f / NN), cy = csum[1] * (1.0f / NN), cz = csum[2] * (1.0f / NN);
    uint4 z = {0u, 0u, 0u, 0u};
    for (int s2 = tid; s2 < 288; s2 += 256) *(uint4*)(feat_s + s2 * 8) = z;  // zero K-pad

    for (int it = 0; it < 4; it++) {
        const int base = blockIdx.x * 128 + it * 32;
        if (base >= NN) break;
        __syncthreads();
        if (tid < 32) {
            int n = base + tid; if (n > NN - 1) n = NN - 1;
            float v[23];
            v[0] = vel[3 * n]; v[1] = vel[3 * n + 1]; v[2] = vel[3 * n + 2];
            v[3] = pos[3 * n] - cx; v[4] = pos[3 * n + 1] - cy; v[5] = pos[3 * n + 2] - cz;
            v[6] = degf[n];
            int rb = rid[n] * 16;
#pragma unroll
            for (int k = 0; k < 16; k++) v[7 + k] = remb[rb + k];
            unsigned short* f = feat_s + tid * 72;
#pragma unroll
            for (int k = 0; k < 23; k++) {
                unsigned short h = f2bf(v[k]);
                f[k] = h; f[32 + k] = f2bf(v[k] - bflo(h));
            }
        }
        __syncthreads();
        f4v acc[2][2];
#pragma unroll
        for (int mt = 0; mt < 2; mt++)
#pragma unroll
            for (int t = 0; t < 2; t++) acc[mt][t] = (f4v){0.f, 0.f, 0.f, 0.f};
        {
            bf8v a0h = *(const bf8v*)(feat_s + col * 72 + quad * 8);
            bf8v a1h = *(const bf8v*)(feat_s + (16 + col) * 72 + quad * 8);
            bf8v a0l = *(const bf8v*)(feat_s + col * 72 + 32 + quad * 8);
            bf8v a1l = *(const bf8v*)(feat_s + (16 + col) * 72 + 32 + quad * 8);
#pragma unroll
            for (int t = 0; t < 2; t++) {
                acc[0][t] = __builtin_amdgcn_mfma_f32_16x16x32_bf16(a0h, W1H[t], acc[0][t], 0, 0, 0);
                acc[1][t] = __builtin_amdgcn_mfma_f32_16x16x32_bf16(a1h, W1H[t], acc[1][t], 0, 0, 0);
                acc[0][t] = __builtin_amdgcn_mfma_f32_16x16x32_bf16(a0l, W1H[t], acc[0][t], 0, 0, 0);
                acc[1][t] = __builtin_amdgcn_mfma_f32_16x16x32_bf16(a1l, W1H[t], acc[1][t], 0, 0, 0);
                acc[0][t] = __builtin_amdgcn_mfma_f32_16x16x32_bf16(a0h, W1L[t], acc[0][t], 0, 0, 0);
                acc[1][t] = __builtin_amdgcn_mfma_f32_16x16x32_bf16(a1h, W1L[t], acc[1][t], 0, 0, 0);
            }
        }
#pragma unroll
        for (int mt = 0; mt < 2; mt++)
#pragma unroll
            for (int t = 0; t < 2; t++) {
                const int nc = (2 * wave + t) * 16 + col;
#pragma unroll
                for (int r = 0; r < 4; r++) {
                    float h = fmaxf(acc[mt][t][r] + bias1[t], 0.f);
                    unsigned short hh = f2bf(h);
                    hid_s[(mt * 16 + quad * 4 + r) * 264 + nc] = hh;
                    hid_s[(mt * 16 + quad * 4 + r) * 264 + 128 + nc] = f2bf(h - bflo(hh));
                }
            }
        __syncthreads();
#pragma unroll
        for (int mt = 0; mt < 2; mt++)
#pragma unroll
            for (int t = 0; t < 2; t++) acc[mt][t] = (f4v){0.f, 0.f, 0.f, 0.f};
#pragma unroll
        for (int kt = 0; kt < 8; kt++) {
            int w = kt & 3;
            bf8v a0 = *(const bf8v*)(hid_s + col * 264 + kt * 32 + quad * 8);
            bf8v a1 = *(const bf8v*)(hid_s + (16 + col) * 264 + kt * 32 + quad * 8);
#pragma unroll
            for (int t = 0; t < 2; t++) {
                acc[0][t] = __builtin_amdgcn_mfma_f32_16x16x32_bf16(a0, W2H[w][t], acc[0][t], 0, 0, 0);
                acc[1][t] = __builtin_amdgcn_mfma_f32_16x16x32_bf16(a1, W2H[w][t], acc[1][t], 0, 0, 0);
            }
        }
#pragma unroll
        for (int kt = 0; kt < 4; kt++) {
            bf8v a0 = *(const bf8v*)(hid_s + col * 264 + kt * 32 + quad * 8);
            bf8v a1 = *(const bf8v*)(hid_s + (16 + col) * 264 + kt * 32 + quad * 8);
#pragma unroll
            for (int t = 0; t < 2; t++) {
                acc[0][t] = __builtin_amdgcn_mfma_f32_16x16x32_bf16(a0, W2L[kt][t], acc[0][t], 0, 0, 0);
                acc[1][t] = __builtin_amdgcn_mfma_f32_16x16x32_bf16(a1, W2L[kt][t], acc[1][t], 0, 0, 0);
            }
        }
        __syncthreads();  // all hid reads done; overwrite with output hi/lo
#pragma unroll
        for (int mt = 0; mt < 2; mt++)
#pragma unroll
            for (int t = 0; t < 2; t++) {
                const int nc = (2 * wave + t) * 16 + col;
#pragma unroll
                for (int r = 0; r < 4; r++) {
                    const int row = mt * 16 + quad * 4 + r;
                    float v = acc[mt][t][r] + bias2[t];
                    unsigned short hh = f2bf(v);
                    hid_s[row * 264 + nc] = hh;
                    hid_s[row * 264 + 128 + nc] = f2bf(v - bflo(hh));
                }
            }
        __syncthreads();
#pragma unroll
        for (int p = 0; p < 2; p++) {
            int s2 = p * 256 + tid, e = s2 >> 4, c16 = s2 & 15;
            if (base + e < NN) {
                *(uint4*)(nlh + (size_t)(base + e) * 128 + c16 * 8) =
                    *(const uint4*)(hid_s + e * 264 + c16 * 8);
                *(uint4*)(nll + (size_t)(base + e) * 128 + c16 * 8) =
                    *(const uint4*)(hid_s + e * 264 + 128 + c16 * 8);
            }
        }
    }
}

// ---------------- MFMA edge encoder (split-precision): feat(9 pad 32, hi|lo) -> 128 -> 128 ----------------

__global__ __launch_bounds__(256) void k_edge_enc_m(
    const float* __restrict__ pos, const float* __restrict__ vel,
    const int* __restrict__ rid,
    const unsigned short* __restrict__ snd, const unsigned short* __restrict__ rcv,
    const unsigned short* __restrict__ w1h, const unsigned short* __restrict__ w1l,
    const float* __restrict__ b1,
    const unsigned short* __restrict__ w2h, const unsigned short* __restrict__ w2l,
    const float* __restrict__ b2,
    unsigned short* __restrict__ el) {
    __shared__ __align__(16) unsigned short feat_s[32 * 72];
    __shared__ __align__(16) unsigned short hid_s[32 * 264];
    const int tid = threadIdx.x, wave = tid >> 6, lane = tid & 63;
    const int col = lane & 15, quad = lane >> 4;
    bf8v W1H[2], W1L[2], W2H[4][2], W2L[4][2];
#pragma unroll
    for (int t = 0; t < 2; t++) {
        W1H[t] = *(const bf8v*)(w1h + ((size_t)(2 * wave + t) * 64 + lane) * 8);
        W1L[t] = *(const bf8v*)(w1l + ((size_t)(2 * wave + t) * 64 + lane) * 8);
    }
#pragma unroll
    for (int kt = 0; kt < 4; kt++)
#pragma unroll
        for (int t = 0; t < 2; t++) {
            W2H[kt][t] = *(const bf8v*)(w2h + ((size_t)(kt * 8 + 2 * wave + t) * 64 + lane) * 8);
            W2L[kt][t] = *(const bf8v*)(w2l + ((size_t)(kt * 8 + 2 * wave + t) * 64 + lane) * 8);
        }
    float bias1[2], bias2[2];
#pragma unroll
    for (int t = 0; t < 2; t++) {
        bias1[t] = b1[(2 * wave + t) * 16 + col];
        bias2[t] = b2[(2 * wave + t) * 16 + col];
    }
    uint4 z = {0u, 0u, 0u, 0u};
    for (int s2 = tid; s2 < 288; s2 += 256) *(uint4*)(feat_s + s2 * 8) = z;

    for (int it = 0; it < 4; it++) {
        const int base = blockIdx.x * 128 + it * 32;
        __syncthreads();
        if (tid < 32) {
            int e = base + tid;
            int s = snd[e], r = rcv[e];
            float v[9];
            v[0] = pos[3 * s] - pos[3 * r]; v[1] = pos[3 * s + 1] - pos[3 * r + 1]; v[2] = pos[3 * s + 2] - pos[3 * r + 2];
            v[3] = vel[3 * s] - vel[3 * r]; v[4] = vel[3 * s + 1] - vel[3 * r + 1]; v[5] = vel[3 * s + 2] - vel[3 * r + 2];
            float sq = v[0] * v[0] + v[1] * v[1] + v[2] * v[2];
            v[6] = sqrtf(sq); v[7] = sq;
            v[8] = (rid[s] == rid[r]) ? 1.f : 0.f;
            unsigned short* f = feat_s + tid * 72;
#pragma unroll
            for (int k = 0; k < 9; k++) {
                unsigned short h = f2bf(v[k]);
                f[k] = h; f[32 + k] = f2bf(v[k] - bflo(h));
            }
        }
        __syncthreads();
        f4v acc[2][2];
#pragma unroll
        for (int mt = 0; mt < 2; mt++)
#pragma unroll
            for (int t = 0; t < 2; t++) acc[mt][t] = (f4v){0.f, 0.f, 0.f, 0.f};
        {
            bf8v a0h = *(const bf8v*)(feat_s + col * 72 + quad * 8);
            bf8v a1h = *(const bf8v*)(feat_s + (16 + col) * 72 + quad * 8);
            bf8v a0l = *(const bf8v*)(feat_s + col * 72 + 32 + quad * 8);
            bf8v a1l = *(const bf8v*)(feat_s + (16 + col) * 72 + 32 + quad * 8);
#pragma unroll
            for (int t = 0; t < 2; t++) {
                acc[0][t] = __builtin_amdgcn_mfma_f32_16x16x32_bf16(a0h, W1H[t], acc[0][t], 0, 0, 0);
                acc[1][t] = __builtin_amdgcn_mfma_f32_16x16x32_bf16(a1h, W1H[t], acc[1][t], 0, 0, 0);
                acc[0][t] = __builtin_amdgcn_mfma_f32_16x16x32_bf16(a0l, W1H[t], acc[0][t], 0, 0, 0);
                acc[1][t] = __builtin_amdgcn_mfma_f32_16x16x32_bf16(a1l, W1H[t], acc[1][t], 0, 0, 0);
                acc[0][t] = __builtin_amdgcn_mfma_f32_16x16x32_bf16(a0h, W1L[t], acc[0][t], 0, 0, 0);
                acc[1][t] = __builtin_amdgcn_mfma_f32_16x16x32_bf16(a1h, W1L[t], acc[1][t], 0, 0, 0);
            }
        }
#pragma unroll
        for (int mt = 0; mt < 2; mt++)
#pragma unroll
            for (int t = 0; t < 2; t++) {
                const int nc = (2 * wave + t) * 16 + col;
#pragma unroll
                for (int r = 0; r < 4; r++) {
                    float h = fmaxf(acc[mt][t][r] + bias1[t], 0.f);
                    unsigned short hh = f2bf(h);
                    hid_s[(mt * 16 + quad * 4 + r) * 264 + nc] = hh;
                    hid_s[(mt * 16 + quad * 4 + r) * 264 + 128 + nc] = f2bf(h - bflo(hh));
                }
            }
        __syncthreads();
#pragma unroll
        for (int mt = 0; mt < 2; mt++)
#pragma unroll
            for (int t = 0; t < 2; t++) acc[mt][t] = (f4v){0.f, 0.f, 0.f, 0.f};
#pragma unroll
        for (int kt = 0; kt < 8; kt++) {
            int w = kt & 3;
            bf8v a0 = *(const bf8v*)(hid_s + col * 264 + kt * 32 + quad * 8);
            bf8v a1 = *(const bf8v*)(hid_s + (16 + col) * 264 + kt * 32 + quad * 8);
#pragma unroll
            for (int t = 0; t < 2; t++) {
                acc[0][t] = __builtin_amdgcn_mfma_f32_16x16x32_bf16(a0, W2H[w][t], acc[0][t], 0, 0, 0);
                acc[1][t] = __builtin_amdgcn_mfma_f32_16x16x32_bf16(a1, W2H[w][t], acc[1][t], 0, 0, 0);
            }
        }
#pragma unroll
        for (int kt = 0; kt < 4; kt++) {
            bf8v a0 = *(const bf8v*)(hid_s + col * 264 + kt * 32 + quad * 8);
            bf8v a1 = *(const bf8v*)(hid_s + (16 + col) * 264 + kt * 32 + quad * 8);
#pragma unroll
            for (int t = 0; t < 2; t++) {
                acc[0][t] = __builtin_amdgcn_mfma_f32_16x16x32_bf16(a0, W2L[kt][t], acc[0][t], 0, 0, 0);
                acc[1][t] = __builtin_amdgcn_mfma_f32_16x16x32_bf16(a1, W2L[kt][t], acc[1][t], 0, 0, 0);
            }
        }
        __syncthreads();
#pragma unroll
        for (int mt = 0; mt < 2; mt++)
#pragma unroll
            for (int t = 0; t < 2; t++) {
                const int nc = (2 * wave + t) * 16 + col;
#pragma unroll
                for (int r = 0; r < 4; r++)
                    hid_s[(mt * 16 + quad * 4 + r) * 264 + nc] = f2bf(acc[mt][t][r] + bias2[t]);
            }
        __syncthreads();
#pragma unroll
        for (int p = 0; p < 2; p++) {
            int s2 = p * 256 + tid, e = s2 >> 4, c16 = s2 & 15;
            *(uint4*)(el + (size_t)(base + e) * 128 + c16 * 8) =
                *(const uint4*)(hid_s + e * 264 + c16 * 8);
        }
    }
}

// ---------------- MFMA edge processor step (CSR order) ----------------
// v13 = v6 + separate out_s buffer (the ONE un-isolated piece of v7's bundle):
// epilogue writes out_s instead of overwriting hid_s, removing the WAR barrier
// between layer-2's LDS reads and the epilogue (4 -> 3 barriers/tile). LDS
// 57.9 -> 66.4 KB, still 2 blocks/CU (v7 confirmed no spill at this size).
// Everything else identical to v6 (2887/2890 us verified twice).

__global__ __launch_bounds__(256) void k_edge_step(
    unsigned short* __restrict__ el, const unsigned short* __restrict__ nlh,
    const unsigned short* __restrict__ snd, const unsigned short* __restrict__ rcv,
    const unsigned short* __restrict__ w1f, const float* __restrict__ b1,
    const unsigned short* __restrict__ w2f, const float* __restrict__ b2) {
    __shared__ __align__(1024) unsigned short stage_s[2][3][32][128];  // 48 KB
    __shared__ __align__(16) unsigned short hid_s[32 * 136];           // 8.5 KB
    __shared__ __align__(16) unsigned short out_s[32 * 136];           // 8.5 KB
    const int tid = threadIdx.x;
    const int wave = tid >> 6, lane = tid & 63;
    const int col = lane & 15, quad = lane >> 4;
    const int erow = tid >> 4, c16 = tid & 15;

    bf8v W1[12][2], W2[4][2];
#pragma unroll
    for (int kt = 0; kt < 12; kt++)
#pragma unroll
        for (int t = 0; t < 2; t++)
            W1[kt][t] = *(const bf8v*)(w1f + ((size_t)(kt * 8 + 2 * wave + t) * 64 + lane) * 8);
#pragma unroll
    for (int kt = 0; kt < 4; kt++)
#pragma unroll
        for (int t = 0; t < 2; t++)
            W2[kt][t] = *(const bf8v*)(w2f + ((size_t)(kt * 8 + 2 * wave + t) * 64 + lane) * 8);
    float bias1[2], bias2[2];
#pragma unroll
    for (int t = 0; t < 2; t++) {
        bias1[t] = b1[(2 * wave + t) * 16 + col];
        bias2[t] = b2[(2 * wave + t) * 16 + col];
    }

    // staging geometry: wave stages rows [wave*8, wave*8+8) of each stream,
    // 2 instructions x 1024 B. lane covers row = wave*8 + i*4 + (lane>>4),
    // 16 B at byte (lane&15)*16 within the row. Global source pre-swizzled.
    const int srow0 = wave * 8 + (lane >> 4);
    const int srow1 = srow0 + 4;
    const int skb = (lane & 15) * 16;
    const int soff0 = skb ^ ((srow0 & 7) << 4);
    const int soff1 = skb ^ ((srow1 & 7) << 4);
    const int gb0 = blockIdx.x * 128;
    const char* elc = (const char*)el;
    const char* nlc = (const char*)nlh;

    auto issue = [&](int t, int b, int si0, int si1, int ri0, int ri1) {
        char* s0 = (char*)&stage_s[b][0][wave * 8][0];
        char* s1 = (char*)&stage_s[b][1][wave * 8][0];
        char* s2 = (char*)&stage_s[b][2][wave * 8][0];
        const size_t gb = (size_t)(gb0 + t * 32);
        gl_lds16(elc + (gb + srow0) * 256 + soff0, s0);
        gl_lds16(elc + (gb + srow1) * 256 + soff1, s0 + 1024);
        gl_lds16(nlc + (size_t)si0 * 256 + soff0, s1);
        gl_lds16(nlc + (size_t)si1 * 256 + soff1, s1 + 1024);
        gl_lds16(nlc + (size_t)ri0 * 256 + soff0, s2);
        gl_lds16(nlc + (size_t)ri1 * 256 + soff1, s2 + 1024);
    };

    // prologue: issue tile 0; preload gather indices for tile 1
    {
        int si0 = snd[gb0 + srow0], si1 = snd[gb0 + srow1];
        int ri0 = rcv[gb0 + srow0], ri1 = rcv[gb0 + srow1];
        issue(0, 0, si0, si1, ri0, ri1);
    }
    int nsi0 = snd[gb0 + 32 + srow0], nsi1 = snd[gb0 + 32 + srow1];
    int nri0 = rcv[gb0 + 32 + srow0], nri1 = rcv[gb0 + 32 + srow1];

    for (int it = 0; it < 4; it++) {
        const int cur = it & 1, nxt = cur ^ 1;
        const int base = gb0 + it * 32;
        __syncthreads();  // B0: cur staged+visible; prev stores' out_s reads done
        if (it < 3) {
            issue(it + 1, nxt, nsi0, nsi1, nri0, nri1);  // drains at B1 (under L1)
            if (it < 2) {
                int gb = gb0 + (it + 2) * 32;
                nsi0 = snd[gb + srow0]; nsi1 = snd[gb + srow1];
                nri0 = rcv[gb + srow0]; nri1 = rcv[gb + srow1];
            }
        }

        // ---- layer 1: K=384 over [el|snd|rcv] buffers (swizzled reads) ----
        f4v acc[2][2];
#pragma unroll
        for (int mt = 0; mt < 2; mt++)
#pragma unroll
            for (int t = 0; t < 2; t++) acc[mt][t] = (f4v){0.f, 0.f, 0.f, 0.f};
        const int sw = (col & 7) << 4;
#pragma unroll
        for (int kt = 0; kt < 12; kt++) {
            const char* sb = (const char*)&stage_s[cur][kt >> 2][0][0];
            const int kb = (kt & 3) * 64 + quad * 16;
            bf8v a0 = *(const bf8v*)(sb + col * 256 + (kb ^ sw));
            bf8v a1 = *(const bf8v*)(sb + (16 + col) * 256 + (kb ^ sw));
            acc[0][0] = __builtin_amdgcn_mfma_f32_16x16x32_bf16(a0, W1[kt][0], acc[0][0], 0, 0, 0);
            acc[0][1] = __builtin_amdgcn_mfma_f32_16x16x32_bf16(a0, W1[kt][1], acc[0][1], 0, 0, 0);
            acc[1][0] = __builtin_amdgcn_mfma_f32_16x16x32_bf16(a1, W1[kt][0], acc[1][0], 0, 0, 0);
            acc[1][1] = __builtin_amdgcn_mfma_f32_16x16x32_bf16(a1, W1[kt][1], acc[1][1], 0, 0, 0);
        }
#pragma unroll
        for (int mt = 0; mt < 2; mt++)
#pragma unroll
            for (int t = 0; t < 2; t++) {
                const int nc = (2 * wave + t) * 16 + col;
#pragma unroll
                for (int r = 0; r < 4; r++) {
                    float v = fmaxf(acc[mt][t][r] + bias1[t], 0.f);
                    hid_s[(mt * 16 + quad * 4 + r) * 136 + nc] = f2bf(v);
                }
            }
        __syncthreads();  // B1: hid visible; prefetch vmcnt drained here

        // ---- layer 2 ----
#pragma unroll
        for (int mt = 0; mt < 2; mt++)
#pragma unroll
            for (int t = 0; t < 2; t++) acc[mt][t] = (f4v){0.f, 0.f, 0.f, 0.f};
#pragma unroll
        for (int kt = 0; kt < 4; kt++) {
            bf8v a0 = *(const bf8v*)(hid_s + col * 136 + kt * 32 + quad * 8);
            bf8v a1 = *(const bf8v*)(hid_s + (16 + col) * 136 + kt * 32 + quad * 8);
            acc[0][0] = __builtin_amdgcn_mfma_f32_16x16x32_bf16(a0, W2[kt][0], acc[0][0], 0, 0, 0);
            acc[0][1] = __builtin_amdgcn_mfma_f32_16x16x32_bf16(a0, W2[kt][1], acc[0][1], 0, 0, 0);
            acc[1][0] = __builtin_amdgcn_mfma_f32_16x16x32_bf16(a1, W2[kt][0], acc[1][0], 0, 0, 0);
            acc[1][1] = __builtin_amdgcn_mfma_f32_16x16x32_bf16(a1, W2[kt][1], acc[1][1], 0, 0, 0);
        }
        // no barrier: epilogue writes out_s (no WAR with hid_s reads)

        // ---- epilogue: residual (from cur el buffer, swizzled) + bias2 -> out_s ----
#pragma unroll
        for (int mt = 0; mt < 2; mt++)
#pragma unroll
            for (int t = 0; t < 2; t++) {
                const int nc = (2 * wave + t) * 16 + col;
#pragma unroll
                for (int r = 0; r < 4; r++) {
                    const int row = mt * 16 + quad * 4 + r;
                    float res = bflo((unsigned int)stage_s[cur][0][row][nc ^ ((row & 7) << 3)]);
                    float v = acc[mt][t][r] + bias2[t] + res;
                    out_s[row * 136 + nc] = f2bf(v);
                }
            }
        __syncthreads();  // B2: out_s staged; cur fully consumed
#pragma unroll
        for (int p = 0; p < 2; p++) {
            int e = p * 16 + erow;
            *(uint4*)(el + (size_t)(base + e) * 128 + c16 * 8) =
                *(const uint4*)(out_s + e * 136 + c16 * 8);
        }
    }
}

// ---------------- node step: [nl_hi|nl_lo|agg_hi] (K=384) -> 128 -> 128, residual, hi/lo out ----------------
// 64 nodes/block (2 tiles of 32), grid 782. agg precomputed bf16 by k_agg.

__global__ __launch_bounds__(256) void k_node_step_s(
    unsigned short* __restrict__ nlh, unsigned short* __restrict__ nll,
    const unsigned short* __restrict__ agg,
    const unsigned short* __restrict__ w1h, const unsigned short* __restrict__ w1l,
    const float* __restrict__ b1,
    const unsigned short* __restrict__ w2h, const unsigned short* __restrict__ w2l,
    const float* __restrict__ b2) {
    __shared__ __align__(16) unsigned short a_s[32 * 392];
    __shared__ __align__(16) unsigned short hid_s[32 * 264];
    const int tid = threadIdx.x, wave = tid >> 6, lane = tid & 63;
    const int col = lane & 15, quad = lane >> 4;
    bf8v W1H[8][2], W1L[8][2], W2H[4][2], W2L[4][2];
#pragma unroll
    for (int kt = 0; kt < 8; kt++)
#pragma unroll
        for (int t = 0; t < 2; t++) {
            W1H[kt][t] = *(const bf8v*)(w1h + ((size_t)(kt * 8 + 2 * wave + t) * 64 + lane) * 8);
            W1L[kt][t] = *(const bf8v*)(w1l + ((size_t)(kt * 8 + 2 * wave + t) * 64 + lane) * 8);
        }
#pragma unroll
    for (int kt = 0; kt < 4; kt++)
#pragma unroll
        for (int t = 0; t < 2; t++) {
            W2H[kt][t] = *(const bf8v*)(w2h + ((size_t)(kt * 8 + 2 * wave + t) * 64 + lane) * 8);
            W2L[kt][t] = *(const bf8v*)(w2l + ((size_t)(kt * 8 + 2 * wave + t) * 64 + lane) * 8);
        }
    float bias1[2], bias2[2];
#pragma unroll
    for (int t = 0; t < 2; t++) {
        bias1[t] = b1[(2 * wave + t) * 16 + col];
        bias2[t] = b2[(2 * wave + t) * 16 + col];
    }
    for (int it = 0; it < 2; it++) {
        const int base = blockIdx.x * 64 + it * 32;
        if (base >= NN) break;
        __syncthreads();  // prev-iter a_s/hid_s reads done
        // stage: direct uint4 copies (hi | lo | agg)
#pragma unroll
        for (int p = 0; p < 2; p++) {
            int e = p * 16 + (tid >> 4), c16 = tid & 15;
            int n = base + e; if (n > NN - 1) n = NN - 1;
            *(uint4*)(a_s + e * 392 + c16 * 8) =
                *(const uint4*)(nlh + (size_t)n * 128 + c16 * 8);
            *(uint4*)(a_s + e * 392 + 128 + c16 * 8) =
                *(const uint4*)(nll + (size_t)n * 128 + c16 * 8);
            *(uint4*)(a_s + e * 392 + 256 + c16 * 8) =
                *(const uint4*)(agg + (size_t)n * 128 + c16 * 8);
        }
        __syncthreads();

        f4v acc[2][2];
#pragma unroll
        for (int mt = 0; mt < 2; mt++)
#pragma unroll
            for (int t = 0; t < 2; t++) acc[mt][t] = (f4v){0.f, 0.f, 0.f, 0.f};
        // layer1: nl hi+lo vs W1H[0..3], agg vs W1H[4..7], nl hi vs W1L[0..3], agg vs W1L[4..7]
#pragma unroll
        for (int kt = 0; kt < 8; kt++) {
            bf8v a0 = *(const bf8v*)(a_s + col * 392 + kt * 32 + quad * 8);
            bf8v a1 = *(const bf8v*)(a_s + (16 + col) * 392 + kt * 32 + quad * 8);
#pragma unroll
            for (int t = 0; t < 2; t++) {
                acc[0][t] = __builtin_amdgcn_mfma_f32_16x16x32_bf16(a0, W1H[kt & 3][t], acc[0][t], 0, 0, 0);
                acc[1][t] = __builtin_amdgcn_mfma_f32_16x16x32_bf16(a1, W1H[kt & 3][t], acc[1][t], 0, 0, 0);
            }
        }
#pragma unroll
        for (int kt = 0; kt < 4; kt++) {
            bf8v a0 = *(const bf8v*)(a_s + col * 392 + 256 + kt * 32 + quad * 8);
            bf8v a1 = *(const bf8v*)(a_s + (16 + col) * 392 + 256 + kt * 32 + quad * 8);
#pragma unroll
            for (int t = 0; t < 2; t++) {
                acc[0][t] = __builtin_amdgcn_mfma_f32_16x16x32_bf16(a0, W1H[4 + kt][t], acc[0][t], 0, 0, 0);
                acc[1][t] = __builtin_amdgcn_mfma_f32_16x16x32_bf16(a1, W1H[4 + kt][t], acc[1][t], 0, 0, 0);
            }
        }
#pragma unroll
        for (int kt = 0; kt < 4; kt++) {
            bf8v a0 = *(const bf8v*)(a_s + col * 392 + kt * 32 + quad * 8);
            bf8v a1 = *(const bf8v*)(a_s + (16 + col) * 392 + kt * 32 + quad * 8);
#pragma unroll
            for (int t = 0; t < 2; t++) {
                acc[0][t] = __builtin_amdgcn_mfma_f32_16x16x32_bf16(a0, W1L[kt][t], acc[0][t], 0, 0, 0);
                acc[1][t] = __builtin_amdgcn_mfma_f32_16x16x32_bf16(a1, W1L[kt][t], acc[1][t], 0, 0, 0);
            }
        }
#pragma unroll
        for (int kt = 0; kt < 4; kt++) {
            bf8v a0 = *(const bf8v*)(a_s + col * 392 + 256 + kt * 32 + quad * 8);
            bf8v a1 = *(const bf8v*)(a_s + (16 + col) * 392 + 256 + kt * 32 + quad * 8);
#pragma unroll
            for (int t = 0; t < 2; t++) {
                acc[0][t] = __builtin_amdgcn_mfma_f32_16x16x32_bf16(a0, W1L[4 + kt][t], acc[0][t], 0, 0, 0);
                acc[1][t] = __builtin_amdgcn_mfma_f32_16x16x32_bf16(a1, W1L[4 + kt][t], acc[1][t], 0, 0, 0);
            }
        }
#pragma unroll
        for (int mt = 0; mt < 2; mt++)
#pragma unroll
            for (int t = 0; t < 2; t++) {
                const int nc = (2 * wave + t) * 16 + col;
#pragma unroll
                for (int r = 0; r < 4; r++) {
                    float h = fmaxf(acc[mt][t][r] + bias1[t], 0.f);
                    unsigned short hh = f2bf(h);
                    hid_s[(mt * 16 + quad * 4 + r) * 264 + nc] = hh;
                    hid_s[(mt * 16 + quad * 4 + r) * 264 + 128 + nc] = f2bf(h - bflo(hh));
                }
            }
        __syncthreads();
#pragma unroll
        for (int mt = 0; mt < 2; mt++)
#pragma unroll
            for (int t = 0; t < 2; t++) acc[mt][t] = (f4v){0.f, 0.f, 0.f, 0.f};
#pragma unroll
        for (int kt = 0; kt < 8; kt++) {
            int w = kt & 3;
            bf8v a0 = *(const bf8v*)(hid_s + col * 264 + kt * 32 + quad * 8);
            bf8v a1 = *(const bf8v*)(hid_s + (16 + col) * 264 + kt * 32 + quad * 8);
#pragma unroll
            for (int t = 0; t < 2; t++) {
                acc[0][t] = __builtin_amdgcn_mfma_f32_16x16x32_bf16(a0, W2H[w][t], acc[0][t], 0, 0, 0);
                acc[1][t] = __builtin_amdgcn_mfma_f32_16x16x32_bf16(a1, W2H[w][t], acc[1][t], 0, 0, 0);
            }
        }
#pragma unroll
        for (int kt = 0; kt < 4; kt++) {
            bf8v a0 = *(const bf8v*)(hid_s + col * 264 + kt * 32 + quad * 8);
            bf8v a1 = *(const bf8v*)(hid_s + (16 + col) * 264 + kt * 32 + quad * 8);
#pragma unroll
            for (int t = 0; t < 2; t++) {
                acc[0][t] = __builtin_amdgcn_mfma_f32_16x16x32_bf16(a0, W2L[kt][t], acc[0][t], 0, 0, 0);
                acc[1][t] = __builtin_amdgcn_mfma_f32_16x16x32_bf16(a1, W2L[kt][t], acc[1][t], 0, 0, 0);
            }
        }
        __syncthreads();  // all L2 reads of hid done; reuse hid_s for output staging
#pragma unroll
        for (int mt = 0; mt < 2; mt++)
#pragma unroll
            for (int t = 0; t < 2; t++) {
                const int nc = (2 * wave + t) * 16 + col;
#pragma unroll
                for (int r = 0; r < 4; r++) {
                    const int row = mt * 16 + quad * 4 + r;
                    // residual from a_s hi+lo (still intact)
                    float res = bflo((unsigned int)a_s[row * 392 + nc]) +
                                bflo((unsigned int)a_s[row * 392 + 128 + nc]);
                    float v = acc[mt][t][r] + bias2[t] + res;
                    unsigned short hh = f2bf(v);
                    hid_s[row * 264 + nc] = hh;
                    hid_s[row * 264 + 128 + nc] = f2bf(v - bflo(hh));
                }
            }
        __syncthreads();  // out staged
#pragma unroll
        for (int p = 0; p < 2; p++) {
            int e = p * 16 + (tid >> 4), c16 = tid & 15;
            if (base + e < NN) {
                *(uint4*)(nlh + (size_t)(base + e) * 128 + c16 * 8) =
                    *(const uint4*)(hid_s + e * 264 + c16 * 8);
                *(uint4*)(nll + (size_t)(base + e) * 128 + c16 * 8) =
                    *(const uint4*)(hid_s + e * 264 + 128 + c16 * 8);
            }
        }
    }
}

// ---------------- decoder: 128 -> 128 -> 3 (fp32 VALU, reads hi+lo) ----------------

__global__ __launch_bounds__(128) void k_decode(
    const unsigned short* __restrict__ nlh, const unsigned short* __restrict__ nll,
    const float* __restrict__ w1, const float* __restrict__ b1,
    const float* __restrict__ w2, const float* __restrict__ b2,
    float* __restrict__ out) {
    __shared__ float inl[16][128];
    __shared__ float hid[16][128];
    int j = threadIdx.x;
    int base = blockIdx.x * 16;
    for (int e = 0; e < 16; e++)
        inl[e][j] = bflo((unsigned int)nlh[(size_t)(base + e) * 128 + j]) +
                    bflo((unsigned int)nll[(size_t)(base + e) * 128 + j]);
    __syncthreads();
    float acc[16];
#pragma unroll
    for (int e = 0; e < 16; e++) acc[e] = b1[j];
    for (int kc = 0; kc < 16; kc++) {
        float w[8];
#pragma unroll
        for (int t = 0; t < 8; t++) w[t] = w1[(kc * 8 + t) * 128 + j];
#pragma unroll
        for (int e = 0; e < 16; e++) {
            float4 h0 = *(const float4*)&inl[e][kc * 8];
            float4 h1 = *(const float4*)&inl[e][kc * 8 + 4];
            acc[e] = fmaf(h0.x, w[0], acc[e]); acc[e] = fmaf(h0.y, w[1], acc[e]);
            acc[e] = fmaf(h0.z, w[2], acc[e]); acc[e] = fmaf(h0.w, w[3], acc[e]);
            acc[e] = fmaf(h1.x, w[4], acc[e]); acc[e] = fmaf(h1.y, w[5], acc[e]);
            acc[e] = fmaf(h1.z, w[6], acc[e]); acc[e] = fmaf(h1.w, w[7], acc[e]);
        }
    }
#pragma unroll
    for (int e = 0; e < 16; e++) hid[e][j] = fmaxf(acc[e], 0.f);
    __syncthreads();
    if (j < 48) {
        int e = j / 3, ch = j - 3 * (j / 3);
        float s = b2[ch];
        for (int k = 0; k < 128; k++) s = fmaf(hid[e][k], w2[k * 3 + ch], s);
        out[(size_t)(base + e) * 3 + ch] = s;
    }
}

// ---------------- launch ----------------

extern "C" void kernel_launch(void* const* d_in, const int* in_sizes, int n_in,
                              void* d_out, int out_size, void* d_ws, size_t ws_size,
                              hipStream_t stream) {
    (void)in_sizes; (void)n_in; (void)out_size; (void)ws_size;
    const float* pos   = (const float*)d_in[0];
    const float* vel   = (const float*)d_in[1];
    const int*   rid   = (const int*)d_in[2];
    const int*   snd   = (const int*)d_in[3];
    const int*   rcv   = (const int*)d_in[4];
    const float* remb  = (const float*)d_in[5];
    const float* ne_w1 = (const float*)d_in[6];
    const float* ne_b1 = (const float*)d_in[7];
    const float* ne_w2 = (const float*)d_in[8];
    const float* ne_b2 = (const float*)d_in[9];
    const float* ee_w1 = (const float*)d_in[10];
    const float* ee_b1 = (const float*)d_in[11];
    const float* ee_w2 = (const float*)d_in[12];
    const float* ee_b2 = (const float*)d_in[13];
    const float* pe_w1 = (const float*)d_in[14];
    const float* pe_b1 = (const float*)d_in[15];
    const float* pe_w2 = (const float*)d_in[16];
    const float* pe_b2 = (const float*)d_in[17];
    const float* pn_w1 = (const float*)d_in[18];
    const float* pn_b1 = (const float*)d_in[19];
    const float* pn_w2 = (const float*)d_in[20];
    const float* pn_b2 = (const float*)d_in[21];
    const float* de_w1 = (const float*)d_in[22];
    const float* de_b1 = (const float*)d_in[23];
    const float* de_w2 = (const float*)d_in[24];
    const float* de_b2 = (const float*)d_in[25];
    float* out = (float*)d_out;

    // workspace carve (~250.6e6 B — under the 256.2e6 proven available)
    char* p = (char*)d_ws;
    auto carve = [&](size_t bytes) { void* q = (void*)p; p += (bytes + 15) & ~(size_t)15; return q; };
    unsigned short* el    = (unsigned short*)carve((size_t)NE * LDIM * 2);   // 204.8e6, CSR order
    unsigned short* nlh   = (unsigned short*)carve((size_t)NN * LDIM * 2);   // 12.8e6
    unsigned short* nll   = (unsigned short*)carve((size_t)NN * LDIM * 2);   // 12.8e6
    unsigned short* agg   = (unsigned short*)carve((size_t)NN * LDIM * 2);   // 12.8e6 (bf16)
    unsigned short* w1f_e = (unsigned short*)carve((size_t)NSTEPS * 12 * 8 * 512 * 2);
    unsigned short* w2f_e = (unsigned short*)carve((size_t)NSTEPS * 4 * 8 * 512 * 2);
    unsigned short* w1h_n = (unsigned short*)carve((size_t)NSTEPS * 8 * 8 * 512 * 2);
    unsigned short* w1l_n = (unsigned short*)carve((size_t)NSTEPS * 8 * 8 * 512 * 2);
    unsigned short* w2h_n = (unsigned short*)carve((size_t)NSTEPS * 4 * 8 * 512 * 2);
    unsigned short* w2l_n = (unsigned short*)carve((size_t)NSTEPS * 4 * 8 * 512 * 2);
    unsigned short* eew1h = (unsigned short*)carve((size_t)1 * 8 * 512 * 2);
    unsigned short* eew1l = (unsigned short*)carve((size_t)1 * 8 * 512 * 2);
    unsigned short* eew2h = (unsigned short*)carve((size_t)4 * 8 * 512 * 2);
    unsigned short* eew2l = (unsigned short*)carve((size_t)4 * 8 * 512 * 2);
    unsigned short* new1h = (unsigned short*)carve((size_t)1 * 8 * 512 * 2);
    unsigned short* new1l = (unsigned short*)carve((size_t)1 * 8 * 512 * 2);
    unsigned short* new2h = (unsigned short*)carve((size_t)4 * 8 * 512 * 2);
    unsigned short* new2l = (unsigned short*)carve((size_t)4 * 8 * 512 * 2);
    unsigned short* snd_p = (unsigned short*)carve((size_t)NE * 2);          // 1.6e6
    unsigned short* rcv_p = (unsigned short*)carve((size_t)NE * 2);          // 1.6e6
    int*            rs    = (int*)carve((size_t)(NN + 1) * 4);
    int*            cnt   = (int*)carve((size_t)NN * 4);
    int*            cur   = (int*)carve((size_t)NN * 4);
    float*          degf  = (float*)carve((size_t)NN * 4);
    float*          csum  = (float*)carve(16);

    hipMemsetAsync(cnt, 0, (size_t)NN * 4, stream);
    hipMemsetAsync(csum, 0, 16, stream);
    k_hist<<<NE / 256, 256, 0, stream>>>(rcv, cnt);
    k_scan<<<1, 1024, 0, stream>>>(cnt, rs, cur, degf);
    k_center<<<64, 256, 0, stream>>>(pos, csum);
    k_scatter<<<NE / 256, 256, 0, stream>>>(snd, rcv, cur, snd_p, rcv_p);
    k_prep_w<<<NSTEPS * 12 * 8, 64, 0, stream>>>(pe_w1, w1f_e, 12, 384, 0);
    k_prep_w<<<NSTEPS * 4 * 8, 64, 0, stream>>>(pe_w2, w2f_e, 4, 128, 0);
    k_prep_w<<<NSTEPS * 8 * 8, 64, 0, stream>>>(pn_w1, w1h_n, 8, 256, 0);
    k_prep_w<<<NSTEPS * 8 * 8, 64, 0, stream>>>(pn_w1, w1l_n, 8, 256, 1);
    k_prep_w<<<NSTEPS * 4 * 8, 64, 0, stream>>>(pn_w2, w2h_n, 4, 128, 0);
    k_prep_w<<<NSTEPS * 4 * 8, 64, 0, stream>>>(pn_w2, w2l_n, 4, 128, 1);
    k_prep_w<<<8, 64, 0, stream>>>(ee_w1, eew1h, 1, 9, 0);
    k_prep_w<<<8, 64, 0, stream>>>(ee_w1, eew1l, 1, 9, 1);
    k_prep_w<<<4 * 8, 64, 0, stream>>>(ee_w2, eew2h, 4, 128, 0);
    k_prep_w<<<4 * 8, 64, 0, stream>>>(ee_w2, eew2l, 4, 128, 1);
    k_prep_w<<<8, 64, 0, stream>>>(ne_w1, new1h, 1, 23, 0);
    k_prep_w<<<8, 64, 0, stream>>>(ne_w1, new1l, 1, 23, 1);
    k_prep_w<<<4 * 8, 64, 0, stream>>>(ne_w2, new2h, 4, 128, 0);
    k_prep_w<<<4 * 8, 64, 0, stream>>>(ne_w2, new2l, 4, 128, 1);

    k_node_enc_m<<<(NN + 127) / 128, 256, 0, stream>>>(pos, vel, rid, remb, degf, csum,
                                                       new1h, new1l, ne_b1, new2h, new2l, ne_b2, nlh, nll);
    k_edge_enc_m<<<NE / 128, 256, 0, stream>>>(pos, vel, rid, snd_p, rcv_p,
                                               eew1h, eew1l, ee_b1, eew2h, eew2l, ee_b2, el);
    for (int i = 0; i < NSTEPS; i++) {
        k_edge_step<<<NE / 128, 256, 0, stream>>>(el, nlh, snd_p, rcv_p,
            w1f_e + (size_t)i * 12 * 8 * 512, pe_b1 + i * 128,
            w2f_e + (size_t)i * 4 * 8 * 512, pe_b2 + i * 128);
        k_agg<<<(NN + 3) / 4, 256, 0, stream>>>(el, rs, agg);
        k_node_step_s<<<(NN + 63) / 64, 256, 0, stream>>>(nlh, nll, agg,
            w1h_n + (size_t)i * 8 * 8 * 512, w1l_n + (size_t)i * 8 * 8 * 512, pn_b1 + i * 128,
            w2h_n + (size_t)i * 4 * 8 * 512, w2l_n + (size_t)i * 4 * 8 * 512, pn_b2 + i * 128);
    }
    k_decode<<<NN / 16, 128, 0, stream>>>(nlh, nll, de_w1, de_b1, de_w2, de_b2, out);
}

// Round 13
// 2861.007 us; speedup vs baseline: 1.7921x; 1.0005x over previous
//
#include <hip/hip_runtime.h>
#include <hip/hip_bf16.h>

#define NN 50000
#define NE 800000
#define LDIM 128
#define NSTEPS 10

typedef __hip_bfloat16 bf16;
typedef __bf16 bf8v __attribute__((ext_vector_type(8)));
typedef float f4v __attribute__((ext_vector_type(4)));
typedef unsigned short u16x8 __attribute__((ext_vector_type(8)));

__device__ inline float bflo(unsigned int u) {
    union { unsigned int i; float f; } x; x.i = u << 16; return x.f;
}
__device__ inline float bfhi(unsigned int u) {
    union { unsigned int i; float f; } x; x.i = u & 0xffff0000u; return x.f;
}
__device__ inline unsigned short f2bf(float f) {
    __hip_bfloat16 h = __float2bfloat16(f);
    unsigned short u; __builtin_memcpy(&u, &h, 2); return u;
}

// async global->LDS DMA, 16 B per lane. LDS dest is wave-uniform base + lane*16
// (linear); global src is per-lane. Drained by the vmcnt(0) the compiler emits
// at the next __syncthreads.
__device__ __forceinline__ void gl_lds16(const void* g, void* l) {
    __builtin_amdgcn_global_load_lds(
        (const __attribute__((address_space(1))) unsigned int*)g,
        (__attribute__((address_space(3))) unsigned int*)l, 16, 0, 0);
}

// ---------------- CSR build: histogram, scan, scatter (ushort permuted endpoints) ----------------

__global__ void k_hist(const int* __restrict__ rcv, int* __restrict__ cnt) {
    int i = blockIdx.x * 256 + threadIdx.x;
    if (i < NE) atomicAdd(&cnt[rcv[i]], 1);
}

__global__ __launch_bounds__(1024) void k_scan(
    const int* __restrict__ cnt, int* __restrict__ row_start,
    int* __restrict__ cur, float* __restrict__ degf) {
    __shared__ int part[1024];
    const int t = threadIdx.x;
    const int CH = (NN + 1023) / 1024;  // 49
    int b0 = t * CH, b1 = b0 + CH; if (b1 > NN) b1 = NN; if (b0 > NN) b0 = NN;
    int s = 0;
    for (int i = b0; i < b1; i++) s += cnt[i];
    part[t] = s;
    __syncthreads();
    for (int off = 1; off < 1024; off <<= 1) {
        int v = (t >= off) ? part[t - off] : 0;
        __syncthreads();
        part[t] += v;
        __syncthreads();
    }
    int run = part[t] - s;  // exclusive prefix
    for (int i = b0; i < b1; i++) {
        row_start[i] = run; cur[i] = run; degf[i] = (float)cnt[i];
        run += cnt[i];
    }
    if (t == 1023) row_start[NN] = part[1023];
}

__global__ void k_scatter(const int* __restrict__ snd, const int* __restrict__ rcv,
                          int* __restrict__ cur,
                          unsigned short* __restrict__ snd_p, unsigned short* __restrict__ rcv_p) {
    int i = blockIdx.x * 256 + threadIdx.x;
    if (i < NE) {
        int r = rcv[i];
        int p = atomicAdd(&cur[r], 1);
        snd_p[p] = (unsigned short)snd[i];
        rcv_p[p] = (unsigned short)r;
    }
}

__global__ void k_center(const float* __restrict__ pos, float* __restrict__ csum) {
    __shared__ float s[3][256];
    float a = 0.f, b = 0.f, c = 0.f;
    for (int i = blockIdx.x * 256 + threadIdx.x; i < NN; i += gridDim.x * 256) {
        a += pos[3 * i]; b += pos[3 * i + 1]; c += pos[3 * i + 2];
    }
    int t = threadIdx.x;
    s[0][t] = a; s[1][t] = b; s[2][t] = c;
    __syncthreads();
    for (int off = 128; off > 0; off >>= 1) {
        if (t < off) {
            s[0][t] += s[0][t + off];
            s[1][t] += s[1][t + off];
            s[2][t] += s[2][t + off];
        }
        __syncthreads();
    }
    if (t == 0) {
        atomicAdd(&csum[0], s[0][0]);
        atomicAdd(&csum[1], s[1][0]);
        atomicAdd(&csum[2], s[2][0]);
    }
}

// ---------------- weight prep: fp32 -> bf16 B-frag order; lo=1 emits bf16(x - bf16(x)) ----------------

__global__ void k_prep_w(const float* __restrict__ w, unsigned short* __restrict__ wf,
                         int KT, int Ksrc, int lo) {
    int b = blockIdx.x;
    int s = b / (KT * 8), rem = b % (KT * 8);
    int kt = rem / 8, nt = rem % 8;
    int lane = threadIdx.x, col = lane & 15, quad = lane >> 4;
    const float* W = w + (size_t)s * Ksrc * 128;
    u16x8 o;
#pragma unroll
    for (int jj = 0; jj < 8; jj++) {
        int k = kt * 32 + quad * 8 + jj;
        float x = (k < Ksrc) ? W[(size_t)k * 128 + nt * 16 + col] : 0.f;
        unsigned short h = f2bf(x);
        if (lo) h = f2bf(x - bflo(h));
        o[jj] = h;
    }
    *(u16x8*)(wf + (((size_t)b) * 64 + lane) * 8) = o;
}

// ---------------- CSR aggregation: streaming reduction el (CSR order) -> bf16 agg ----------------

__global__ __launch_bounds__(256) void k_agg(
    const unsigned short* __restrict__ el, const int* __restrict__ row_start,
    unsigned short* __restrict__ agg) {
    const int wave = threadIdx.x >> 6, lane = threadIdx.x & 63;
    const int n = blockIdx.x * 4 + wave;
    if (n >= NN) return;
    const int sub = lane >> 4, c16 = lane & 15;
    const int st = row_start[n], en = row_start[n + 1];
    float s[8];
#pragma unroll
    for (int k = 0; k < 8; k++) s[k] = 0.f;
    for (int q = st + sub; q < en; q += 4) {
        uint4 v = *(const uint4*)(el + (size_t)q * 128 + c16 * 8);
        s[0] += bflo(v.x); s[1] += bfhi(v.x);
        s[2] += bflo(v.y); s[3] += bfhi(v.y);
        s[4] += bflo(v.z); s[5] += bfhi(v.z);
        s[6] += bflo(v.w); s[7] += bfhi(v.w);
    }
#pragma unroll
    for (int k = 0; k < 8; k++) {
        s[k] += __shfl_xor(s[k], 16);
        s[k] += __shfl_xor(s[k], 32);
    }
    if (sub == 0) {
        u16x8 o;
#pragma unroll
        for (int k = 0; k < 8; k++) o[k] = f2bf(s[k]);
        *(u16x8*)(agg + (size_t)n * 128 + c16 * 8) = o;
    }
}

// ---------------- MFMA node encoder (split-precision): feat(23 pad 32, hi|lo) -> 128 -> 128 ----------------
// Output: node latent as bf16 hi/lo pair (nlh, nll).

__global__ __launch_bounds__(256) void k_node_enc_m(
    const float* __restrict__ pos, const float* __restrict__ vel,
    const int* __restrict__ rid, const float* __restrict__ remb,
    const float* __restrict__ degf, const float* __restrict__ csum,
    const unsigned short* __restrict__ w1h, const unsigned short* __restrict__ w1l,
    const float* __restrict__ b1,
    const unsigned short* __restrict__ w2h, const unsigned short* __restrict__ w2l,
    const float* __restrict__ b2,
    unsigned short* __restrict__ nlh, unsigned short* __restrict__ nll) {
    __shared__ __align__(16) unsigned short feat_s[32 * 72];   // [hi(32)|lo(32)|pad]
    __shared__ __align__(16) unsigned short hid_s[32 * 264];   // [hi(128)|lo(128)|pad]
    const int tid = threadIdx.x, wave = tid >> 6, lane = tid & 63;
    const int col = lane & 15, quad = lane >> 4;
    bf8v W1H[2], W1L[2], W2H[4][2], W2L[4][2];
#pragma unroll
    for (int t = 0; t < 2; t++) {
        W1H[t] = *(const bf8v*)(w1h + ((size_t)(2 * wave + t) * 64 + lane) * 8);
        W1L[t] = *(const bf8v*)(w1l + ((size_t)(2 * wave + t) * 64 + lane) * 8);
    }
#pragma unroll
    for (int kt = 0; kt < 4; kt++)
#pragma unroll
        for (int t = 0; t < 2; t++) {
            W2H[kt][t] = *(const bf8v*)(w2h + ((size_t)(kt * 8 + 2 * wave + t) * 64 + lane) * 8);
            W2L[kt][t] = *(const bf8v*)(w2l + ((size_t)(kt * 8 + 2 * wave + t) * 64 + lane) * 8);
        }
    float bias1[2], bias2[2];
#pragma unroll
    for (int t = 0; t < 2; t++) {
        bias1[t] = b1[(2 * wave + t) * 16 + col];
        bias2[t] = b2[(2 * wave + t) * 16 + col];
    }
    float cx = csum[0] * (1.0f / NN), cy = csum[1] * (1.0f / NN), cz = csum[2] * (1.0f / NN);
    uint4 z = {0u, 0u, 0u, 0u};
    for (int s2 = tid; s2 < 288; s2 += 256) *(uint4*)(feat_s + s2 * 8) = z;  // zero K-pad

    for (int it = 0; it < 4; it++) {
        const int base = blockIdx.x * 128 + it * 32;
        if (base >= NN) break;
        __syncthreads();
        if (tid < 32) {
            int n = base + tid; if (n > NN - 1) n = NN - 1;
            float v[23];
            v[0] = vel[3 * n]; v[1] = vel[3 * n + 1]; v[2] = vel[3 * n + 2];
            v[3] = pos[3 * n] - cx; v[4] = pos[3 * n + 1] - cy; v[5] = pos[3 * n + 2] - cz;
            v[6] = degf[n];
            int rb = rid[n] * 16;
#pragma unroll
            for (int k = 0; k < 16; k++) v[7 + k] = remb[rb + k];
            unsigned short* f = feat_s + tid * 72;
#pragma unroll
            for (int k = 0; k < 23; k++) {
                unsigned short h = f2bf(v[k]);
                f[k] = h; f[32 + k] = f2bf(v[k] - bflo(h));
            }
        }
        __syncthreads();
        f4v acc[2][2];
#pragma unroll
        for (int mt = 0; mt < 2; mt++)
#pragma unroll
            for (int t = 0; t < 2; t++) acc[mt][t] = (f4v){0.f, 0.f, 0.f, 0.f};
        {
            bf8v a0h = *(const bf8v*)(feat_s + col * 72 + quad * 8);
            bf8v a1h = *(const bf8v*)(feat_s + (16 + col) * 72 + quad * 8);
            bf8v a0l = *(const bf8v*)(feat_s + col * 72 + 32 + quad * 8);
            bf8v a1l = *(const bf8v*)(feat_s + (16 + col) * 72 + 32 + quad * 8);
#pragma unroll
            for (int t = 0; t < 2; t++) {
                acc[0][t] = __builtin_amdgcn_mfma_f32_16x16x32_bf16(a0h, W1H[t], acc[0][t], 0, 0, 0);
                acc[1][t] = __builtin_amdgcn_mfma_f32_16x16x32_bf16(a1h, W1H[t], acc[1][t], 0, 0, 0);
                acc[0][t] = __builtin_amdgcn_mfma_f32_16x16x32_bf16(a0l, W1H[t], acc[0][t], 0, 0, 0);
                acc[1][t] = __builtin_amdgcn_mfma_f32_16x16x32_bf16(a1l, W1H[t], acc[1][t], 0, 0, 0);
                acc[0][t] = __builtin_amdgcn_mfma_f32_16x16x32_bf16(a0h, W1L[t], acc[0][t], 0, 0, 0);
                acc[1][t] = __builtin_amdgcn_mfma_f32_16x16x32_bf16(a1h, W1L[t], acc[1][t], 0, 0, 0);
            }
        }
#pragma unroll
        for (int mt = 0; mt < 2; mt++)
#pragma unroll
            for (int t = 0; t < 2; t++) {
                const int nc = (2 * wave + t) * 16 + col;
#pragma unroll
                for (int r = 0; r < 4; r++) {
                    float h = fmaxf(acc[mt][t][r] + bias1[t], 0.f);
                    unsigned short hh = f2bf(h);
                    hid_s[(mt * 16 + quad * 4 + r) * 264 + nc] = hh;
                    hid_s[(mt * 16 + quad * 4 + r) * 264 + 128 + nc] = f2bf(h - bflo(hh));
                }
            }
        __syncthreads();
#pragma unroll
        for (int mt = 0; mt < 2; mt++)
#pragma unroll
            for (int t = 0; t < 2; t++) acc[mt][t] = (f4v){0.f, 0.f, 0.f, 0.f};
#pragma unroll
        for (int kt = 0; kt < 8; kt++) {
            int w = kt & 3;
            bf8v a0 = *(const bf8v*)(hid_s + col * 264 + kt * 32 + quad * 8);
            bf8v a1 = *(const bf8v*)(hid_s + (16 + col) * 264 + kt * 32 + quad * 8);
#pragma unroll
            for (int t = 0; t < 2; t++) {
                acc[0][t] = __builtin_amdgcn_mfma_f32_16x16x32_bf16(a0, W2H[w][t], acc[0][t], 0, 0, 0);
                acc[1][t] = __builtin_amdgcn_mfma_f32_16x16x32_bf16(a1, W2H[w][t], acc[1][t], 0, 0, 0);
            }
        }
#pragma unroll
        for (int kt = 0; kt < 4; kt++) {
            bf8v a0 = *(const bf8v*)(hid_s + col * 264 + kt * 32 + quad * 8);
            bf8v a1 = *(const bf8v*)(hid_s + (16 + col) * 264 + kt * 32 + quad * 8);
#pragma unroll
            for (int t = 0; t < 2; t++) {
                acc[0][t] = __builtin_amdgcn_mfma_f32_16x16x32_bf16(a0, W2L[kt][t], acc[0][t], 0, 0, 0);
                acc[1][t] = __builtin_amdgcn_mfma_f32_16x16x32_bf16(a1, W2L[kt][t], acc[1][t], 0, 0, 0);
            }
        }
        __syncthreads();  // all hid reads done; overwrite with output hi/lo
#pragma unroll
        for (int mt = 0; mt < 2; mt++)
#pragma unroll
            for (int t = 0; t < 2; t++) {
                const int nc = (2 * wave + t) * 16 + col;
#pragma unroll
                for (int r = 0; r < 4; r++) {
                    const int row = mt * 16 + quad * 4 + r;
                    float v = acc[mt][t][r] + bias2[t];
                    unsigned short hh = f2bf(v);
                    hid_s[row * 264 + nc] = hh;
                    hid_s[row * 264 + 128 + nc] = f2bf(v - bflo(hh));
                }
            }
        __syncthreads();
#pragma unroll
        for (int p = 0; p < 2; p++) {
            int s2 = p * 256 + tid, e = s2 >> 4, c16 = s2 & 15;
            if (base + e < NN) {
                *(uint4*)(nlh + (size_t)(base + e) * 128 + c16 * 8) =
                    *(const uint4*)(hid_s + e * 264 + c16 * 8);
                *(uint4*)(nll + (size_t)(base + e) * 128 + c16 * 8) =
                    *(const uint4*)(hid_s + e * 264 + 128 + c16 * 8);
            }
        }
    }
}

// ---------------- MFMA edge encoder (split-precision): feat(9 pad 32, hi|lo) -> 128 -> 128 ----------------

__global__ __launch_bounds__(256) void k_edge_enc_m(
    const float* __restrict__ pos, const float* __restrict__ vel,
    const int* __restrict__ rid,
    const unsigned short* __restrict__ snd, const unsigned short* __restrict__ rcv,
    const unsigned short* __restrict__ w1h, const unsigned short* __restrict__ w1l,
    const float* __restrict__ b1,
    const unsigned short* __restrict__ w2h, const unsigned short* __restrict__ w2l,
    const float* __restrict__ b2,
    unsigned short* __restrict__ el) {
    __shared__ __align__(16) unsigned short feat_s[32 * 72];
    __shared__ __align__(16) unsigned short hid_s[32 * 264];
    const int tid = threadIdx.x, wave = tid >> 6, lane = tid & 63;
    const int col = lane & 15, quad = lane >> 4;
    bf8v W1H[2], W1L[2], W2H[4][2], W2L[4][2];
#pragma unroll
    for (int t = 0; t < 2; t++) {
        W1H[t] = *(const bf8v*)(w1h + ((size_t)(2 * wave + t) * 64 + lane) * 8);
        W1L[t] = *(const bf8v*)(w1l + ((size_t)(2 * wave + t) * 64 + lane) * 8);
    }
#pragma unroll
    for (int kt = 0; kt < 4; kt++)
#pragma unroll
        for (int t = 0; t < 2; t++) {
            W2H[kt][t] = *(const bf8v*)(w2h + ((size_t)(kt * 8 + 2 * wave + t) * 64 + lane) * 8);
            W2L[kt][t] = *(const bf8v*)(w2l + ((size_t)(kt * 8 + 2 * wave + t) * 64 + lane) * 8);
        }
    float bias1[2], bias2[2];
#pragma unroll
    for (int t = 0; t < 2; t++) {
        bias1[t] = b1[(2 * wave + t) * 16 + col];
        bias2[t] = b2[(2 * wave + t) * 16 + col];
    }
    uint4 z = {0u, 0u, 0u, 0u};
    for (int s2 = tid; s2 < 288; s2 += 256) *(uint4*)(feat_s + s2 * 8) = z;

    for (int it = 0; it < 4; it++) {
        const int base = blockIdx.x * 128 + it * 32;
        __syncthreads();
        if (tid < 32) {
            int e = base + tid;
            int s = snd[e], r = rcv[e];
            float v[9];
            v[0] = pos[3 * s] - pos[3 * r]; v[1] = pos[3 * s + 1] - pos[3 * r + 1]; v[2] = pos[3 * s + 2] - pos[3 * r + 2];
            v[3] = vel[3 * s] - vel[3 * r]; v[4] = vel[3 * s + 1] - vel[3 * r + 1]; v[5] = vel[3 * s + 2] - vel[3 * r + 2];
            float sq = v[0] * v[0] + v[1] * v[1] + v[2] * v[2];
            v[6] = sqrtf(sq); v[7] = sq;
            v[8] = (rid[s] == rid[r]) ? 1.f : 0.f;
            unsigned short* f = feat_s + tid * 72;
#pragma unroll
            for (int k = 0; k < 9; k++) {
                unsigned short h = f2bf(v[k]);
                f[k] = h; f[32 + k] = f2bf(v[k] - bflo(h));
            }
        }
        __syncthreads();
        f4v acc[2][2];
#pragma unroll
        for (int mt = 0; mt < 2; mt++)
#pragma unroll
            for (int t = 0; t < 2; t++) acc[mt][t] = (f4v){0.f, 0.f, 0.f, 0.f};
        {
            bf8v a0h = *(const bf8v*)(feat_s + col * 72 + quad * 8);
            bf8v a1h = *(const bf8v*)(feat_s + (16 + col) * 72 + quad * 8);
            bf8v a0l = *(const bf8v*)(feat_s + col * 72 + 32 + quad * 8);
            bf8v a1l = *(const bf8v*)(feat_s + (16 + col) * 72 + 32 + quad * 8);
#pragma unroll
            for (int t = 0; t < 2; t++) {
                acc[0][t] = __builtin_amdgcn_mfma_f32_16x16x32_bf16(a0h, W1H[t], acc[0][t], 0, 0, 0);
                acc[1][t] = __builtin_amdgcn_mfma_f32_16x16x32_bf16(a1h, W1H[t], acc[1][t], 0, 0, 0);
                acc[0][t] = __builtin_amdgcn_mfma_f32_16x16x32_bf16(a0l, W1H[t], acc[0][t], 0, 0, 0);
                acc[1][t] = __builtin_amdgcn_mfma_f32_16x16x32_bf16(a1l, W1H[t], acc[1][t], 0, 0, 0);
                acc[0][t] = __builtin_amdgcn_mfma_f32_16x16x32_bf16(a0h, W1L[t], acc[0][t], 0, 0, 0);
                acc[1][t] = __builtin_amdgcn_mfma_f32_16x16x32_bf16(a1h, W1L[t], acc[1][t], 0, 0, 0);
            }
        }
#pragma unroll
        for (int mt = 0; mt < 2; mt++)
#pragma unroll
            for (int t = 0; t < 2; t++) {
                const int nc = (2 * wave + t) * 16 + col;
#pragma unroll
                for (int r = 0; r < 4; r++) {
                    float h = fmaxf(acc[mt][t][r] + bias1[t], 0.f);
                    unsigned short hh = f2bf(h);
                    hid_s[(mt * 16 + quad * 4 + r) * 264 + nc] = hh;
                    hid_s[(mt * 16 + quad * 4 + r) * 264 + 128 + nc] = f2bf(h - bflo(hh));
                }
            }
        __syncthreads();
#pragma unroll
        for (int mt = 0; mt < 2; mt++)
#pragma unroll
            for (int t = 0; t < 2; t++) acc[mt][t] = (f4v){0.f, 0.f, 0.f, 0.f};
#pragma unroll
        for (int kt = 0; kt < 8; kt++) {
            int w = kt & 3;
            bf8v a0 = *(const bf8v*)(hid_s + col * 264 + kt * 32 + quad * 8);
            bf8v a1 = *(const bf8v*)(hid_s + (16 + col) * 264 + kt * 32 + quad * 8);
#pragma unroll
            for (int t = 0; t < 2; t++) {
                acc[0][t] = __builtin_amdgcn_mfma_f32_16x16x32_bf16(a0, W2H[w][t], acc[0][t], 0, 0, 0);
                acc[1][t] = __builtin_amdgcn_mfma_f32_16x16x32_bf16(a1, W2H[w][t], acc[1][t], 0, 0, 0);
            }
        }
#pragma unroll
        for (int kt = 0; kt < 4; kt++) {
            bf8v a0 = *(const bf8v*)(hid_s + col * 264 + kt * 32 + quad * 8);
            bf8v a1 = *(const bf8v*)(hid_s + (16 + col) * 264 + kt * 32 + quad * 8);
#pragma unroll
            for (int t = 0; t < 2; t++) {
                acc[0][t] = __builtin_amdgcn_mfma_f32_16x16x32_bf16(a0, W2L[kt][t], acc[0][t], 0, 0, 0);
                acc[1][t] = __builtin_amdgcn_mfma_f32_16x16x32_bf16(a1, W2L[kt][t], acc[1][t], 0, 0, 0);
            }
        }
        __syncthreads();
#pragma unroll
        for (int mt = 0; mt < 2; mt++)
#pragma unroll
            for (int t = 0; t < 2; t++) {
                const int nc = (2 * wave + t) * 16 + col;
#pragma unroll
                for (int r = 0; r < 4; r++)
                    hid_s[(mt * 16 + quad * 4 + r) * 264 + nc] = f2bf(acc[mt][t][r] + bias2[t]);
            }
        __syncthreads();
#pragma unroll
        for (int p = 0; p < 2; p++) {
            int s2 = p * 256 + tid, e = s2 >> 4, c16 = s2 & 15;
            *(uint4*)(el + (size_t)(base + e) * 128 + c16 * 8) =
                *(const uint4*)(hid_s + e * 264 + c16 * 8);
        }
    }
}

// ---------------- MFMA edge processor step (CSR order) ----------------
// v13 (verified 2862.6 us): v6 + separate out_s buffer; epilogue writes out_s
// instead of overwriting hid_s, removing the WAR barrier between layer-2's
// LDS reads and the epilogue (4 -> 3 barriers/tile; edge_step 184.7 -> 181.5).

__global__ __launch_bounds__(256) void k_edge_step(
    unsigned short* __restrict__ el, const unsigned short* __restrict__ nlh,
    const unsigned short* __restrict__ snd, const unsigned short* __restrict__ rcv,
    const unsigned short* __restrict__ w1f, const float* __restrict__ b1,
    const unsigned short* __restrict__ w2f, const float* __restrict__ b2) {
    __shared__ __align__(1024) unsigned short stage_s[2][3][32][128];  // 48 KB
    __shared__ __align__(16) unsigned short hid_s[32 * 136];           // 8.5 KB
    __shared__ __align__(16) unsigned short out_s[32 * 136];           // 8.5 KB
    const int tid = threadIdx.x;
    const int wave = tid >> 6, lane = tid & 63;
    const int col = lane & 15, quad = lane >> 4;
    const int erow = tid >> 4, c16 = tid & 15;

    bf8v W1[12][2], W2[4][2];
#pragma unroll
    for (int kt = 0; kt < 12; kt++)
#pragma unroll
        for (int t = 0; t < 2; t++)
            W1[kt][t] = *(const bf8v*)(w1f + ((size_t)(kt * 8 + 2 * wave + t) * 64 + lane) * 8);
#pragma unroll
    for (int kt = 0; kt < 4; kt++)
#pragma unroll
        for (int t = 0; t < 2; t++)
            W2[kt][t] = *(const bf8v*)(w2f + ((size_t)(kt * 8 + 2 * wave + t) * 64 + lane) * 8);
    float bias1[2], bias2[2];
#pragma unroll
    for (int t = 0; t < 2; t++) {
        bias1[t] = b1[(2 * wave + t) * 16 + col];
        bias2[t] = b2[(2 * wave + t) * 16 + col];
    }

    // staging geometry: wave stages rows [wave*8, wave*8+8) of each stream,
    // 2 instructions x 1024 B. lane covers row = wave*8 + i*4 + (lane>>4),
    // 16 B at byte (lane&15)*16 within the row. Global source pre-swizzled.
    const int srow0 = wave * 8 + (lane >> 4);
    const int srow1 = srow0 + 4;
    const int skb = (lane & 15) * 16;
    const int soff0 = skb ^ ((srow0 & 7) << 4);
    const int soff1 = skb ^ ((srow1 & 7) << 4);
    const int gb0 = blockIdx.x * 128;
    const char* elc = (const char*)el;
    const char* nlc = (const char*)nlh;

    auto issue = [&](int t, int b, int si0, int si1, int ri0, int ri1) {
        char* s0 = (char*)&stage_s[b][0][wave * 8][0];
        char* s1 = (char*)&stage_s[b][1][wave * 8][0];
        char* s2 = (char*)&stage_s[b][2][wave * 8][0];
        const size_t gb = (size_t)(gb0 + t * 32);
        gl_lds16(elc + (gb + srow0) * 256 + soff0, s0);
        gl_lds16(elc + (gb + srow1) * 256 + soff1, s0 + 1024);
        gl_lds16(nlc + (size_t)si0 * 256 + soff0, s1);
        gl_lds16(nlc + (size_t)si1 * 256 + soff1, s1 + 1024);
        gl_lds16(nlc + (size_t)ri0 * 256 + soff0, s2);
        gl_lds16(nlc + (size_t)ri1 * 256 + soff1, s2 + 1024);
    };

    // prologue: issue tile 0; preload gather indices for tile 1
    {
        int si0 = snd[gb0 + srow0], si1 = snd[gb0 + srow1];
        int ri0 = rcv[gb0 + srow0], ri1 = rcv[gb0 + srow1];
        issue(0, 0, si0, si1, ri0, ri1);
    }
    int nsi0 = snd[gb0 + 32 + srow0], nsi1 = snd[gb0 + 32 + srow1];
    int nri0 = rcv[gb0 + 32 + srow0], nri1 = rcv[gb0 + 32 + srow1];

    for (int it = 0; it < 4; it++) {
        const int cur = it & 1, nxt = cur ^ 1;
        const int base = gb0 + it * 32;
        __syncthreads();  // B0: cur staged+visible; prev stores' out_s reads done
        if (it < 3) {
            issue(it + 1, nxt, nsi0, nsi1, nri0, nri1);  // drains at B1 (under L1)
            if (it < 2) {
                int gb = gb0 + (it + 2) * 32;
                nsi0 = snd[gb + srow0]; nsi1 = snd[gb + srow1];
                nri0 = rcv[gb + srow0]; nri1 = rcv[gb + srow1];
            }
        }

        // ---- layer 1: K=384 over [el|snd|rcv] buffers (swizzled reads) ----
        f4v acc[2][2];
#pragma unroll
        for (int mt = 0; mt < 2; mt++)
#pragma unroll
            for (int t = 0; t < 2; t++) acc[mt][t] = (f4v){0.f, 0.f, 0.f, 0.f};
        const int sw = (col & 7) << 4;
#pragma unroll
        for (int kt = 0; kt < 12; kt++) {
            const char* sb = (const char*)&stage_s[cur][kt >> 2][0][0];
            const int kb = (kt & 3) * 64 + quad * 16;
            bf8v a0 = *(const bf8v*)(sb + col * 256 + (kb ^ sw));
            bf8v a1 = *(const bf8v*)(sb + (16 + col) * 256 + (kb ^ sw));
            acc[0][0] = __builtin_amdgcn_mfma_f32_16x16x32_bf16(a0, W1[kt][0], acc[0][0], 0, 0, 0);
            acc[0][1] = __builtin_amdgcn_mfma_f32_16x16x32_bf16(a0, W1[kt][1], acc[0][1], 0, 0, 0);
            acc[1][0] = __builtin_amdgcn_mfma_f32_16x16x32_bf16(a1, W1[kt][0], acc[1][0], 0, 0, 0);
            acc[1][1] = __builtin_amdgcn_mfma_f32_16x16x32_bf16(a1, W1[kt][1], acc[1][1], 0, 0, 0);
        }
#pragma unroll
        for (int mt = 0; mt < 2; mt++)
#pragma unroll
            for (int t = 0; t < 2; t++) {
                const int nc = (2 * wave + t) * 16 + col;
#pragma unroll
                for (int r = 0; r < 4; r++) {
                    float v = fmaxf(acc[mt][t][r] + bias1[t], 0.f);
                    hid_s[(mt * 16 + quad * 4 + r) * 136 + nc] = f2bf(v);
                }
            }
        __syncthreads();  // B1: hid visible; prefetch vmcnt drained here

        // ---- layer 2 ----
#pragma unroll
        for (int mt = 0; mt < 2; mt++)
#pragma unroll
            for (int t = 0; t < 2; t++) acc[mt][t] = (f4v){0.f, 0.f, 0.f, 0.f};
#pragma unroll
        for (int kt = 0; kt < 4; kt++) {
            bf8v a0 = *(const bf8v*)(hid_s + col * 136 + kt * 32 + quad * 8);
            bf8v a1 = *(const bf8v*)(hid_s + (16 + col) * 136 + kt * 32 + quad * 8);
            acc[0][0] = __builtin_amdgcn_mfma_f32_16x16x32_bf16(a0, W2[kt][0], acc[0][0], 0, 0, 0);
            acc[0][1] = __builtin_amdgcn_mfma_f32_16x16x32_bf16(a0, W2[kt][1], acc[0][1], 0, 0, 0);
            acc[1][0] = __builtin_amdgcn_mfma_f32_16x16x32_bf16(a1, W2[kt][0], acc[1][0], 0, 0, 0);
            acc[1][1] = __builtin_amdgcn_mfma_f32_16x16x32_bf16(a1, W2[kt][1], acc[1][1], 0, 0, 0);
        }
        // no barrier: epilogue writes out_s (no WAR with hid_s reads)

        // ---- epilogue: residual (from cur el buffer, swizzled) + bias2 -> out_s ----
#pragma unroll
        for (int mt = 0; mt < 2; mt++)
#pragma unroll
            for (int t = 0; t < 2; t++) {
                const int nc = (2 * wave + t) * 16 + col;
#pragma unroll
                for (int r = 0; r < 4; r++) {
                    const int row = mt * 16 + quad * 4 + r;
                    float res = bflo((unsigned int)stage_s[cur][0][row][nc ^ ((row & 7) << 3)]);
                    float v = acc[mt][t][r] + bias2[t] + res;
                    out_s[row * 136 + nc] = f2bf(v);
                }
            }
        __syncthreads();  // B2: out_s staged; cur fully consumed
#pragma unroll
        for (int p = 0; p < 2; p++) {
            int e = p * 16 + erow;
            *(uint4*)(el + (size_t)(base + e) * 128 + c16 * 8) =
                *(const uint4*)(out_s + e * 136 + c16 * 8);
        }
    }
}

// ---------------- node step: [nl_hi|nl_lo|agg_hi] (K=384) -> 128 -> 128, residual, hi/lo out ----------------
// v14: same WAR-barrier removal as v13's edge_step, zero LDS cost: the epilogue
// writes the output hi/lo IN PLACE into a_s (each (row,nc) owned by exactly one
// thread; its residual read precedes its write in program order), so the
// "reuse hid_s" barrier disappears (5 -> 4 barriers/iter) and occupancy stays
// 3 blocks/CU (41.9 KB; an out_s buffer would have dropped it to 2).

__global__ __launch_bounds__(256) void k_node_step_s(
    unsigned short* __restrict__ nlh, unsigned short* __restrict__ nll,
    const unsigned short* __restrict__ agg,
    const unsigned short* __restrict__ w1h, const unsigned short* __restrict__ w1l,
    const float* __restrict__ b1,
    const unsigned short* __restrict__ w2h, const unsigned short* __restrict__ w2l,
    const float* __restrict__ b2) {
    __shared__ __align__(16) unsigned short a_s[32 * 392];
    __shared__ __align__(16) unsigned short hid_s[32 * 264];
    const int tid = threadIdx.x, wave = tid >> 6, lane = tid & 63;
    const int col = lane & 15, quad = lane >> 4;
    bf8v W1H[8][2], W1L[8][2], W2H[4][2], W2L[4][2];
#pragma unroll
    for (int kt = 0; kt < 8; kt++)
#pragma unroll
        for (int t = 0; t < 2; t++) {
            W1H[kt][t] = *(const bf8v*)(w1h + ((size_t)(kt * 8 + 2 * wave + t) * 64 + lane) * 8);
            W1L[kt][t] = *(const bf8v*)(w1l + ((size_t)(kt * 8 + 2 * wave + t) * 64 + lane) * 8);
        }
#pragma unroll
    for (int kt = 0; kt < 4; kt++)
#pragma unroll
        for (int t = 0; t < 2; t++) {
            W2H[kt][t] = *(const bf8v*)(w2h + ((size_t)(kt * 8 + 2 * wave + t) * 64 + lane) * 8);
            W2L[kt][t] = *(const bf8v*)(w2l + ((size_t)(kt * 8 + 2 * wave + t) * 64 + lane) * 8);
        }
    float bias1[2], bias2[2];
#pragma unroll
    for (int t = 0; t < 2; t++) {
        bias1[t] = b1[(2 * wave + t) * 16 + col];
        bias2[t] = b2[(2 * wave + t) * 16 + col];
    }
    for (int it = 0; it < 2; it++) {
        const int base = blockIdx.x * 64 + it * 32;
        if (base >= NN) break;
        __syncthreads();  // prev-iter a_s reads (global store) done
        // stage: direct uint4 copies (hi | lo | agg)
#pragma unroll
        for (int p = 0; p < 2; p++) {
            int e = p * 16 + (tid >> 4), c16 = tid & 15;
            int n = base + e; if (n > NN - 1) n = NN - 1;
            *(uint4*)(a_s + e * 392 + c16 * 8) =
                *(const uint4*)(nlh + (size_t)n * 128 + c16 * 8);
            *(uint4*)(a_s + e * 392 + 128 + c16 * 8) =
                *(const uint4*)(nll + (size_t)n * 128 + c16 * 8);
            *(uint4*)(a_s + e * 392 + 256 + c16 * 8) =
                *(const uint4*)(agg + (size_t)n * 128 + c16 * 8);
        }
        __syncthreads();

        f4v acc[2][2];
#pragma unroll
        for (int mt = 0; mt < 2; mt++)
#pragma unroll
            for (int t = 0; t < 2; t++) acc[mt][t] = (f4v){0.f, 0.f, 0.f, 0.f};
        // layer1: nl hi+lo vs W1H[0..3], agg vs W1H[4..7], nl hi vs W1L[0..3], agg vs W1L[4..7]
#pragma unroll
        for (int kt = 0; kt < 8; kt++) {
            bf8v a0 = *(const bf8v*)(a_s + col * 392 + kt * 32 + quad * 8);
            bf8v a1 = *(const bf8v*)(a_s + (16 + col) * 392 + kt * 32 + quad * 8);
#pragma unroll
            for (int t = 0; t < 2; t++) {
                acc[0][t] = __builtin_amdgcn_mfma_f32_16x16x32_bf16(a0, W1H[kt & 3][t], acc[0][t], 0, 0, 0);
                acc[1][t] = __builtin_amdgcn_mfma_f32_16x16x32_bf16(a1, W1H[kt & 3][t], acc[1][t], 0, 0, 0);
            }
        }
#pragma unroll
        for (int kt = 0; kt < 4; kt++) {
            bf8v a0 = *(const bf8v*)(a_s + col * 392 + 256 + kt * 32 + quad * 8);
            bf8v a1 = *(const bf8v*)(a_s + (16 + col) * 392 + 256 + kt * 32 + quad * 8);
#pragma unroll
            for (int t = 0; t < 2; t++) {
                acc[0][t] = __builtin_amdgcn_mfma_f32_16x16x32_bf16(a0, W1H[4 + kt][t], acc[0][t], 0, 0, 0);
                acc[1][t] = __builtin_amdgcn_mfma_f32_16x16x32_bf16(a1, W1H[4 + kt][t], acc[1][t], 0, 0, 0);
            }
        }
#pragma unroll
        for (int kt = 0; kt < 4; kt++) {
            bf8v a0 = *(const bf8v*)(a_s + col * 392 + kt * 32 + quad * 8);
            bf8v a1 = *(const bf8v*)(a_s + (16 + col) * 392 + kt * 32 + quad * 8);
#pragma unroll
            for (int t = 0; t < 2; t++) {
                acc[0][t] = __builtin_amdgcn_mfma_f32_16x16x32_bf16(a0, W1L[kt][t], acc[0][t], 0, 0, 0);
                acc[1][t] = __builtin_amdgcn_mfma_f32_16x16x32_bf16(a1, W1L[kt][t], acc[1][t], 0, 0, 0);
            }
        }
#pragma unroll
        for (int kt = 0; kt < 4; kt++) {
            bf8v a0 = *(const bf8v*)(a_s + col * 392 + 256 + kt * 32 + quad * 8);
            bf8v a1 = *(const bf8v*)(a_s + (16 + col) * 392 + 256 + kt * 32 + quad * 8);
#pragma unroll
            for (int t = 0; t < 2; t++) {
                acc[0][t] = __builtin_amdgcn_mfma_f32_16x16x32_bf16(a0, W1L[4 + kt][t], acc[0][t], 0, 0, 0);
                acc[1][t] = __builtin_amdgcn_mfma_f32_16x16x32_bf16(a1, W1L[4 + kt][t], acc[1][t], 0, 0, 0);
            }
        }
#pragma unroll
        for (int mt = 0; mt < 2; mt++)
#pragma unroll
            for (int t = 0; t < 2; t++) {
                const int nc = (2 * wave + t) * 16 + col;
#pragma unroll
                for (int r = 0; r < 4; r++) {
                    float h = fmaxf(acc[mt][t][r] + bias1[t], 0.f);
                    unsigned short hh = f2bf(h);
                    hid_s[(mt * 16 + quad * 4 + r) * 264 + nc] = hh;
                    hid_s[(mt * 16 + quad * 4 + r) * 264 + 128 + nc] = f2bf(h - bflo(hh));
                }
            }
        __syncthreads();
#pragma unroll
        for (int mt = 0; mt < 2; mt++)
#pragma unroll
            for (int t = 0; t < 2; t++) acc[mt][t] = (f4v){0.f, 0.f, 0.f, 0.f};
#pragma unroll
        for (int kt = 0; kt < 8; kt++) {
            int w = kt & 3;
            bf8v a0 = *(const bf8v*)(hid_s + col * 264 + kt * 32 + quad * 8);
            bf8v a1 = *(const bf8v*)(hid_s + (16 + col) * 264 + kt * 32 + quad * 8);
#pragma unroll
            for (int t = 0; t < 2; t++) {
                acc[0][t] = __builtin_amdgcn_mfma_f32_16x16x32_bf16(a0, W2H[w][t], acc[0][t], 0, 0, 0);
                acc[1][t] = __builtin_amdgcn_mfma_f32_16x16x32_bf16(a1, W2H[w][t], acc[1][t], 0, 0, 0);
            }
        }
#pragma unroll
        for (int kt = 0; kt < 4; kt++) {
            bf8v a0 = *(const bf8v*)(hid_s + col * 264 + kt * 32 + quad * 8);
            bf8v a1 = *(const bf8v*)(hid_s + (16 + col) * 264 + kt * 32 + quad * 8);
#pragma unroll
            for (int t = 0; t < 2; t++) {
                acc[0][t] = __builtin_amdgcn_mfma_f32_16x16x32_bf16(a0, W2L[kt][t], acc[0][t], 0, 0, 0);
                acc[1][t] = __builtin_amdgcn_mfma_f32_16x16x32_bf16(a1, W2L[kt][t], acc[1][t], 0, 0, 0);
            }
        }
        // no barrier: epilogue writes a_s in place (hid_s untouched; each
        // (row,nc) read-then-written by its unique owner thread)
#pragma unroll
        for (int mt = 0; mt < 2; mt++)
#pragma unroll
            for (int t = 0; t < 2; t++) {
                const int nc = (2 * wave + t) * 16 + col;
#pragma unroll
                for (int r = 0; r < 4; r++) {
                    const int row = mt * 16 + quad * 4 + r;
                    // residual from a_s hi+lo, then overwrite same slots with output
                    float res = bflo((unsigned int)a_s[row * 392 + nc]) +
                                bflo((unsigned int)a_s[row * 392 + 128 + nc]);
                    float v = acc[mt][t][r] + bias2[t] + res;
                    unsigned short hh = f2bf(v);
                    a_s[row * 392 + nc] = hh;
                    a_s[row * 392 + 128 + nc] = f2bf(v - bflo(hh));
                }
            }
        __syncthreads();  // out staged in a_s
#pragma unroll
        for (int p = 0; p < 2; p++) {
            int e = p * 16 + (tid >> 4), c16 = tid & 15;
            if (base + e < NN) {
                *(uint4*)(nlh + (size_t)(base + e) * 128 + c16 * 8) =
                    *(const uint4*)(a_s + e * 392 + c16 * 8);
                *(uint4*)(nll + (size_t)(base + e) * 128 + c16 * 8) =
                    *(const uint4*)(a_s + e * 392 + 128 + c16 * 8);
            }
        }
    }
}

// ---------------- decoder: 128 -> 128 -> 3 (fp32 VALU, reads hi+lo) ----------------

__global__ __launch_bounds__(128) void k_decode(
    const unsigned short* __restrict__ nlh, const unsigned short* __restrict__ nll,
    const float* __restrict__ w1, const float* __restrict__ b1,
    const float* __restrict__ w2, const float* __restrict__ b2,
    float* __restrict__ out) {
    __shared__ float inl[16][128];
    __shared__ float hid[16][128];
    int j = threadIdx.x;
    int base = blockIdx.x * 16;
    for (int e = 0; e < 16; e++)
        inl[e][j] = bflo((unsigned int)nlh[(size_t)(base + e) * 128 + j]) +
                    bflo((unsigned int)nll[(size_t)(base + e) * 128 + j]);
    __syncthreads();
    float acc[16];
#pragma unroll
    for (int e = 0; e < 16; e++) acc[e] = b1[j];
    for (int kc = 0; kc < 16; kc++) {
        float w[8];
#pragma unroll
        for (int t = 0; t < 8; t++) w[t] = w1[(kc * 8 + t) * 128 + j];
#pragma unroll
        for (int e = 0; e < 16; e++) {
            float4 h0 = *(const float4*)&inl[e][kc * 8];
            float4 h1 = *(const float4*)&inl[e][kc * 8 + 4];
            acc[e] = fmaf(h0.x, w[0], acc[e]); acc[e] = fmaf(h0.y, w[1], acc[e]);
            acc[e] = fmaf(h0.z, w[2], acc[e]); acc[e] = fmaf(h0.w, w[3], acc[e]);
            acc[e] = fmaf(h1.x, w[4], acc[e]); acc[e] = fmaf(h1.y, w[5], acc[e]);
            acc[e] = fmaf(h1.z, w[6], acc[e]); acc[e] = fmaf(h1.w, w[7], acc[e]);
        }
    }
#pragma unroll
    for (int e = 0; e < 16; e++) hid[e][j] = fmaxf(acc[e], 0.f);
    __syncthreads();
    if (j < 48) {
        int e = j / 3, ch = j - 3 * (j / 3);
        float s = b2[ch];
        for (int k = 0; k < 128; k++) s = fmaf(hid[e][k], w2[k * 3 + ch], s);
        out[(size_t)(base + e) * 3 + ch] = s;
    }
}

// ---------------- launch ----------------

extern "C" void kernel_launch(void* const* d_in, const int* in_sizes, int n_in,
                              void* d_out, int out_size, void* d_ws, size_t ws_size,
                              hipStream_t stream) {
    (void)in_sizes; (void)n_in; (void)out_size; (void)ws_size;
    const float* pos   = (const float*)d_in[0];
    const float* vel   = (const float*)d_in[1];
    const int*   rid   = (const int*)d_in[2];
    const int*   snd   = (const int*)d_in[3];
    const int*   rcv   = (const int*)d_in[4];
    const float* remb  = (const float*)d_in[5];
    const float* ne_w1 = (const float*)d_in[6];
    const float* ne_b1 = (const float*)d_in[7];
    const float* ne_w2 = (const float*)d_in[8];
    const float* ne_b2 = (const float*)d_in[9];
    const float* ee_w1 = (const float*)d_in[10];
    const float* ee_b1 = (const float*)d_in[11];
    const float* ee_w2 = (const float*)d_in[12];
    const float* ee_b2 = (const float*)d_in[13];
    const float* pe_w1 = (const float*)d_in[14];
    const float* pe_b1 = (const float*)d_in[15];
    const float* pe_w2 = (const float*)d_in[16];
    const float* pe_b2 = (const float*)d_in[17];
    const float* pn_w1 = (const float*)d_in[18];
    const float* pn_b1 = (const float*)d_in[19];
    const float* pn_w2 = (const float*)d_in[20];
    const float* pn_b2 = (const float*)d_in[21];
    const float* de_w1 = (const float*)d_in[22];
    const float* de_b1 = (const float*)d_in[23];
    const float* de_w2 = (const float*)d_in[24];
    const float* de_b2 = (const float*)d_in[25];
    float* out = (float*)d_out;

    // workspace carve (~250.6e6 B — under the 256.2e6 proven available)
    char* p = (char*)d_ws;
    auto carve = [&](size_t bytes) { void* q = (void*)p; p += (bytes + 15) & ~(size_t)15; return q; };
    unsigned short* el    = (unsigned short*)carve((size_t)NE * LDIM * 2);   // 204.8e6, CSR order
    unsigned short* nlh   = (unsigned short*)carve((size_t)NN * LDIM * 2);   // 12.8e6
    unsigned short* nll   = (unsigned short*)carve((size_t)NN * LDIM * 2);   // 12.8e6
    unsigned short* agg   = (unsigned short*)carve((size_t)NN * LDIM * 2);   // 12.8e6 (bf16)
    unsigned short* w1f_e = (unsigned short*)carve((size_t)NSTEPS * 12 * 8 * 512 * 2);
    unsigned short* w2f_e = (unsigned short*)carve((size_t)NSTEPS * 4 * 8 * 512 * 2);
    unsigned short* w1h_n = (unsigned short*)carve((size_t)NSTEPS * 8 * 8 * 512 * 2);
    unsigned short* w1l_n = (unsigned short*)carve((size_t)NSTEPS * 8 * 8 * 512 * 2);
    unsigned short* w2h_n = (unsigned short*)carve((size_t)NSTEPS * 4 * 8 * 512 * 2);
    unsigned short* w2l_n = (unsigned short*)carve((size_t)NSTEPS * 4 * 8 * 512 * 2);
    unsigned short* eew1h = (unsigned short*)carve((size_t)1 * 8 * 512 * 2);
    unsigned short* eew1l = (unsigned short*)carve((size_t)1 * 8 * 512 * 2);
    unsigned short* eew2h = (unsigned short*)carve((size_t)4 * 8 * 512 * 2);
    unsigned short* eew2l = (unsigned short*)carve((size_t)4 * 8 * 512 * 2);
    unsigned short* new1h = (unsigned short*)carve((size_t)1 * 8 * 512 * 2);
    unsigned short* new1l = (unsigned short*)carve((size_t)1 * 8 * 512 * 2);
    unsigned short* new2h = (unsigned short*)carve((size_t)4 * 8 * 512 * 2);
    unsigned short* new2l = (unsigned short*)carve((size_t)4 * 8 * 512 * 2);
    unsigned short* snd_p = (unsigned short*)carve((size_t)NE * 2);          // 1.6e6
    unsigned short* rcv_p = (unsigned short*)carve((size_t)NE * 2);          // 1.6e6
    int*            rs    = (int*)carve((size_t)(NN + 1) * 4);
    int*            cnt   = (int*)carve((size_t)NN * 4);
    int*            cur   = (int*)carve((size_t)NN * 4);
    float*          degf  = (float*)carve((size_t)NN * 4);
    float*          csum  = (float*)carve(16);

    hipMemsetAsync(cnt, 0, (size_t)NN * 4, stream);
    hipMemsetAsync(csum, 0, 16, stream);
    k_hist<<<NE / 256, 256, 0, stream>>>(rcv, cnt);
    k_scan<<<1, 1024, 0, stream>>>(cnt, rs, cur, degf);
    k_center<<<64, 256, 0, stream>>>(pos, csum);
    k_scatter<<<NE / 256, 256, 0, stream>>>(snd, rcv, cur, snd_p, rcv_p);
    k_prep_w<<<NSTEPS * 12 * 8, 64, 0, stream>>>(pe_w1, w1f_e, 12, 384, 0);
    k_prep_w<<<NSTEPS * 4 * 8, 64, 0, stream>>>(pe_w2, w2f_e, 4, 128, 0);
    k_prep_w<<<NSTEPS * 8 * 8, 64, 0, stream>>>(pn_w1, w1h_n, 8, 256, 0);
    k_prep_w<<<NSTEPS * 8 * 8, 64, 0, stream>>>(pn_w1, w1l_n, 8, 256, 1);
    k_prep_w<<<NSTEPS * 4 * 8, 64, 0, stream>>>(pn_w2, w2h_n, 4, 128, 0);
    k_prep_w<<<NSTEPS * 4 * 8, 64, 0, stream>>>(pn_w2, w2l_n, 4, 128, 1);
    k_prep_w<<<8, 64, 0, stream>>>(ee_w1, eew1h, 1, 9, 0);
    k_prep_w<<<8, 64, 0, stream>>>(ee_w1, eew1l, 1, 9, 1);
    k_prep_w<<<4 * 8, 64, 0, stream>>>(ee_w2, eew2h, 4, 128, 0);
    k_prep_w<<<4 * 8, 64, 0, stream>>>(ee_w2, eew2l, 4, 128, 1);
    k_prep_w<<<8, 64, 0, stream>>>(ne_w1, new1h, 1, 23, 0);
    k_prep_w<<<8, 64, 0, stream>>>(ne_w1, new1l, 1, 23, 1);
    k_prep_w<<<4 * 8, 64, 0, stream>>>(ne_w2, new2h, 4, 128, 0);
    k_prep_w<<<4 * 8, 64, 0, stream>>>(ne_w2, new2l, 4, 128, 1);

    k_node_enc_m<<<(NN + 127) / 128, 256, 0, stream>>>(pos, vel, rid, remb, degf, csum,
                                                       new1h, new1l, ne_b1, new2h, new2l, ne_b2, nlh, nll);
    k_edge_enc_m<<<NE / 128, 256, 0, stream>>>(pos, vel, rid, snd_p, rcv_p,
                                               eew1h, eew1l, ee_b1, eew2h, eew2l, ee_b2, el);
    for (int i = 0; i < NSTEPS; i++) {
        k_edge_step<<<NE / 128, 256, 0, stream>>>(el, nlh, snd_p, rcv_p,
            w1f_e + (size_t)i * 12 * 8 * 512, pe_b1 + i * 128,
            w2f_e + (size_t)i * 4 * 8 * 512, pe_b2 + i * 128);
        k_agg<<<(NN + 3) / 4, 256, 0, stream>>>(el, rs, agg);
        k_node_step_s<<<(NN + 63) / 64, 256, 0, stream>>>(nlh, nll, agg,
            w1h_n + (size_t)i * 8 * 8 * 512, w1l_n + (size_t)i * 8 * 8 * 512, pn_b1 + i * 128,
            w2h_n + (size_t)i * 4 * 8 * 512, w2l_n + (size_t)i * 4 * 8 * 512, pn_b2 + i * 128);
    }
    k_decode<<<NN / 16, 128, 0, stream>>>(nlh, nll, de_w1, de_b1, de_w2, de_b2, out);
}